// Round 8
// baseline (12579.797 us; speedup 1.0000x reference)
//
#include <hip/hip_runtime.h>
#include <math.h>

#define EPS_BN 1e-5f

// Wire formats (established r0-r7): float inputs = bf16 (runtime-verified by
// k_detect), int inputs = int32/int64 (runtime-detected), OUTPUT = FP32.

// ---------- helpers ----------
static __device__ __forceinline__ float bf2f(unsigned short b){
  return __uint_as_float(((unsigned)b) << 16);
}
static __device__ __forceinline__ unsigned short f2bf(float f){
  unsigned u = __float_as_uint(f);
  u += 0x7fffu + ((u >> 16) & 1u);   // RNE (finite values only)
  return (unsigned short)(u >> 16);
}
static inline int cdiv(int a, int b){ return (a + b - 1) / b; }
static __device__ __forceinline__ int clampi(int v, int lo, int hi){
  return v < lo ? lo : (v > hi ? hi : v);
}
static __device__ __forceinline__ int ld_idx(const void* p, long e, int m64){
  return m64 ? (int)((const long long*)p)[e] : ((const int*)p)[e];
}

// ---------- sentinel: ws too small (fp32 now) ----------
__global__ void k_sentinel(float* out, int n){
  int i = blockIdx.x*256 + threadIdx.x;
  if (i < n) out[i] = -12288.0f;
}

// ---------- runtime dtype detection ----------
// dmode[0]=1 iff ints are int64 on the wire; dmode[1]=1 iff floats are fp32.
__global__ void k_detect(const void* ei, const void* pos, int* dmode){
  __shared__ int nz, ff;
  if (threadIdx.x == 0){ nz = 0; ff = 0; }
  __syncthreads();
  const int* w32 = (const int*)ei;
  if (w32[1 + 2*threadIdx.x] != 0) nz = 1;        // int64 high words are 0
  const unsigned short* ph = (const unsigned short*)pos;
  int bad = 0;
  for (int i = threadIdx.x; i < 8192; i += 256)
    if (((ph[i] >> 7) & 0xFF) == 0xFF) bad = 1;   // fp32 halves hit exp=0xFF; bf16 N(0,1) never
  if (bad) ff = 1;
  __syncthreads();
  if (threadIdx.x == 0){ dmode[0] = nz ? 0 : 1; dmode[1] = ff; }
}

// ---------- expand float inputs -> fp32 scratch (mode-aware) ----------
struct ExpItem { const void* s; float* d; int n; };
struct ExpArgs { ExpItem it[31]; };
__global__ void k_expand(ExpArgs a, int cnt, const int* dmode){
  int i = blockIdx.y;
  if (i >= cnt) return;
  int m32 = dmode[1];
  int t = blockIdx.x*256 + threadIdx.x;
  if (t < a.it[i].n){
    a.it[i].d[t] = m32 ? ((const float*)a.it[i].s)[t]
                       : bf2f(((const unsigned short*)a.it[i].s)[t]);
  }
}

// ---------- W4 split: m4 = Wa@xi + Wb@xj + b4 ----------
__global__ void k_prepW4(const float* __restrict__ W4, float* __restrict__ Wa, float* __restrict__ Wb){
  int i = blockIdx.x*256 + threadIdx.x;
  if (i < 4096){
    int c = i >> 6, k = i & 63;
    float a = W4[c*128 + k], b = W4[c*128 + 64 + k];
    Wa[i] = a - b;
    Wb[i] = b;
  }
}

// ---------- CSR build ----------
__global__ void k_hist(const void* __restrict__ ei, int E, int N, const int* dmode, int* __restrict__ deg){
  int m64 = dmode[0];
  int e = blockIdx.x*256 + threadIdx.x;
  if (e < E) atomicAdd(&deg[clampi(ld_idx(ei, (long)E + e, m64), 0, N-1)], 1);
}

__global__ void k_scan1(const int* __restrict__ deg, int N, int* __restrict__ incl, int* __restrict__ part){
  __shared__ int s[1024];
  int i = blockIdx.x*1024 + threadIdx.x;
  s[threadIdx.x] = (i < N) ? deg[i] : 0;
  __syncthreads();
  for (int off = 1; off < 1024; off <<= 1){
    int t = (threadIdx.x >= off) ? s[threadIdx.x - off] : 0;
    __syncthreads();
    s[threadIdx.x] += t;
    __syncthreads();
  }
  if (i < N) incl[i] = s[threadIdx.x];
  if (threadIdx.x == 1023) part[blockIdx.x] = s[1023];
}

__global__ void k_scan2(int* __restrict__ part, int nb){
  __shared__ int s[1024];
  int i = threadIdx.x;
  s[i] = (i < nb) ? part[i] : 0;
  __syncthreads();
  for (int off = 1; off < 1024; off <<= 1){
    int t = (i >= off) ? s[i - off] : 0;
    __syncthreads();
    s[i] += t;
    __syncthreads();
  }
  if (i < nb) part[i] = s[i];
}

__global__ void k_scan3(const int* __restrict__ deg, const int* __restrict__ part, int N, int E,
                        int* __restrict__ offs, int* __restrict__ cursor){
  int i = blockIdx.x*1024 + threadIdx.x;
  if (i < N){
    int prev = (blockIdx.x > 0) ? part[blockIdx.x - 1] : 0;
    int v = prev + offs[i] - deg[i];   // offs holds inclusive scan
    offs[i] = v;
    cursor[i] = v;
  }
  if (blockIdx.x == 0 && threadIdx.x == 0) offs[N] = E;
}

__global__ void k_fill(const void* __restrict__ ei, int E, int N, const int* dmode,
                       int* __restrict__ cursor, int* __restrict__ bucket){
  int m64 = dmode[0];
  int e = blockIdx.x*256 + threadIdx.x;
  if (e < E){
    int p = atomicAdd(&cursor[clampi(ld_idx(ei, (long)E + e, m64), 0, N-1)], 1);
    if (p >= 0 && p < E) bucket[p] = e;
  }
}

// ---------- conv1 layer1 stats (m1 not materialized; 8 edges/thread) ----------
__global__ void k_m1stats(const float* __restrict__ pos, const void* __restrict__ ei,
                          int E, int N, const int* dmode,
                          const float* __restrict__ W1, const float* __restrict__ b1,
                          float* __restrict__ repl){
  int m64 = dmode[0];
  int lane = threadIdx.x & 63;
  int flatwave = (blockIdx.x*256 + threadIdx.x) >> 6;
  long base = (long)flatwave * 512;
  float as[64], aq[64];
  #pragma unroll
  for (int c = 0; c < 64; c++){ as[c] = 0.f; aq[c] = 0.f; }
  for (int k = 0; k < 8; k++){
    long e = base + (long)k*64 + lane;
    if (e < E){
      int si = clampi(ld_idx(ei, e, m64), 0, N-1);
      int di = clampi(ld_idx(ei, (long)E + e, m64), 0, N-1);
      float x0 = pos[di*3+0], x1 = pos[di*3+1], x2 = pos[di*3+2];
      float j0 = pos[si*3+0]-x0, j1 = pos[si*3+1]-x1, j2 = pos[si*3+2]-x2;
      #pragma unroll
      for (int c = 0; c < 64; c++){
        float m = b1[c];
        m = fmaf(x0, W1[c*6+0], m); m = fmaf(x1, W1[c*6+1], m); m = fmaf(x2, W1[c*6+2], m);
        m = fmaf(j0, W1[c*6+3], m); m = fmaf(j1, W1[c*6+4], m); m = fmaf(j2, W1[c*6+5], m);
        as[c] += m; aq[c] += m*m;
      }
    }
  }
  float outs = 0.f, outq = 0.f;
  #pragma unroll
  for (int c = 0; c < 64; c++){
    float s = as[c], q = aq[c];
    #pragma unroll
    for (int m = 1; m < 64; m <<= 1){ s += __shfl_xor(s, m, 64); q += __shfl_xor(q, m, 64); }
    if (lane == c){ outs = s; outq = q; }
  }
  int r = flatwave & 63;
  atomicAdd(&repl[r*256 + lane], outs);
  atomicAdd(&repl[r*256 + 128 + lane], outq);
}

// ---------- finalize BN: fold (g,be,mean,var) -> scale/shift; clamp var ----------
__global__ void k_finalize(float* __restrict__ repl, int C, float count,
                           const float* __restrict__ g, const float* __restrict__ be,
                           float* __restrict__ ss){
  int c = threadIdx.x;
  if (c < C){
    float s = 0.f, q = 0.f;
    for (int r = 0; r < 64; r++){
      s += repl[r*256 + c];       repl[r*256 + c] = 0.f;
      q += repl[r*256 + 128 + c]; repl[r*256 + 128 + c] = 0.f;
    }
    float mean = s / count;
    float var  = fmaxf(q / count - mean*mean, 0.f);
    float inv  = rsqrtf(var + EPS_BN);
    float sc   = g[c] * inv;
    ss[c]     = sc;
    ss[C + c] = be[c] - mean*sc;
  }
}

// ---------- z[64] @ W[64x64]^T + b -> bf16 row ----------
static __device__ __forceinline__ void matmul64_bf16_store(
    const float* __restrict__ z, const float* __restrict__ W, const float* __restrict__ b,
    unsigned short* __restrict__ rowptr){
  uint4* orow = (uint4*)rowptr;
  for (int c0 = 0; c0 < 64; c0 += 8){
    float acc[8];
    #pragma unroll
    for (int j = 0; j < 8; j++) acc[j] = b[c0 + j];
    #pragma unroll
    for (int i = 0; i < 64; i++){
      float zi = z[i];
      #pragma unroll
      for (int j = 0; j < 8; j++) acc[j] = fmaf(zi, W[(c0 + j)*64 + i], acc[j]);
    }
    uint4 u;
    u.x = ((unsigned)f2bf(acc[1]) << 16) | (unsigned)f2bf(acc[0]);
    u.y = ((unsigned)f2bf(acc[3]) << 16) | (unsigned)f2bf(acc[2]);
    u.z = ((unsigned)f2bf(acc[5]) << 16) | (unsigned)f2bf(acc[4]);
    u.w = ((unsigned)f2bf(acc[7]) << 16) | (unsigned)f2bf(acc[6]);
    orow[c0 >> 3] = u;
  }
}

// ---------- conv1: recompute m1, BN1+ReLU, m2 = z1@W2^T -> mbuf ----------
__global__ void k_conv1_l2(const float* __restrict__ pos, const void* __restrict__ ei,
                           int E, int N, const int* dmode,
                           const float* __restrict__ W1, const float* __restrict__ b1,
                           const float* __restrict__ ss1,
                           const float* __restrict__ W2, const float* __restrict__ b2,
                           unsigned short* __restrict__ mbuf){
  int m64 = dmode[0];
  int e = blockIdx.x*256 + threadIdx.x;
  if (e >= E) return;
  int si = clampi(ld_idx(ei, (long)e, m64), 0, N-1);
  int di = clampi(ld_idx(ei, (long)E + e, m64), 0, N-1);
  float x0 = pos[di*3+0], x1 = pos[di*3+1], x2 = pos[di*3+2];
  float j0 = pos[si*3+0]-x0, j1 = pos[si*3+1]-x1, j2 = pos[si*3+2]-x2;
  float z[64];
  #pragma unroll
  for (int c = 0; c < 64; c++){
    float m = b1[c];
    m = fmaf(x0, W1[c*6+0], m); m = fmaf(x1, W1[c*6+1], m); m = fmaf(x2, W1[c*6+2], m);
    m = fmaf(j0, W1[c*6+3], m); m = fmaf(j1, W1[c*6+4], m); m = fmaf(j2, W1[c*6+5], m);
    z[c] = fmaxf(fmaf(m, ss1[c], ss1[64 + c]), 0.f);
  }
  matmul64_bf16_store(z, W2, b2, mbuf + (size_t)e*64);
}

// ---------- conv1: read m2, BN2+ReLU, m3 = z2@W3^T -> mbuf (in place) ----------
__global__ void k_conv1_l3(unsigned short* __restrict__ mbuf, int E,
                           const float* __restrict__ ss, const float* __restrict__ W3,
                           const float* __restrict__ b3){
  int e = blockIdx.x*256 + threadIdx.x;
  if (e >= E) return;
  uint4* row = (uint4*)(mbuf + (size_t)e*64);
  uint4 u[8];
  #pragma unroll
  for (int k = 0; k < 8; k++) u[k] = row[k];
  float z[64];
  #pragma unroll
  for (int k = 0; k < 8; k++){
    unsigned vals[4] = {u[k].x, u[k].y, u[k].z, u[k].w};
    #pragma unroll
    for (int t = 0; t < 4; t++){
      int c = k*8 + t*2;
      float lo = __uint_as_float(vals[t] << 16);
      float hi = __uint_as_float(vals[t] & 0xffff0000u);
      z[c]   = fmaxf(fmaf(lo, ss[c],   ss[64 + c]),   0.f);
      z[c+1] = fmaxf(fmaf(hi, ss[c+1], ss[64 + c+1]), 0.f);
    }
  }
  matmul64_bf16_store(z, W3, b3, mbuf + (size_t)e*64);
}

// ---------- column stats over bf16 buffer; cmask = C-1 (63 or 127) ----------
__global__ void k_stats_bf16(const unsigned short* __restrict__ buf, long total, int cmask,
                             float* __restrict__ repl){
  int tid = blockIdx.x*256 + threadIdx.x;
  int c = tid & cmask;
  long stride = (long)gridDim.x * 256;
  float s = 0.f, q = 0.f;
  long i = tid;
  for (; i + 3*stride < total; i += 4*stride){
    float v0 = bf2f(buf[i]);
    float v1 = bf2f(buf[i +   stride]);
    float v2 = bf2f(buf[i + 2*stride]);
    float v3 = bf2f(buf[i + 3*stride]);
    s += (v0 + v1) + (v2 + v3);
    q += (v0*v0 + v1*v1) + (v2*v2 + v3*v3);
  }
  for (; i < total; i += stride){ float v = bf2f(buf[i]); s += v; q += v*v; }
  int r = (tid >> 6) & 63;
  atomicAdd(&repl[r*256 + c], s);
  atomicAdd(&repl[r*256 + 128 + c], q);
}

// ---------- aggregate: gather-max over CSR; BN+ReLU folded ----------
__global__ void k_aggregate(const unsigned short* __restrict__ mbuf,
                            const int* __restrict__ offs, const int* __restrict__ bucket,
                            int N, int E, const float* __restrict__ ss,
                            unsigned short* __restrict__ xout){
  int wave = threadIdx.x >> 6;
  int lane = threadIdx.x & 63;
  int n = blockIdx.x*4 + wave;
  if (n >= N) return;
  int s0 = clampi(offs[n], 0, E);
  int s1 = clampi(offs[n + 1], s0, E);
  float sc = ss[lane], sh = ss[64 + lane];
  float acc = 0.f;   // empty segment -> 0; ReLU folded as max-with-0
  for (int k = s0; k < s1; k++){
    int e = clampi(bucket[k], 0, E-1);
    float v = bf2f(mbuf[(size_t)e*64 + lane]);
    acc = fmaxf(acc, fmaf(v, sc, sh));
  }
  xout[(size_t)n*64 + lane] = f2bf(acc);
}

// ---------- unpack a 64-wide bf16 row into fp32 regs ----------
static __device__ __forceinline__ void unpack_row64(const unsigned short* row, float* v){
  const uint4* r4 = (const uint4*)row;
  #pragma unroll
  for (int k = 0; k < 8; k++){
    uint4 u = r4[k];
    unsigned w[4] = {u.x, u.y, u.z, u.w};
    #pragma unroll
    for (int t = 0; t < 4; t++){
      v[k*8 + t*2]     = __uint_as_float(w[t] << 16);
      v[k*8 + t*2 + 1] = __uint_as_float(w[t] & 0xffff0000u);
    }
  }
}

// ---------- conv2: gather x1 rows, m4 = Wa@xi + Wb@xj + b4 -> mbuf ----------
__global__ void k_conv2(const unsigned short* __restrict__ x1, const void* __restrict__ ei,
                        int E, int N, const int* dmode,
                        const float* __restrict__ Wa, const float* __restrict__ Wb,
                        const float* __restrict__ b4, unsigned short* __restrict__ mbuf){
  int m64 = dmode[0];
  int e = blockIdx.x*256 + threadIdx.x;
  if (e >= E) return;
  int si = clampi(ld_idx(ei, (long)e, m64), 0, N-1);
  int di = clampi(ld_idx(ei, (long)E + e, m64), 0, N-1);
  float xi[64], xj[64];
  unpack_row64(x1 + (size_t)di*64, xi);
  unpack_row64(x1 + (size_t)si*64, xj);
  uint4* orow = (uint4*)(mbuf + (size_t)e*64);
  for (int c0 = 0; c0 < 64; c0 += 8){
    float acc[8];
    #pragma unroll
    for (int j = 0; j < 8; j++) acc[j] = b4[c0 + j];
    #pragma unroll
    for (int i = 0; i < 64; i++){
      float a = xi[i], b = xj[i];
      #pragma unroll
      for (int j = 0; j < 8; j++){
        acc[j] = fmaf(a, Wa[(c0 + j)*64 + i], acc[j]);
        acc[j] = fmaf(b, Wb[(c0 + j)*64 + i], acc[j]);
      }
    }
    uint4 u;
    u.x = ((unsigned)f2bf(acc[1]) << 16) | (unsigned)f2bf(acc[0]);
    u.y = ((unsigned)f2bf(acc[3]) << 16) | (unsigned)f2bf(acc[2]);
    u.z = ((unsigned)f2bf(acc[5]) << 16) | (unsigned)f2bf(acc[4]);
    u.w = ((unsigned)f2bf(acc[7]) << 16) | (unsigned)f2bf(acc[6]);
    orow[c0 >> 3] = u;
  }
}

// ---------- lin5: y5 = cat(x1,x2)@W5^T + b5 -> bf16 ----------
__global__ void k_lin5(const unsigned short* __restrict__ x1, const unsigned short* __restrict__ x2,
                       int N, const float* __restrict__ W5, const float* __restrict__ b5,
                       unsigned short* __restrict__ y5){
  int n = blockIdx.x*256 + threadIdx.x;
  if (n >= N) return;
  float xc[128];
  unpack_row64(x1 + (size_t)n*64, xc);
  unpack_row64(x2 + (size_t)n*64, xc + 64);
  uint4* orow = (uint4*)(y5 + (size_t)n*128);
  for (int c0 = 0; c0 < 128; c0 += 8){
    float acc[8];
    #pragma unroll
    for (int j = 0; j < 8; j++) acc[j] = b5[c0 + j];
    #pragma unroll
    for (int i = 0; i < 128; i++){
      float xv = xc[i];
      #pragma unroll
      for (int j = 0; j < 8; j++) acc[j] = fmaf(xv, W5[(c0 + j)*128 + i], acc[j]);
    }
    uint4 u;
    u.x = ((unsigned)f2bf(acc[1]) << 16) | (unsigned)f2bf(acc[0]);
    u.y = ((unsigned)f2bf(acc[3]) << 16) | (unsigned)f2bf(acc[2]);
    u.z = ((unsigned)f2bf(acc[5]) << 16) | (unsigned)f2bf(acc[4]);
    u.w = ((unsigned)f2bf(acc[7]) << 16) | (unsigned)f2bf(acc[6]);
    orow[c0 >> 3] = u;
  }
}

// ---------- pool: BN5+ReLU then segment_max by sorted batch ----------
__global__ void k_pool(const unsigned short* __restrict__ y5, const void* __restrict__ batch, int N,
                       const int* dmode, const float* __restrict__ ss5, unsigned int* __restrict__ pooled){
  int m64 = dmode[0];
  int c = threadIdx.x;               // 128 threads
  int n0 = blockIdx.x*512;
  int n1 = min(n0 + 512, N);
  float sc = ss5[c], sh = ss5[128 + c];
  int curb = -1; float curm = 0.f;
  for (int n = n0; n < n1; n++){
    int b = clampi(ld_idx(batch, (long)n, m64), 0, 63);
    float v = fmaf(bf2f(y5[(size_t)n*128 + c]), sc, sh);
    if (b != curb){
      if (curb >= 0) atomicMax(&pooled[curb*128 + c], __float_as_uint(fmaxf(curm, 0.f)));
      curb = b; curm = v;
    } else {
      curm = fmaxf(curm, v);
    }
  }
  if (curb >= 0) atomicMax(&pooled[curb*128 + c], __float_as_uint(fmaxf(curm, 0.f)));
}

// ---------- head: small dumb kernels ----------
__global__ void k_pooled2f(const unsigned int* __restrict__ pooled, float* __restrict__ pf){
  int i = blockIdx.x*256 + threadIdx.x;
  if (i < 8192) pf[i] = __uint_as_float(pooled[i]);
}

// Y[64,CO] = X[64,CI] @ W[CO,CI]^T + b
__global__ void k_linH(const float* __restrict__ X, const float* __restrict__ W,
                       const float* __restrict__ b, int CI, int CO, float* __restrict__ Y){
  int cell = blockIdx.x*256 + threadIdx.x;
  if (cell >= 64*CO) return;
  int r = cell / CO, c = cell - r*CO;
  const float* xr = X + r*CI;
  const float* wr = W + c*CI;
  float a = b[c];
  for (int j = 0; j < CI; j++) a = fmaf(xr[j], wr[j], a);
  Y[cell] = a;
}

// two-pass BN stats over 64 rows -> scale/shift (matches reference numerics)
__global__ void k_bnH(const float* __restrict__ Y, int CO,
                      const float* __restrict__ g, const float* __restrict__ be,
                      float* __restrict__ ss){
  int c = threadIdx.x;
  if (c >= CO) return;
  float s = 0.f;
  for (int r = 0; r < 64; r++) s += Y[r*CO + c];
  float mean = s * (1.f/64.f);
  float q = 0.f;
  for (int r = 0; r < 64; r++){ float d = Y[r*CO + c] - mean; q += d*d; }
  float var = fmaxf(q * (1.f/64.f), 0.f);
  float inv = rsqrtf(var + EPS_BN);
  float sc = g[c] * inv;
  ss[c] = sc;
  ss[CO + c] = be[c] - mean*sc;
}

__global__ void k_bnreluH(float* __restrict__ Y, int CO, const float* __restrict__ ss){
  int cell = blockIdx.x*256 + threadIdx.x;
  if (cell >= 64*CO) return;
  int c = cell % CO;
  Y[cell] = fmaxf(fmaf(Y[cell], ss[c], ss[CO + c]), 0.f);
}

// output is FP32 (the fix)
__global__ void k_logsm(const float* __restrict__ Z, float* __restrict__ out){
  int r = threadIdx.x;   // 64 threads
  const float* zr = Z + r*40;
  float m = zr[0];
  for (int c = 1; c < 40; c++) m = fmaxf(m, zr[c]);
  float s = 0.f;
  for (int c = 0; c < 40; c++) s += expf(zr[c] - m);
  float ls = logf(s);
  for (int c = 0; c < 40; c++) out[r*40 + c] = zr[c] - m - ls;
}

// ---------- launch ----------
extern "C" void kernel_launch(void* const* d_in, const int* in_sizes, int n_in,
                              void* d_out, int out_size, void* d_ws, size_t ws_size,
                              hipStream_t stream) {
  const void* pos   = d_in[0];
  const void* ei    = d_in[1];
  const void* batch = d_in[2];
  (void)n_in;

  const int N = in_sizes[0] / 3;
  const int E = in_sizes[1] / 2;

  // ---- workspace layout ----
  auto al = [](size_t x){ return (x + 255) & ~(size_t)255; };
  char* w = (char*)d_ws;
  size_t o = 0;
  float* repl = (float*)(w + o);                 o += (size_t)64*256*4;
  unsigned int* pooled = (unsigned int*)(w + o); o += (size_t)64*128*4;
  int* deg = (int*)(w + o);                      o += al((size_t)4*N);
  size_t zero_bytes = o;
  int* dmode = (int*)(w + o);                    o += 256;
  int* offs = (int*)(w + o);                     o += al((size_t)4*(N + 1));
  int* cursor = (int*)(w + o);                   o += al((size_t)4*N);
  int* part = (int*)(w + o);                     o += 4096;
  int* bucket = (int*)(w + o);                   o += al((size_t)4*E);
  float* ss1 = (float*)(w + o);                  o += 1024;
  float* ss2 = (float*)(w + o);                  o += 1024;
  float* ss3 = (float*)(w + o);                  o += 1024;
  float* ss4 = (float*)(w + o);                  o += 1024;
  float* ss5 = (float*)(w + o);                  o += 1024;
  float* ssH = (float*)(w + o);                  o += 1024;
  float* Wa = (float*)(w + o);                   o += (size_t)4096*4;
  float* Wb = (float*)(w + o);                   o += (size_t)4096*4;
  float* pooledF = (float*)(w + o);              o += (size_t)8192*4;
  float* Y6 = (float*)(w + o);                   o += (size_t)8192*4;
  float* Y7 = (float*)(w + o);                   o += (size_t)8192*4;
  float* Zl = (float*)(w + o);                   o += al((size_t)2560*4);
  // fp32 expansion region
  float* expBase = (float*)(w + o);
  float* ep = expBase;
  float* epos = ep; ep += (size_t)3*N;
  float* eW[9], *eb[9], *eg[9], *ebe[9];
  const int wsz[9] = {0, 64*6, 64*64, 64*64, 64*128, 128*128, 128*128, 128*128, 40*128};
  const int bsz[9] = {0, 64, 64, 64, 64, 128, 128, 128, 40};
  for (int i = 1; i <= 8; i++){
    eW[i] = ep; ep += wsz[i];
    eb[i] = ep; ep += bsz[i];
    if (i < 8){ eg[i] = ep; ep += bsz[i]; ebe[i] = ep; ep += bsz[i]; }
  }
  long expCount = (long)(ep - expBase);
  o += al((size_t)expCount * 4);
  unsigned short* x1b = (unsigned short*)(w + o); o += al((size_t)2*64*N);
  unsigned short* x2b = (unsigned short*)(w + o); o += al((size_t)2*64*N);
  unsigned short* y5b = (unsigned short*)(w + o); o += al((size_t)2*128*N);
  unsigned short* mbuf = (unsigned short*)(w + o); o += al((size_t)2*64*E);

  float* out_f = (float*)d_out;
  if (ws_size < o){
    k_sentinel<<<cdiv(out_size,256), 256, 0, stream>>>(out_f, out_size);
    return;
  }

  hipMemsetAsync(w, 0, zero_bytes, stream);
  k_detect<<<1, 256, 0, stream>>>(ei, pos, dmode);

  // expand all float inputs -> fp32
  ExpArgs ea;
  int it = 0;
  ea.it[it++] = {pos, epos, 3*N};
  int di_idx = 3;
  for (int i = 1; i <= 8; i++){
    ea.it[it++] = {d_in[di_idx++], eW[i], wsz[i]};
    ea.it[it++] = {d_in[di_idx++], eb[i], bsz[i]};
    if (i < 8){
      ea.it[it++] = {d_in[di_idx++], eg[i], bsz[i]};
      ea.it[it++] = {d_in[di_idx++], ebe[i], bsz[i]};
    }
  }
  k_expand<<<dim3(cdiv(3*N,256), 31), 256, 0, stream>>>(ea, it, dmode);
  k_prepW4<<<16, 256, 0, stream>>>(eW[4], Wa, Wb);

  const int nb = cdiv(N, 1024);
  // CSR build
  k_hist<<<cdiv(E,256), 256, 0, stream>>>(ei, E, N, dmode, deg);
  k_scan1<<<nb, 1024, 0, stream>>>(deg, N, offs, part);
  k_scan2<<<1, 1024, 0, stream>>>(part, nb);
  k_scan3<<<nb, 1024, 0, stream>>>(deg, part, N, E, offs, cursor);
  k_fill<<<cdiv(E,256), 256, 0, stream>>>(ei, E, N, dmode, cursor, bucket);

  // conv1
  k_m1stats<<<cdiv(E,2048), 256, 0, stream>>>(epos, ei, E, N, dmode, eW[1], eb[1], repl);
  k_finalize<<<1, 128, 0, stream>>>(repl, 64, (float)E, eg[1], ebe[1], ss1);
  k_conv1_l2<<<cdiv(E,256), 256, 0, stream>>>(epos, ei, E, N, dmode, eW[1], eb[1], ss1, eW[2], eb[2], mbuf);
  k_stats_bf16<<<1024, 256, 0, stream>>>(mbuf, (long)E*64, 63, repl);
  k_finalize<<<1, 128, 0, stream>>>(repl, 64, (float)E, eg[2], ebe[2], ss2);
  k_conv1_l3<<<cdiv(E,256), 256, 0, stream>>>(mbuf, E, ss2, eW[3], eb[3]);
  k_stats_bf16<<<1024, 256, 0, stream>>>(mbuf, (long)E*64, 63, repl);
  k_finalize<<<1, 128, 0, stream>>>(repl, 64, (float)E, eg[3], ebe[3], ss3);
  k_aggregate<<<cdiv(N,4), 256, 0, stream>>>(mbuf, offs, bucket, N, E, ss3, x1b);

  // conv2
  k_conv2<<<cdiv(E,256), 256, 0, stream>>>(x1b, ei, E, N, dmode, Wa, Wb, eb[4], mbuf);
  k_stats_bf16<<<1024, 256, 0, stream>>>(mbuf, (long)E*64, 63, repl);
  k_finalize<<<1, 128, 0, stream>>>(repl, 64, (float)E, eg[4], ebe[4], ss4);
  k_aggregate<<<cdiv(N,4), 256, 0, stream>>>(mbuf, offs, bucket, N, E, ss4, x2b);

  // lin5 + BN5 stats + pool
  k_lin5<<<cdiv(N,256), 256, 0, stream>>>(x1b, x2b, N, eW[5], eb[5], y5b);
  k_stats_bf16<<<512, 256, 0, stream>>>(y5b, (long)N*128, 127, repl);
  k_finalize<<<1, 128, 0, stream>>>(repl, 128, (float)N, eg[5], ebe[5], ss5);
  k_pool<<<cdiv(N,512), 128, 0, stream>>>(y5b, batch, N, dmode, ss5, pooled);

  // head
  k_pooled2f<<<32, 256, 0, stream>>>(pooled, pooledF);
  k_linH<<<32, 256, 0, stream>>>(pooledF, eW[6], eb[6], 128, 128, Y6);
  k_bnH<<<1, 128, 0, stream>>>(Y6, 128, eg[6], ebe[6], ssH);
  k_bnreluH<<<32, 256, 0, stream>>>(Y6, 128, ssH);
  k_linH<<<32, 256, 0, stream>>>(Y6, eW[7], eb[7], 128, 128, Y7);
  k_bnH<<<1, 128, 0, stream>>>(Y7, 128, eg[7], ebe[7], ssH);
  k_bnreluH<<<32, 256, 0, stream>>>(Y7, 128, ssH);
  k_linH<<<10, 256, 0, stream>>>(Y7, eW[8], eb[8], 128, 40, Zl);
  k_logsm<<<1, 64, 0, stream>>>(Zl, out_f);
}

// Round 9
// 11133.957 us; speedup vs baseline: 1.1299x; 1.1299x over previous
//
#include <hip/hip_runtime.h>
#include <math.h>

#define EPS_BN 1e-5f

// Wire formats (established r0-r8): float inputs = bf16 (runtime-detected),
// int inputs = int32/int64 (runtime-detected), OUTPUT = FP32.
// mbuf layout: [tile=64 edges][8 chunks][64 edge-slots][16B] -> fully coalesced
// edge I/O; edges processed in CSR-bucket order so aggregation is sequential.

// ---------- helpers ----------
static __device__ __forceinline__ float bf2f(unsigned short b){
  return __uint_as_float(((unsigned)b) << 16);
}
static __device__ __forceinline__ unsigned short f2bf(float f){
  unsigned u = __float_as_uint(f);
  u += 0x7fffu + ((u >> 16) & 1u);   // RNE (finite values only)
  return (unsigned short)(u >> 16);
}
static inline int cdiv(int a, int b){ return (a + b - 1) / b; }
static __device__ __forceinline__ int clampi(int v, int lo, int hi){
  return v < lo ? lo : (v > hi ? hi : v);
}
static __device__ __forceinline__ int ld_idx(const void* p, long e, int m64){
  return m64 ? (int)((const long long*)p)[e] : ((const int*)p)[e];
}
static __device__ __forceinline__ uint4 pack8(const float* acc){
  uint4 u;
  u.x = ((unsigned)f2bf(acc[1]) << 16) | (unsigned)f2bf(acc[0]);
  u.y = ((unsigned)f2bf(acc[3]) << 16) | (unsigned)f2bf(acc[2]);
  u.z = ((unsigned)f2bf(acc[5]) << 16) | (unsigned)f2bf(acc[4]);
  u.w = ((unsigned)f2bf(acc[7]) << 16) | (unsigned)f2bf(acc[6]);
  return u;
}
// butterfly-reduce s,q over 64 lanes; lane j commits channel c0+j
static __device__ __forceinline__ void stat_commit(float v, int valid, int lane, int j,
                                                   float* repl, int r, int c){
  float s = valid ? v : 0.f;
  float q = s * s;
  #pragma unroll
  for (int m = 1; m < 64; m <<= 1){ s += __shfl_xor(s, m, 64); q += __shfl_xor(q, m, 64); }
  if (lane == j){
    atomicAdd(&repl[r*256 + c], s);
    atomicAdd(&repl[r*256 + 128 + c], q);
  }
}

// ---------- sentinel ----------
__global__ void k_sentinel(float* out, int n){
  int i = blockIdx.x*256 + threadIdx.x;
  if (i < n) out[i] = -12288.0f;
}

// ---------- runtime dtype detection ----------
__global__ void k_detect(const void* ei, const void* pos, int* dmode){
  __shared__ int nz, ff;
  if (threadIdx.x == 0){ nz = 0; ff = 0; }
  __syncthreads();
  const int* w32 = (const int*)ei;
  if (w32[1 + 2*threadIdx.x] != 0) nz = 1;
  const unsigned short* ph = (const unsigned short*)pos;
  int bad = 0;
  for (int i = threadIdx.x; i < 8192; i += 256)
    if (((ph[i] >> 7) & 0xFF) == 0xFF) bad = 1;
  if (bad) ff = 1;
  __syncthreads();
  if (threadIdx.x == 0){ dmode[0] = nz ? 0 : 1; dmode[1] = ff; }
}

// ---------- expand float inputs -> fp32 scratch ----------
struct ExpItem { const void* s; float* d; int n; };
struct ExpArgs { ExpItem it[31]; };
__global__ void k_expand(ExpArgs a, int cnt, const int* dmode){
  int i = blockIdx.y;
  if (i >= cnt) return;
  int m32 = dmode[1];
  int t = blockIdx.x*256 + threadIdx.x;
  if (t < a.it[i].n){
    a.it[i].d[t] = m32 ? ((const float*)a.it[i].s)[t]
                       : bf2f(((const unsigned short*)a.it[i].s)[t]);
  }
}

// ---------- W4 split ----------
__global__ void k_prepW4(const float* __restrict__ W4, float* __restrict__ Wa, float* __restrict__ Wb){
  int i = blockIdx.x*256 + threadIdx.x;
  if (i < 4096){
    int c = i >> 6, k = i & 63;
    float a = W4[c*128 + k], b = W4[c*128 + 64 + k];
    Wa[i] = a - b;
    Wb[i] = b;
  }
}

// ---------- CSR build ----------
__global__ void k_hist(const void* __restrict__ ei, int E, int N, const int* dmode, int* __restrict__ deg){
  int m64 = dmode[0];
  int e = blockIdx.x*256 + threadIdx.x;
  if (e < E) atomicAdd(&deg[clampi(ld_idx(ei, (long)E + e, m64), 0, N-1)], 1);
}

__global__ void k_scan1(const int* __restrict__ deg, int N, int* __restrict__ incl, int* __restrict__ part){
  __shared__ int s[1024];
  int i = blockIdx.x*1024 + threadIdx.x;
  s[threadIdx.x] = (i < N) ? deg[i] : 0;
  __syncthreads();
  for (int off = 1; off < 1024; off <<= 1){
    int t = (threadIdx.x >= off) ? s[threadIdx.x - off] : 0;
    __syncthreads();
    s[threadIdx.x] += t;
    __syncthreads();
  }
  if (i < N) incl[i] = s[threadIdx.x];
  if (threadIdx.x == 1023) part[blockIdx.x] = s[1023];
}

__global__ void k_scan2(int* __restrict__ part, int nb){
  __shared__ int s[1024];
  int i = threadIdx.x;
  s[i] = (i < nb) ? part[i] : 0;
  __syncthreads();
  for (int off = 1; off < 1024; off <<= 1){
    int t = (i >= off) ? s[i - off] : 0;
    __syncthreads();
    s[i] += t;
    __syncthreads();
  }
  if (i < nb) part[i] = s[i];
}

__global__ void k_scan3(const int* __restrict__ deg, const int* __restrict__ part, int N, int E,
                        int* __restrict__ offs, int* __restrict__ cursor){
  int i = blockIdx.x*1024 + threadIdx.x;
  if (i < N){
    int prev = (blockIdx.x > 0) ? part[blockIdx.x - 1] : 0;
    int v = prev + offs[i] - deg[i];
    offs[i] = v;
    cursor[i] = v;
  }
  if (blockIdx.x == 0 && threadIdx.x == 0) offs[N] = E;
}

__global__ void k_fill(const void* __restrict__ ei, int E, int N, const int* dmode,
                       int* __restrict__ cursor, int* __restrict__ bucket){
  int m64 = dmode[0];
  int e = blockIdx.x*256 + threadIdx.x;
  if (e < E){
    int p = atomicAdd(&cursor[clampi(ld_idx(ei, (long)E + e, m64), 0, N-1)], 1);
    if (p >= 0 && p < E) bucket[p] = e;
  }
}

// ---------- conv1 layer1 stats (m1 not materialized) ----------
__global__ void k_m1stats(const float* __restrict__ pos, const void* __restrict__ ei,
                          int E, int N, const int* dmode,
                          const float* __restrict__ W1, const float* __restrict__ b1,
                          float* __restrict__ repl){
  int m64 = dmode[0];
  int lane = threadIdx.x & 63;
  int flatwave = (blockIdx.x*256 + threadIdx.x) >> 6;
  long base = (long)flatwave * 512;
  float as[64], aq[64];
  #pragma unroll
  for (int c = 0; c < 64; c++){ as[c] = 0.f; aq[c] = 0.f; }
  for (int k = 0; k < 8; k++){
    long e = base + (long)k*64 + lane;
    if (e < E){
      int si = clampi(ld_idx(ei, e, m64), 0, N-1);
      int di = clampi(ld_idx(ei, (long)E + e, m64), 0, N-1);
      float x0 = pos[di*3+0], x1 = pos[di*3+1], x2 = pos[di*3+2];
      float j0 = pos[si*3+0]-x0, j1 = pos[si*3+1]-x1, j2 = pos[si*3+2]-x2;
      #pragma unroll
      for (int c = 0; c < 64; c++){
        float m = b1[c];
        m = fmaf(x0, W1[c*6+0], m); m = fmaf(x1, W1[c*6+1], m); m = fmaf(x2, W1[c*6+2], m);
        m = fmaf(j0, W1[c*6+3], m); m = fmaf(j1, W1[c*6+4], m); m = fmaf(j2, W1[c*6+5], m);
        as[c] += m; aq[c] += m*m;
      }
    }
  }
  float outs = 0.f, outq = 0.f;
  #pragma unroll
  for (int c = 0; c < 64; c++){
    float s = as[c], q = aq[c];
    #pragma unroll
    for (int m = 1; m < 64; m <<= 1){ s += __shfl_xor(s, m, 64); q += __shfl_xor(q, m, 64); }
    if (lane == c){ outs = s; outq = q; }
  }
  int r = flatwave & 63;
  atomicAdd(&repl[r*256 + lane], outs);
  atomicAdd(&repl[r*256 + 128 + lane], outq);
}

// ---------- finalize BN ----------
__global__ void k_finalize(float* __restrict__ repl, int C, float count,
                           const float* __restrict__ g, const float* __restrict__ be,
                           float* __restrict__ ss){
  int c = threadIdx.x;
  if (c < C){
    float s = 0.f, q = 0.f;
    for (int r = 0; r < 64; r++){
      s += repl[r*256 + c];       repl[r*256 + c] = 0.f;
      q += repl[r*256 + 128 + c]; repl[r*256 + 128 + c] = 0.f;
    }
    float mean = s / count;
    float var  = fmaxf(q / count - mean*mean, 0.f);
    float inv  = rsqrtf(var + EPS_BN);
    float sc   = g[c] * inv;
    ss[c]     = sc;
    ss[C + c] = be[c] - mean*sc;
  }
}

// ---------- conv1 l2: bucket order, tiled store, fused stats ----------
__global__ void k_conv1_l2(const float* __restrict__ pos, const void* __restrict__ ei,
                           const int* __restrict__ bucket, int E, int N, const int* dmode,
                           const float* __restrict__ W1, const float* __restrict__ b1,
                           const float* __restrict__ ss1,
                           const float* __restrict__ W2, const float* __restrict__ b2,
                           uint4* __restrict__ mbuf4, float* __restrict__ repl){
  int m64 = dmode[0];
  int t = blockIdx.x*256 + threadIdx.x;
  int lane = threadIdx.x & 63;
  int valid = (t < E);
  int p = valid ? bucket[t] : 0;
  int si = clampi(ld_idx(ei, (long)p, m64), 0, N-1);
  int di = clampi(ld_idx(ei, (long)E + p, m64), 0, N-1);
  float x0 = pos[di*3+0], x1 = pos[di*3+1], x2 = pos[di*3+2];
  float j0 = pos[si*3+0]-x0, j1 = pos[si*3+1]-x1, j2 = pos[si*3+2]-x2;
  float z[64];
  #pragma unroll
  for (int c = 0; c < 64; c++){
    float m = b1[c];
    m = fmaf(x0, W1[c*6+0], m); m = fmaf(x1, W1[c*6+1], m); m = fmaf(x2, W1[c*6+2], m);
    m = fmaf(j0, W1[c*6+3], m); m = fmaf(j1, W1[c*6+4], m); m = fmaf(j2, W1[c*6+5], m);
    z[c] = fmaxf(fmaf(m, ss1[c], ss1[64 + c]), 0.f);
  }
  int tt = valid ? t : 0;
  uint4* obase = mbuf4 + (((size_t)(tt >> 6)) << 9) + (tt & 63);
  int r = ((blockIdx.x*256 + threadIdx.x) >> 6) & 63;
  for (int c0 = 0; c0 < 64; c0 += 8){
    float acc[8];
    #pragma unroll
    for (int j = 0; j < 8; j++) acc[j] = b2[c0 + j];
    #pragma unroll
    for (int i = 0; i < 64; i++){
      float zi = z[i];
      #pragma unroll
      for (int j = 0; j < 8; j++) acc[j] = fmaf(zi, W2[(c0 + j)*64 + i], acc[j]);
    }
    #pragma unroll
    for (int j = 0; j < 8; j++) stat_commit(acc[j], valid, lane, j, repl, r, c0 + j);
    if (valid) obase[(size_t)(c0 << 3)] = pack8(acc);
  }
}

// ---------- conv1 l3: tiled in-place, fused stats ----------
__global__ void k_conv1_l3(uint4* __restrict__ mbuf4, int E,
                           const float* __restrict__ ss, const float* __restrict__ W3,
                           const float* __restrict__ b3, float* __restrict__ repl){
  int t = blockIdx.x*256 + threadIdx.x;
  int lane = threadIdx.x & 63;
  int valid = (t < E);
  int tt = valid ? t : 0;
  uint4* base = mbuf4 + (((size_t)(tt >> 6)) << 9) + (tt & 63);
  uint4 u[8];
  #pragma unroll
  for (int k = 0; k < 8; k++) u[k] = base[(size_t)(k << 6)];
  float z[64];
  #pragma unroll
  for (int k = 0; k < 8; k++){
    unsigned vals[4] = {u[k].x, u[k].y, u[k].z, u[k].w};
    #pragma unroll
    for (int q = 0; q < 4; q++){
      int c = k*8 + q*2;
      float lo = __uint_as_float(vals[q] << 16);
      float hi = __uint_as_float(vals[q] & 0xffff0000u);
      z[c]   = fmaxf(fmaf(lo, ss[c],   ss[64 + c]),   0.f);
      z[c+1] = fmaxf(fmaf(hi, ss[c+1], ss[64 + c+1]), 0.f);
    }
  }
  int r = ((blockIdx.x*256 + threadIdx.x) >> 6) & 63;
  for (int c0 = 0; c0 < 64; c0 += 8){
    float acc[8];
    #pragma unroll
    for (int j = 0; j < 8; j++) acc[j] = b3[c0 + j];
    #pragma unroll
    for (int i = 0; i < 64; i++){
      float zi = z[i];
      #pragma unroll
      for (int j = 0; j < 8; j++) acc[j] = fmaf(zi, W3[(c0 + j)*64 + i], acc[j]);
    }
    #pragma unroll
    for (int j = 0; j < 8; j++) stat_commit(acc[j], valid, lane, j, repl, r, c0 + j);
    if (valid) base[(size_t)(c0 << 3)] = pack8(acc);
  }
}

// ---------- aggregate: sequential CSR rows in tiled layout; BN per edge + max ----------
__global__ void k_aggregate(const unsigned short* __restrict__ mbuf,
                            const int* __restrict__ offs, int N, int E,
                            const float* __restrict__ ss, unsigned short* __restrict__ xout){
  int wave = threadIdx.x >> 6;
  int lane = threadIdx.x & 63;
  int n = blockIdx.x*4 + wave;
  if (n >= N) return;
  int s0 = clampi(offs[n], 0, E);
  int s1 = clampi(offs[n + 1], s0, E);
  float sc = ss[lane], sh = ss[64 + lane];
  int g = lane >> 3, pz = lane & 7;
  float acc = 0.f;   // empty segment -> 0; ReLU folded as max-with-0 (exact: per-edge BN then max)
  for (int k = s0; k < s1; k++){
    size_t idx = (((size_t)(k >> 6)) << 12) + (g << 9) + ((k & 63) << 3) + pz;
    float v = bf2f(mbuf[idx]);
    acc = fmaxf(acc, fmaf(v, sc, sh));
  }
  xout[(size_t)n*64 + lane] = f2bf(acc);
}

// ---------- unpack row-major 64-wide bf16 row ----------
static __device__ __forceinline__ void unpack_row64(const unsigned short* row, float* v){
  const uint4* r4 = (const uint4*)row;
  #pragma unroll
  for (int k = 0; k < 8; k++){
    uint4 u = r4[k];
    unsigned w[4] = {u.x, u.y, u.z, u.w};
    #pragma unroll
    for (int q = 0; q < 4; q++){
      v[k*8 + q*2]     = __uint_as_float(w[q] << 16);
      v[k*8 + q*2 + 1] = __uint_as_float(w[q] & 0xffff0000u);
    }
  }
}

// ---------- conv2: bucket order, x1 gather, tiled store, fused stats ----------
__global__ void k_conv2(const unsigned short* __restrict__ x1, const void* __restrict__ ei,
                        const int* __restrict__ bucket, int E, int N, const int* dmode,
                        const float* __restrict__ Wa, const float* __restrict__ Wb,
                        const float* __restrict__ b4, uint4* __restrict__ mbuf4,
                        float* __restrict__ repl){
  int m64 = dmode[0];
  int t = blockIdx.x*256 + threadIdx.x;
  int lane = threadIdx.x & 63;
  int valid = (t < E);
  int p = valid ? bucket[t] : 0;
  int si = clampi(ld_idx(ei, (long)p, m64), 0, N-1);
  int di = clampi(ld_idx(ei, (long)E + p, m64), 0, N-1);
  float xi[64], xj[64];
  unpack_row64(x1 + (size_t)di*64, xi);
  unpack_row64(x1 + (size_t)si*64, xj);
  int tt = valid ? t : 0;
  uint4* obase = mbuf4 + (((size_t)(tt >> 6)) << 9) + (tt & 63);
  int r = ((blockIdx.x*256 + threadIdx.x) >> 6) & 63;
  for (int c0 = 0; c0 < 64; c0 += 8){
    float acc[8];
    #pragma unroll
    for (int j = 0; j < 8; j++) acc[j] = b4[c0 + j];
    #pragma unroll
    for (int i = 0; i < 64; i++){
      float a = xi[i], b = xj[i];
      #pragma unroll
      for (int j = 0; j < 8; j++){
        acc[j] = fmaf(a, Wa[(c0 + j)*64 + i], acc[j]);
        acc[j] = fmaf(b, Wb[(c0 + j)*64 + i], acc[j]);
      }
    }
    #pragma unroll
    for (int j = 0; j < 8; j++) stat_commit(acc[j], valid, lane, j, repl, r, c0 + j);
    if (valid) obase[(size_t)(c0 << 3)] = pack8(acc);
  }
}

// ---------- lin5: 16 nodes x 16 col-groups per block, LDS-staged inputs ----------
__global__ void k_lin5(const unsigned short* __restrict__ x1, const unsigned short* __restrict__ x2,
                       int N, const float* __restrict__ W5, const float* __restrict__ b5,
                       unsigned short* __restrict__ y5){
  __shared__ float xs[16][130];   // +2 pad: no bank conflicts
  int t = threadIdx.x;            // 256
  int nb0 = blockIdx.x * 16;
  {
    int row = t >> 4, col4 = (t & 15) * 4;
    if (nb0 + row < N){
      uint2 a = *(const uint2*)(x1 + (size_t)(nb0 + row)*64 + col4);
      uint2 b = *(const uint2*)(x2 + (size_t)(nb0 + row)*64 + col4);
      xs[row][col4+0] = __uint_as_float(a.x << 16);
      xs[row][col4+1] = __uint_as_float(a.x & 0xffff0000u);
      xs[row][col4+2] = __uint_as_float(a.y << 16);
      xs[row][col4+3] = __uint_as_float(a.y & 0xffff0000u);
      xs[row][64+col4+0] = __uint_as_float(b.x << 16);
      xs[row][64+col4+1] = __uint_as_float(b.x & 0xffff0000u);
      xs[row][64+col4+2] = __uint_as_float(b.y << 16);
      xs[row][64+col4+3] = __uint_as_float(b.y & 0xffff0000u);
    } else {
      #pragma unroll
      for (int q = 0; q < 4; q++){ xs[row][col4+q] = 0.f; xs[row][64+col4+q] = 0.f; }
    }
  }
  __syncthreads();
  int node = t >> 4, cg = t & 15;
  int n = nb0 + node;
  const float* xr = xs[node];
  const float* wbase = W5 + (size_t)(cg*8)*128;
  float acc[8];
  #pragma unroll
  for (int j = 0; j < 8; j++) acc[j] = b5[cg*8 + j];
  for (int i = 0; i < 128; i++){
    float xv = xr[i];
    #pragma unroll
    for (int j = 0; j < 8; j++) acc[j] = fmaf(xv, wbase[j*128 + i], acc[j]);
  }
  if (n < N) *(uint4*)(y5 + (size_t)n*128 + cg*8) = pack8(acc);
}

// ---------- column stats over row-major bf16 (y5 only) ----------
__global__ void k_stats_bf16(const unsigned short* __restrict__ buf, long total, int cmask,
                             float* __restrict__ repl){
  int tid = blockIdx.x*256 + threadIdx.x;
  int c = tid & cmask;
  long stride = (long)gridDim.x * 256;
  float s = 0.f, q = 0.f;
  long i = tid;
  for (; i + 3*stride < total; i += 4*stride){
    float v0 = bf2f(buf[i]);
    float v1 = bf2f(buf[i +   stride]);
    float v2 = bf2f(buf[i + 2*stride]);
    float v3 = bf2f(buf[i + 3*stride]);
    s += (v0 + v1) + (v2 + v3);
    q += (v0*v0 + v1*v1) + (v2*v2 + v3*v3);
  }
  for (; i < total; i += stride){ float v = bf2f(buf[i]); s += v; q += v*v; }
  int r = (tid >> 6) & 63;
  atomicAdd(&repl[r*256 + c], s);
  atomicAdd(&repl[r*256 + 128 + c], q);
}

// ---------- pool ----------
__global__ void k_pool(const unsigned short* __restrict__ y5, const void* __restrict__ batch, int N,
                       const int* dmode, const float* __restrict__ ss5, unsigned int* __restrict__ pooled){
  int m64 = dmode[0];
  int c = threadIdx.x;               // 128 threads
  int n0 = blockIdx.x*512;
  int n1 = min(n0 + 512, N);
  float sc = ss5[c], sh = ss5[128 + c];
  int curb = -1; float curm = 0.f;
  for (int n = n0; n < n1; n++){
    int b = clampi(ld_idx(batch, (long)n, m64), 0, 63);
    float v = fmaf(bf2f(y5[(size_t)n*128 + c]), sc, sh);
    if (b != curb){
      if (curb >= 0) atomicMax(&pooled[curb*128 + c], __float_as_uint(fmaxf(curm, 0.f)));
      curb = b; curm = v;
    } else {
      curm = fmaxf(curm, v);
    }
  }
  if (curb >= 0) atomicMax(&pooled[curb*128 + c], __float_as_uint(fmaxf(curm, 0.f)));
}

// ---------- head ----------
__global__ void k_pooled2f(const unsigned int* __restrict__ pooled, float* __restrict__ pf){
  int i = blockIdx.x*256 + threadIdx.x;
  if (i < 8192) pf[i] = __uint_as_float(pooled[i]);
}

__global__ void k_linH(const float* __restrict__ X, const float* __restrict__ W,
                       const float* __restrict__ b, int CI, int CO, float* __restrict__ Y){
  int cell = blockIdx.x*256 + threadIdx.x;
  if (cell >= 64*CO) return;
  int r = cell / CO, c = cell - r*CO;
  const float* xr = X + r*CI;
  const float* wr = W + c*CI;
  float a = b[c];
  for (int j = 0; j < CI; j++) a = fmaf(xr[j], wr[j], a);
  Y[cell] = a;
}

__global__ void k_bnH(const float* __restrict__ Y, int CO,
                      const float* __restrict__ g, const float* __restrict__ be,
                      float* __restrict__ ss){
  int c = threadIdx.x;
  if (c >= CO) return;
  float s = 0.f;
  for (int r = 0; r < 64; r++) s += Y[r*CO + c];
  float mean = s * (1.f/64.f);
  float q = 0.f;
  for (int r = 0; r < 64; r++){ float d = Y[r*CO + c] - mean; q += d*d; }
  float var = fmaxf(q * (1.f/64.f), 0.f);
  float inv = rsqrtf(var + EPS_BN);
  float sc = g[c] * inv;
  ss[c] = sc;
  ss[CO + c] = be[c] - mean*sc;
}

__global__ void k_bnreluH(float* __restrict__ Y, int CO, const float* __restrict__ ss){
  int cell = blockIdx.x*256 + threadIdx.x;
  if (cell >= 64*CO) return;
  int c = cell % CO;
  Y[cell] = fmaxf(fmaf(Y[cell], ss[c], ss[CO + c]), 0.f);
}

__global__ void k_logsm(const float* __restrict__ Z, float* __restrict__ out){
  int r = threadIdx.x;   // 64 threads
  const float* zr = Z + r*40;
  float m = zr[0];
  for (int c = 1; c < 40; c++) m = fmaxf(m, zr[c]);
  float s = 0.f;
  for (int c = 0; c < 40; c++) s += expf(zr[c] - m);
  float ls = logf(s);
  for (int c = 0; c < 40; c++) out[r*40 + c] = zr[c] - m - ls;
}

// ---------- launch ----------
extern "C" void kernel_launch(void* const* d_in, const int* in_sizes, int n_in,
                              void* d_out, int out_size, void* d_ws, size_t ws_size,
                              hipStream_t stream) {
  const void* pos   = d_in[0];
  const void* ei    = d_in[1];
  const void* batch = d_in[2];
  (void)n_in;

  const int N = in_sizes[0] / 3;
  const int E = in_sizes[1] / 2;
  const int nTiles = cdiv(E, 64);

  // ---- workspace layout ----
  auto al = [](size_t x){ return (x + 255) & ~(size_t)255; };
  char* w = (char*)d_ws;
  size_t o = 0;
  float* repl = (float*)(w + o);                 o += (size_t)64*256*4;
  unsigned int* pooled = (unsigned int*)(w + o); o += (size_t)64*128*4;
  int* deg = (int*)(w + o);                      o += al((size_t)4*N);
  size_t zero_bytes = o;
  int* dmode = (int*)(w + o);                    o += 256;
  int* offs = (int*)(w + o);                     o += al((size_t)4*(N + 1));
  int* cursor = (int*)(w + o);                   o += al((size_t)4*N);
  int* part = (int*)(w + o);                     o += 4096;
  int* bucket = (int*)(w + o);                   o += al((size_t)4*E);
  float* ss1 = (float*)(w + o);                  o += 1024;
  float* ss2 = (float*)(w + o);                  o += 1024;
  float* ss3 = (float*)(w + o);                  o += 1024;
  float* ss4 = (float*)(w + o);                  o += 1024;
  float* ss5 = (float*)(w + o);                  o += 1024;
  float* ssH = (float*)(w + o);                  o += 1024;
  float* Wa = (float*)(w + o);                   o += (size_t)4096*4;
  float* Wb = (float*)(w + o);                   o += (size_t)4096*4;
  float* pooledF = (float*)(w + o);              o += (size_t)8192*4;
  float* Y6 = (float*)(w + o);                   o += (size_t)8192*4;
  float* Y7 = (float*)(w + o);                   o += (size_t)8192*4;
  float* Zl = (float*)(w + o);                   o += al((size_t)2560*4);
  // fp32 expansion region
  float* expBase = (float*)(w + o);
  float* ep = expBase;
  float* epos = ep; ep += (size_t)3*N;
  float* eW[9], *eb[9], *eg[9], *ebe[9];
  const int wsz[9] = {0, 64*6, 64*64, 64*64, 64*128, 128*128, 128*128, 128*128, 40*128};
  const int bsz[9] = {0, 64, 64, 64, 64, 128, 128, 128, 40};
  for (int i = 1; i <= 8; i++){
    eW[i] = ep; ep += wsz[i];
    eb[i] = ep; ep += bsz[i];
    if (i < 8){ eg[i] = ep; ep += bsz[i]; ebe[i] = ep; ep += bsz[i]; }
  }
  long expCount = (long)(ep - expBase);
  o += al((size_t)expCount * 4);
  unsigned short* x1b = (unsigned short*)(w + o); o += al((size_t)2*64*N);
  unsigned short* x2b = (unsigned short*)(w + o); o += al((size_t)2*64*N);
  unsigned short* y5b = (unsigned short*)(w + o); o += al((size_t)2*128*N);
  unsigned short* mbuf = (unsigned short*)(w + o); o += al((size_t)8192*nTiles);
  uint4* mbuf4 = (uint4*)mbuf;

  float* out_f = (float*)d_out;
  if (ws_size < o){
    k_sentinel<<<cdiv(out_size,256), 256, 0, stream>>>(out_f, out_size);
    return;
  }

  hipMemsetAsync(w, 0, zero_bytes, stream);
  k_detect<<<1, 256, 0, stream>>>(ei, pos, dmode);

  // expand all float inputs -> fp32
  ExpArgs ea;
  int it = 0;
  ea.it[it++] = {pos, epos, 3*N};
  int di_idx = 3;
  for (int i = 1; i <= 8; i++){
    ea.it[it++] = {d_in[di_idx++], eW[i], wsz[i]};
    ea.it[it++] = {d_in[di_idx++], eb[i], bsz[i]};
    if (i < 8){
      ea.it[it++] = {d_in[di_idx++], eg[i], bsz[i]};
      ea.it[it++] = {d_in[di_idx++], ebe[i], bsz[i]};
    }
  }
  k_expand<<<dim3(cdiv(3*N,256), 31), 256, 0, stream>>>(ea, it, dmode);
  k_prepW4<<<16, 256, 0, stream>>>(eW[4], Wa, Wb);

  const int nb = cdiv(N, 1024);
  // CSR build
  k_hist<<<cdiv(E,256), 256, 0, stream>>>(ei, E, N, dmode, deg);
  k_scan1<<<nb, 1024, 0, stream>>>(deg, N, offs, part);
  k_scan2<<<1, 1024, 0, stream>>>(part, nb);
  k_scan3<<<nb, 1024, 0, stream>>>(deg, part, N, E, offs, cursor);
  k_fill<<<cdiv(E,256), 256, 0, stream>>>(ei, E, N, dmode, cursor, bucket);

  // conv1 (fused stats; edges in bucket order)
  k_m1stats<<<cdiv(E,2048), 256, 0, stream>>>(epos, ei, E, N, dmode, eW[1], eb[1], repl);
  k_finalize<<<1, 128, 0, stream>>>(repl, 64, (float)E, eg[1], ebe[1], ss1);
  k_conv1_l2<<<cdiv(E,256), 256, 0, stream>>>(epos, ei, bucket, E, N, dmode,
                                              eW[1], eb[1], ss1, eW[2], eb[2], mbuf4, repl);
  k_finalize<<<1, 128, 0, stream>>>(repl, 64, (float)E, eg[2], ebe[2], ss2);
  k_conv1_l3<<<cdiv(E,256), 256, 0, stream>>>(mbuf4, E, ss2, eW[3], eb[3], repl);
  k_finalize<<<1, 128, 0, stream>>>(repl, 64, (float)E, eg[3], ebe[3], ss3);
  k_aggregate<<<cdiv(N,4), 256, 0, stream>>>(mbuf, offs, N, E, ss3, x1b);

  // conv2
  k_conv2<<<cdiv(E,256), 256, 0, stream>>>(x1b, ei, bucket, E, N, dmode, Wa, Wb, eb[4], mbuf4, repl);
  k_finalize<<<1, 128, 0, stream>>>(repl, 64, (float)E, eg[4], ebe[4], ss4);
  k_aggregate<<<cdiv(N,4), 256, 0, stream>>>(mbuf, offs, N, E, ss4, x2b);

  // lin5 + BN5 stats + pool
  k_lin5<<<cdiv(N,16), 256, 0, stream>>>(x1b, x2b, N, eW[5], eb[5], y5b);
  k_stats_bf16<<<512, 256, 0, stream>>>(y5b, (long)N*128, 127, repl);
  k_finalize<<<1, 128, 0, stream>>>(repl, 128, (float)N, eg[5], ebe[5], ss5);
  k_pool<<<cdiv(N,512), 128, 0, stream>>>(y5b, batch, N, dmode, ss5, pooled);

  // head
  k_pooled2f<<<32, 256, 0, stream>>>(pooled, pooledF);
  k_linH<<<32, 256, 0, stream>>>(pooledF, eW[6], eb[6], 128, 128, Y6);
  k_bnH<<<1, 128, 0, stream>>>(Y6, 128, eg[6], ebe[6], ssH);
  k_bnreluH<<<32, 256, 0, stream>>>(Y6, 128, ssH);
  k_linH<<<32, 256, 0, stream>>>(Y6, eW[7], eb[7], 128, 128, Y7);
  k_bnH<<<1, 128, 0, stream>>>(Y7, 128, eg[7], ebe[7], ssH);
  k_bnreluH<<<32, 256, 0, stream>>>(Y7, 128, ssH);
  k_linH<<<10, 256, 0, stream>>>(Y7, eW[8], eb[8], 128, 40, Zl);
  k_logsm<<<1, 64, 0, stream>>>(Zl, out_f);
}

// Round 10
// 11133.013 us; speedup vs baseline: 1.1300x; 1.0001x over previous
//
#include <hip/hip_runtime.h>
#include <math.h>

#define EPS_BN 1e-5f

// Wire formats (established r0-r8): float inputs = bf16 (runtime-detected),
// int inputs = int32/int64 (runtime-detected), OUTPUT = FP32.
// mbuf layout: [tile=64 edges][8 chunks][64 edge-slots][16B]; edges in CSR-bucket order.
// r10: k_conv2 stages random xj rows in LDS via cooperative gather (8 rows per
// load instruction) -- kills the 8x-rematerialized random global re-reads.

// ---------- helpers ----------
static __device__ __forceinline__ float bf2f(unsigned short b){
  return __uint_as_float(((unsigned)b) << 16);
}
static __device__ __forceinline__ unsigned short f2bf(float f){
  unsigned u = __float_as_uint(f);
  u += 0x7fffu + ((u >> 16) & 1u);   // RNE (finite values only)
  return (unsigned short)(u >> 16);
}
static inline int cdiv(int a, int b){ return (a + b - 1) / b; }
static __device__ __forceinline__ int clampi(int v, int lo, int hi){
  return v < lo ? lo : (v > hi ? hi : v);
}
static __device__ __forceinline__ int ld_idx(const void* p, long e, int m64){
  return m64 ? (int)((const long long*)p)[e] : ((const int*)p)[e];
}
static __device__ __forceinline__ uint4 pack8(const float* acc){
  uint4 u;
  u.x = ((unsigned)f2bf(acc[1]) << 16) | (unsigned)f2bf(acc[0]);
  u.y = ((unsigned)f2bf(acc[3]) << 16) | (unsigned)f2bf(acc[2]);
  u.z = ((unsigned)f2bf(acc[5]) << 16) | (unsigned)f2bf(acc[4]);
  u.w = ((unsigned)f2bf(acc[7]) << 16) | (unsigned)f2bf(acc[6]);
  return u;
}
// butterfly-reduce s,q over 64 lanes; lane j commits channel c
static __device__ __forceinline__ void stat_commit(float v, int valid, int lane, int j,
                                                   float* repl, int r, int c){
  float s = valid ? v : 0.f;
  float q = s * s;
  #pragma unroll
  for (int m = 1; m < 64; m <<= 1){ s += __shfl_xor(s, m, 64); q += __shfl_xor(q, m, 64); }
  if (lane == j){
    atomicAdd(&repl[r*256 + c], s);
    atomicAdd(&repl[r*256 + 128 + c], q);
  }
}

// ---------- sentinel ----------
__global__ void k_sentinel(float* out, int n){
  int i = blockIdx.x*256 + threadIdx.x;
  if (i < n) out[i] = -12288.0f;
}

// ---------- runtime dtype detection ----------
__global__ void k_detect(const void* ei, const void* pos, int* dmode){
  __shared__ int nz, ff;
  if (threadIdx.x == 0){ nz = 0; ff = 0; }
  __syncthreads();
  const int* w32 = (const int*)ei;
  if (w32[1 + 2*threadIdx.x] != 0) nz = 1;
  const unsigned short* ph = (const unsigned short*)pos;
  int bad = 0;
  for (int i = threadIdx.x; i < 8192; i += 256)
    if (((ph[i] >> 7) & 0xFF) == 0xFF) bad = 1;
  if (bad) ff = 1;
  __syncthreads();
  if (threadIdx.x == 0){ dmode[0] = nz ? 0 : 1; dmode[1] = ff; }
}

// ---------- expand float inputs -> fp32 scratch ----------
struct ExpItem { const void* s; float* d; int n; };
struct ExpArgs { ExpItem it[31]; };
__global__ void k_expand(ExpArgs a, int cnt, const int* dmode){
  int i = blockIdx.y;
  if (i >= cnt) return;
  int m32 = dmode[1];
  int t = blockIdx.x*256 + threadIdx.x;
  if (t < a.it[i].n){
    a.it[i].d[t] = m32 ? ((const float*)a.it[i].s)[t]
                       : bf2f(((const unsigned short*)a.it[i].s)[t]);
  }
}

// ---------- W4 split ----------
__global__ void k_prepW4(const float* __restrict__ W4, float* __restrict__ Wa, float* __restrict__ Wb){
  int i = blockIdx.x*256 + threadIdx.x;
  if (i < 4096){
    int c = i >> 6, k = i & 63;
    float a = W4[c*128 + k], b = W4[c*128 + 64 + k];
    Wa[i] = a - b;
    Wb[i] = b;
  }
}

// ---------- CSR build ----------
__global__ void k_hist(const void* __restrict__ ei, int E, int N, const int* dmode, int* __restrict__ deg){
  int m64 = dmode[0];
  int e = blockIdx.x*256 + threadIdx.x;
  if (e < E) atomicAdd(&deg[clampi(ld_idx(ei, (long)E + e, m64), 0, N-1)], 1);
}

__global__ void k_scan1(const int* __restrict__ deg, int N, int* __restrict__ incl, int* __restrict__ part){
  __shared__ int s[1024];
  int i = blockIdx.x*1024 + threadIdx.x;
  s[threadIdx.x] = (i < N) ? deg[i] : 0;
  __syncthreads();
  for (int off = 1; off < 1024; off <<= 1){
    int t = (threadIdx.x >= off) ? s[threadIdx.x - off] : 0;
    __syncthreads();
    s[threadIdx.x] += t;
    __syncthreads();
  }
  if (i < N) incl[i] = s[threadIdx.x];
  if (threadIdx.x == 1023) part[blockIdx.x] = s[1023];
}

__global__ void k_scan2(int* __restrict__ part, int nb){
  __shared__ int s[1024];
  int i = threadIdx.x;
  s[i] = (i < nb) ? part[i] : 0;
  __syncthreads();
  for (int off = 1; off < 1024; off <<= 1){
    int t = (i >= off) ? s[i - off] : 0;
    __syncthreads();
    s[i] += t;
    __syncthreads();
  }
  if (i < nb) part[i] = s[i];
}

__global__ void k_scan3(const int* __restrict__ deg, const int* __restrict__ part, int N, int E,
                        int* __restrict__ offs, int* __restrict__ cursor){
  int i = blockIdx.x*1024 + threadIdx.x;
  if (i < N){
    int prev = (blockIdx.x > 0) ? part[blockIdx.x - 1] : 0;
    int v = prev + offs[i] - deg[i];
    offs[i] = v;
    cursor[i] = v;
  }
  if (blockIdx.x == 0 && threadIdx.x == 0) offs[N] = E;
}

__global__ void k_fill(const void* __restrict__ ei, int E, int N, const int* dmode,
                       int* __restrict__ cursor, int* __restrict__ bucket){
  int m64 = dmode[0];
  int e = blockIdx.x*256 + threadIdx.x;
  if (e < E){
    int p = atomicAdd(&cursor[clampi(ld_idx(ei, (long)E + e, m64), 0, N-1)], 1);
    if (p >= 0 && p < E) bucket[p] = e;
  }
}

// ---------- conv1 layer1 stats ----------
__global__ void k_m1stats(const float* __restrict__ pos, const void* __restrict__ ei,
                          int E, int N, const int* dmode,
                          const float* __restrict__ W1, const float* __restrict__ b1,
                          float* __restrict__ repl){
  int m64 = dmode[0];
  int lane = threadIdx.x & 63;
  int flatwave = (blockIdx.x*256 + threadIdx.x) >> 6;
  long base = (long)flatwave * 512;
  float as[64], aq[64];
  #pragma unroll
  for (int c = 0; c < 64; c++){ as[c] = 0.f; aq[c] = 0.f; }
  for (int k = 0; k < 8; k++){
    long e = base + (long)k*64 + lane;
    if (e < E){
      int si = clampi(ld_idx(ei, e, m64), 0, N-1);
      int di = clampi(ld_idx(ei, (long)E + e, m64), 0, N-1);
      float x0 = pos[di*3+0], x1 = pos[di*3+1], x2 = pos[di*3+2];
      float j0 = pos[si*3+0]-x0, j1 = pos[si*3+1]-x1, j2 = pos[si*3+2]-x2;
      #pragma unroll
      for (int c = 0; c < 64; c++){
        float m = b1[c];
        m = fmaf(x0, W1[c*6+0], m); m = fmaf(x1, W1[c*6+1], m); m = fmaf(x2, W1[c*6+2], m);
        m = fmaf(j0, W1[c*6+3], m); m = fmaf(j1, W1[c*6+4], m); m = fmaf(j2, W1[c*6+5], m);
        as[c] += m; aq[c] += m*m;
      }
    }
  }
  float outs = 0.f, outq = 0.f;
  #pragma unroll
  for (int c = 0; c < 64; c++){
    float s = as[c], q = aq[c];
    #pragma unroll
    for (int m = 1; m < 64; m <<= 1){ s += __shfl_xor(s, m, 64); q += __shfl_xor(q, m, 64); }
    if (lane == c){ outs = s; outq = q; }
  }
  int r = flatwave & 63;
  atomicAdd(&repl[r*256 + lane], outs);
  atomicAdd(&repl[r*256 + 128 + lane], outq);
}

// ---------- finalize BN ----------
__global__ void k_finalize(float* __restrict__ repl, int C, float count,
                           const float* __restrict__ g, const float* __restrict__ be,
                           float* __restrict__ ss){
  int c = threadIdx.x;
  if (c < C){
    float s = 0.f, q = 0.f;
    for (int r = 0; r < 64; r++){
      s += repl[r*256 + c];       repl[r*256 + c] = 0.f;
      q += repl[r*256 + 128 + c]; repl[r*256 + 128 + c] = 0.f;
    }
    float mean = s / count;
    float var  = fmaxf(q / count - mean*mean, 0.f);
    float inv  = rsqrtf(var + EPS_BN);
    float sc   = g[c] * inv;
    ss[c]     = sc;
    ss[C + c] = be[c] - mean*sc;
  }
}

// ---------- conv1 l2: bucket order, tiled store, fused stats ----------
__global__ void k_conv1_l2(const float* __restrict__ pos, const void* __restrict__ ei,
                           const int* __restrict__ bucket, int E, int N, const int* dmode,
                           const float* __restrict__ W1, const float* __restrict__ b1,
                           const float* __restrict__ ss1,
                           const float* __restrict__ W2, const float* __restrict__ b2,
                           uint4* __restrict__ mbuf4, float* __restrict__ repl){
  int m64 = dmode[0];
  int t = blockIdx.x*256 + threadIdx.x;
  int lane = threadIdx.x & 63;
  int valid = (t < E);
  int p = valid ? bucket[t] : 0;
  int si = clampi(ld_idx(ei, (long)p, m64), 0, N-1);
  int di = clampi(ld_idx(ei, (long)E + p, m64), 0, N-1);
  float x0 = pos[di*3+0], x1 = pos[di*3+1], x2 = pos[di*3+2];
  float j0 = pos[si*3+0]-x0, j1 = pos[si*3+1]-x1, j2 = pos[si*3+2]-x2;
  float z[64];
  #pragma unroll
  for (int c = 0; c < 64; c++){
    float m = b1[c];
    m = fmaf(x0, W1[c*6+0], m); m = fmaf(x1, W1[c*6+1], m); m = fmaf(x2, W1[c*6+2], m);
    m = fmaf(j0, W1[c*6+3], m); m = fmaf(j1, W1[c*6+4], m); m = fmaf(j2, W1[c*6+5], m);
    z[c] = fmaxf(fmaf(m, ss1[c], ss1[64 + c]), 0.f);
  }
  int tt = valid ? t : 0;
  uint4* obase = mbuf4 + (((size_t)(tt >> 6)) << 9) + (tt & 63);
  int r = ((blockIdx.x*256 + threadIdx.x) >> 6) & 63;
  for (int c0 = 0; c0 < 64; c0 += 8){
    float acc[8];
    #pragma unroll
    for (int j = 0; j < 8; j++) acc[j] = b2[c0 + j];
    #pragma unroll
    for (int i = 0; i < 64; i++){
      float zi = z[i];
      #pragma unroll
      for (int j = 0; j < 8; j++) acc[j] = fmaf(zi, W2[(c0 + j)*64 + i], acc[j]);
    }
    #pragma unroll
    for (int j = 0; j < 8; j++) stat_commit(acc[j], valid, lane, j, repl, r, c0 + j);
    if (valid) obase[(size_t)(c0 << 3)] = pack8(acc);
  }
}

// ---------- conv1 l3: tiled in-place, fused stats ----------
__global__ void k_conv1_l3(uint4* __restrict__ mbuf4, int E,
                           const float* __restrict__ ss, const float* __restrict__ W3,
                           const float* __restrict__ b3, float* __restrict__ repl){
  int t = blockIdx.x*256 + threadIdx.x;
  int lane = threadIdx.x & 63;
  int valid = (t < E);
  int tt = valid ? t : 0;
  uint4* base = mbuf4 + (((size_t)(tt >> 6)) << 9) + (tt & 63);
  uint4 u[8];
  #pragma unroll
  for (int k = 0; k < 8; k++) u[k] = base[(size_t)(k << 6)];
  float z[64];
  #pragma unroll
  for (int k = 0; k < 8; k++){
    unsigned vals[4] = {u[k].x, u[k].y, u[k].z, u[k].w};
    #pragma unroll
    for (int q = 0; q < 4; q++){
      int c = k*8 + q*2;
      float lo = __uint_as_float(vals[q] << 16);
      float hi = __uint_as_float(vals[q] & 0xffff0000u);
      z[c]   = fmaxf(fmaf(lo, ss[c],   ss[64 + c]),   0.f);
      z[c+1] = fmaxf(fmaf(hi, ss[c+1], ss[64 + c+1]), 0.f);
    }
  }
  int r = ((blockIdx.x*256 + threadIdx.x) >> 6) & 63;
  for (int c0 = 0; c0 < 64; c0 += 8){
    float acc[8];
    #pragma unroll
    for (int j = 0; j < 8; j++) acc[j] = b3[c0 + j];
    #pragma unroll
    for (int i = 0; i < 64; i++){
      float zi = z[i];
      #pragma unroll
      for (int j = 0; j < 8; j++) acc[j] = fmaf(zi, W3[(c0 + j)*64 + i], acc[j]);
    }
    #pragma unroll
    for (int j = 0; j < 8; j++) stat_commit(acc[j], valid, lane, j, repl, r, c0 + j);
    if (valid) base[(size_t)(c0 << 3)] = pack8(acc);
  }
}

// ---------- aggregate: sequential CSR rows in tiled layout ----------
__global__ void k_aggregate(const unsigned short* __restrict__ mbuf,
                            const int* __restrict__ offs, int N, int E,
                            const float* __restrict__ ss, unsigned short* __restrict__ xout){
  int wave = threadIdx.x >> 6;
  int lane = threadIdx.x & 63;
  int n = blockIdx.x*4 + wave;
  if (n >= N) return;
  int s0 = clampi(offs[n], 0, E);
  int s1 = clampi(offs[n + 1], s0, E);
  float sc = ss[lane], sh = ss[64 + lane];
  int g = lane >> 3, pz = lane & 7;
  float acc = 0.f;
  for (int k = s0; k < s1; k++){
    size_t idx = (((size_t)(k >> 6)) << 12) + (g << 9) + ((k & 63) << 3) + pz;
    float v = bf2f(mbuf[idx]);
    acc = fmaxf(acc, fmaf(v, sc, sh));
  }
  xout[(size_t)n*64 + lane] = f2bf(acc);
}

// ---------- unpack row-major 64-wide bf16 row ----------
static __device__ __forceinline__ void unpack_row64(const unsigned short* row, float* v){
  const uint4* r4 = (const uint4*)row;
  #pragma unroll
  for (int k = 0; k < 8; k++){
    uint4 u = r4[k];
    unsigned w[4] = {u.x, u.y, u.z, u.w};
    #pragma unroll
    for (int q = 0; q < 4; q++){
      v[k*8 + q*2]     = __uint_as_float(w[q] << 16);
      v[k*8 + q*2 + 1] = __uint_as_float(w[q] & 0xffff0000u);
    }
  }
}

// ---------- conv2: LDS-staged xj gather (cooperative, 8 rows/instruction) ----------
__global__ void k_conv2(const unsigned short* __restrict__ x1, const void* __restrict__ ei,
                        const int* __restrict__ bucket, int E, int N, const int* dmode,
                        const float* __restrict__ Wa, const float* __restrict__ Wb,
                        const float* __restrict__ b4, uint4* __restrict__ mbuf4,
                        float* __restrict__ repl){
  __shared__ __align__(16) unsigned short xjs[4][64][68];  // stride 68: 2-way bank alias = free
  __shared__ int sis[4][64];
  int m64 = dmode[0];
  int wv = threadIdx.x >> 6, lane = threadIdx.x & 63;
  int t = blockIdx.x*256 + threadIdx.x;
  int valid = (t < E);
  int p = valid ? bucket[t] : 0;
  int si = clampi(ld_idx(ei, (long)p, m64), 0, N-1);
  int di = clampi(ld_idx(ei, (long)E + p, m64), 0, N-1);
  sis[wv][lane] = si;
  __syncthreads();
  // cooperative gather: pass r loads rows r*8..r*8+7; 8 lanes per row, 16B each
  int rl = lane >> 3, ch = lane & 7;
  #pragma unroll
  for (int r = 0; r < 8; r++){
    int row = sis[wv][r*8 + rl];
    uint4 v = *(const uint4*)(x1 + (size_t)row*64 + ch*8);
    unsigned short* dp = &xjs[wv][r*8 + rl][ch*8];
    *(uint2*)(dp)     = make_uint2(v.x, v.y);
    *(uint2*)(dp + 4) = make_uint2(v.z, v.w);
  }
  __syncthreads();
  float xi[64], xj[64];
  unpack_row64(x1 + (size_t)di*64, xi);   // dst-sequential: L1/L2-hot
  {
    const unsigned short* xr = xjs[wv][lane];
    #pragma unroll
    for (int k = 0; k < 8; k++){
      uint2 a = *(const uint2*)(xr + k*8);
      uint2 b = *(const uint2*)(xr + k*8 + 4);
      xj[k*8+0] = __uint_as_float(a.x << 16);
      xj[k*8+1] = __uint_as_float(a.x & 0xffff0000u);
      xj[k*8+2] = __uint_as_float(a.y << 16);
      xj[k*8+3] = __uint_as_float(a.y & 0xffff0000u);
      xj[k*8+4] = __uint_as_float(b.x << 16);
      xj[k*8+5] = __uint_as_float(b.x & 0xffff0000u);
      xj[k*8+6] = __uint_as_float(b.y << 16);
      xj[k*8+7] = __uint_as_float(b.y & 0xffff0000u);
    }
  }
  int tt = valid ? t : 0;
  uint4* obase = mbuf4 + (((size_t)(tt >> 6)) << 9) + (tt & 63);
  int r2 = (t >> 6) & 63;
  for (int c0 = 0; c0 < 64; c0 += 8){
    float acc[8];
    #pragma unroll
    for (int j = 0; j < 8; j++) acc[j] = b4[c0 + j];
    #pragma unroll
    for (int i = 0; i < 64; i++){
      float a = xi[i], b = xj[i];
      #pragma unroll
      for (int j = 0; j < 8; j++){
        acc[j] = fmaf(a, Wa[(c0 + j)*64 + i], acc[j]);
        acc[j] = fmaf(b, Wb[(c0 + j)*64 + i], acc[j]);
      }
    }
    #pragma unroll
    for (int j = 0; j < 8; j++) stat_commit(acc[j], valid, lane, j, repl, r2, c0 + j);
    if (valid) obase[(size_t)(c0 << 3)] = pack8(acc);
  }
}

// ---------- lin5: 16 nodes x 16 col-groups per block, LDS-staged inputs ----------
__global__ void k_lin5(const unsigned short* __restrict__ x1, const unsigned short* __restrict__ x2,
                       int N, const float* __restrict__ W5, const float* __restrict__ b5,
                       unsigned short* __restrict__ y5){
  __shared__ float xs[16][130];
  int t = threadIdx.x;            // 256
  int nb0 = blockIdx.x * 16;
  {
    int row = t >> 4, col4 = (t & 15) * 4;
    if (nb0 + row < N){
      uint2 a = *(const uint2*)(x1 + (size_t)(nb0 + row)*64 + col4);
      uint2 b = *(const uint2*)(x2 + (size_t)(nb0 + row)*64 + col4);
      xs[row][col4+0] = __uint_as_float(a.x << 16);
      xs[row][col4+1] = __uint_as_float(a.x & 0xffff0000u);
      xs[row][col4+2] = __uint_as_float(a.y << 16);
      xs[row][col4+3] = __uint_as_float(a.y & 0xffff0000u);
      xs[row][64+col4+0] = __uint_as_float(b.x << 16);
      xs[row][64+col4+1] = __uint_as_float(b.x & 0xffff0000u);
      xs[row][64+col4+2] = __uint_as_float(b.y << 16);
      xs[row][64+col4+3] = __uint_as_float(b.y & 0xffff0000u);
    } else {
      #pragma unroll
      for (int q = 0; q < 4; q++){ xs[row][col4+q] = 0.f; xs[row][64+col4+q] = 0.f; }
    }
  }
  __syncthreads();
  int node = t >> 4, cg = t & 15;
  int n = nb0 + node;
  const float* xr = xs[node];
  const float* wbase = W5 + (size_t)(cg*8)*128;
  float acc[8];
  #pragma unroll
  for (int j = 0; j < 8; j++) acc[j] = b5[cg*8 + j];
  for (int i = 0; i < 128; i++){
    float xv = xr[i];
    #pragma unroll
    for (int j = 0; j < 8; j++) acc[j] = fmaf(xv, wbase[j*128 + i], acc[j]);
  }
  if (n < N) *(uint4*)(y5 + (size_t)n*128 + cg*8) = pack8(acc);
}

// ---------- column stats over row-major bf16 (y5 only) ----------
__global__ void k_stats_bf16(const unsigned short* __restrict__ buf, long total, int cmask,
                             float* __restrict__ repl){
  int tid = blockIdx.x*256 + threadIdx.x;
  int c = tid & cmask;
  long stride = (long)gridDim.x * 256;
  float s = 0.f, q = 0.f;
  long i = tid;
  for (; i + 3*stride < total; i += 4*stride){
    float v0 = bf2f(buf[i]);
    float v1 = bf2f(buf[i +   stride]);
    float v2 = bf2f(buf[i + 2*stride]);
    float v3 = bf2f(buf[i + 3*stride]);
    s += (v0 + v1) + (v2 + v3);
    q += (v0*v0 + v1*v1) + (v2*v2 + v3*v3);
  }
  for (; i < total; i += stride){ float v = bf2f(buf[i]); s += v; q += v*v; }
  int r = (tid >> 6) & 63;
  atomicAdd(&repl[r*256 + c], s);
  atomicAdd(&repl[r*256 + 128 + c], q);
}

// ---------- pool ----------
__global__ void k_pool(const unsigned short* __restrict__ y5, const void* __restrict__ batch, int N,
                       const int* dmode, const float* __restrict__ ss5, unsigned int* __restrict__ pooled){
  int m64 = dmode[0];
  int c = threadIdx.x;               // 128 threads
  int n0 = blockIdx.x*512;
  int n1 = min(n0 + 512, N);
  float sc = ss5[c], sh = ss5[128 + c];
  int curb = -1; float curm = 0.f;
  for (int n = n0; n < n1; n++){
    int b = clampi(ld_idx(batch, (long)n, m64), 0, 63);
    float v = fmaf(bf2f(y5[(size_t)n*128 + c]), sc, sh);
    if (b != curb){
      if (curb >= 0) atomicMax(&pooled[curb*128 + c], __float_as_uint(fmaxf(curm, 0.f)));
      curb = b; curm = v;
    } else {
      curm = fmaxf(curm, v);
    }
  }
  if (curb >= 0) atomicMax(&pooled[curb*128 + c], __float_as_uint(fmaxf(curm, 0.f)));
}

// ---------- head ----------
__global__ void k_pooled2f(const unsigned int* __restrict__ pooled, float* __restrict__ pf){
  int i = blockIdx.x*256 + threadIdx.x;
  if (i < 8192) pf[i] = __uint_as_float(pooled[i]);
}

__global__ void k_linH(const float* __restrict__ X, const float* __restrict__ W,
                       const float* __restrict__ b, int CI, int CO, float* __restrict__ Y){
  int cell = blockIdx.x*256 + threadIdx.x;
  if (cell >= 64*CO) return;
  int r = cell / CO, c = cell - r*CO;
  const float* xr = X + r*CI;
  const float* wr = W + c*CI;
  float a = b[c];
  for (int j = 0; j < CI; j++) a = fmaf(xr[j], wr[j], a);
  Y[cell] = a;
}

__global__ void k_bnH(const float* __restrict__ Y, int CO,
                      const float* __restrict__ g, const float* __restrict__ be,
                      float* __restrict__ ss){
  int c = threadIdx.x;
  if (c >= CO) return;
  float s = 0.f;
  for (int r = 0; r < 64; r++) s += Y[r*CO + c];
  float mean = s * (1.f/64.f);
  float q = 0.f;
  for (int r = 0; r < 64; r++){ float d = Y[r*CO + c] - mean; q += d*d; }
  float var = fmaxf(q * (1.f/64.f), 0.f);
  float inv = rsqrtf(var + EPS_BN);
  float sc = g[c] * inv;
  ss[c] = sc;
  ss[CO + c] = be[c] - mean*sc;
}

__global__ void k_bnreluH(float* __restrict__ Y, int CO, const float* __restrict__ ss){
  int cell = blockIdx.x*256 + threadIdx.x;
  if (cell >= 64*CO) return;
  int c = cell % CO;
  Y[cell] = fmaxf(fmaf(Y[cell], ss[c], ss[CO + c]), 0.f);
}

__global__ void k_logsm(const float* __restrict__ Z, float* __restrict__ out){
  int r = threadIdx.x;   // 64 threads
  const float* zr = Z + r*40;
  float m = zr[0];
  for (int c = 1; c < 40; c++) m = fmaxf(m, zr[c]);
  float s = 0.f;
  for (int c = 0; c < 40; c++) s += expf(zr[c] - m);
  float ls = logf(s);
  for (int c = 0; c < 40; c++) out[r*40 + c] = zr[c] - m - ls;
}

// ---------- launch ----------
extern "C" void kernel_launch(void* const* d_in, const int* in_sizes, int n_in,
                              void* d_out, int out_size, void* d_ws, size_t ws_size,
                              hipStream_t stream) {
  const void* pos   = d_in[0];
  const void* ei    = d_in[1];
  const void* batch = d_in[2];
  (void)n_in;

  const int N = in_sizes[0] / 3;
  const int E = in_sizes[1] / 2;
  const int nTiles = cdiv(E, 64);

  // ---- workspace layout ----
  auto al = [](size_t x){ return (x + 255) & ~(size_t)255; };
  char* w = (char*)d_ws;
  size_t o = 0;
  float* repl = (float*)(w + o);                 o += (size_t)64*256*4;
  unsigned int* pooled = (unsigned int*)(w + o); o += (size_t)64*128*4;
  int* deg = (int*)(w + o);                      o += al((size_t)4*N);
  size_t zero_bytes = o;
  int* dmode = (int*)(w + o);                    o += 256;
  int* offs = (int*)(w + o);                     o += al((size_t)4*(N + 1));
  int* cursor = (int*)(w + o);                   o += al((size_t)4*N);
  int* part = (int*)(w + o);                     o += 4096;
  int* bucket = (int*)(w + o);                   o += al((size_t)4*E);
  float* ss1 = (float*)(w + o);                  o += 1024;
  float* ss2 = (float*)(w + o);                  o += 1024;
  float* ss3 = (float*)(w + o);                  o += 1024;
  float* ss4 = (float*)(w + o);                  o += 1024;
  float* ss5 = (float*)(w + o);                  o += 1024;
  float* ssH = (float*)(w + o);                  o += 1024;
  float* Wa = (float*)(w + o);                   o += (size_t)4096*4;
  float* Wb = (float*)(w + o);                   o += (size_t)4096*4;
  float* pooledF = (float*)(w + o);              o += (size_t)8192*4;
  float* Y6 = (float*)(w + o);                   o += (size_t)8192*4;
  float* Y7 = (float*)(w + o);                   o += (size_t)8192*4;
  float* Zl = (float*)(w + o);                   o += al((size_t)2560*4);
  // fp32 expansion region
  float* expBase = (float*)(w + o);
  float* ep = expBase;
  float* epos = ep; ep += (size_t)3*N;
  float* eW[9], *eb[9], *eg[9], *ebe[9];
  const int wsz[9] = {0, 64*6, 64*64, 64*64, 64*128, 128*128, 128*128, 128*128, 40*128};
  const int bsz[9] = {0, 64, 64, 64, 64, 128, 128, 128, 40};
  for (int i = 1; i <= 8; i++){
    eW[i] = ep; ep += wsz[i];
    eb[i] = ep; ep += bsz[i];
    if (i < 8){ eg[i] = ep; ep += bsz[i]; ebe[i] = ep; ep += bsz[i]; }
  }
  long expCount = (long)(ep - expBase);
  o += al((size_t)expCount * 4);
  unsigned short* x1b = (unsigned short*)(w + o); o += al((size_t)2*64*N);
  unsigned short* x2b = (unsigned short*)(w + o); o += al((size_t)2*64*N);
  unsigned short* y5b = (unsigned short*)(w + o); o += al((size_t)2*128*N);
  unsigned short* mbuf = (unsigned short*)(w + o); o += al((size_t)8192*nTiles);
  uint4* mbuf4 = (uint4*)mbuf;

  float* out_f = (float*)d_out;
  if (ws_size < o){
    k_sentinel<<<cdiv(out_size,256), 256, 0, stream>>>(out_f, out_size);
    return;
  }

  hipMemsetAsync(w, 0, zero_bytes, stream);
  k_detect<<<1, 256, 0, stream>>>(ei, pos, dmode);

  // expand all float inputs -> fp32
  ExpArgs ea;
  int it = 0;
  ea.it[it++] = {pos, epos, 3*N};
  int di_idx = 3;
  for (int i = 1; i <= 8; i++){
    ea.it[it++] = {d_in[di_idx++], eW[i], wsz[i]};
    ea.it[it++] = {d_in[di_idx++], eb[i], bsz[i]};
    if (i < 8){
      ea.it[it++] = {d_in[di_idx++], eg[i], bsz[i]};
      ea.it[it++] = {d_in[di_idx++], ebe[i], bsz[i]};
    }
  }
  k_expand<<<dim3(cdiv(3*N,256), 31), 256, 0, stream>>>(ea, it, dmode);
  k_prepW4<<<16, 256, 0, stream>>>(eW[4], Wa, Wb);

  const int nb = cdiv(N, 1024);
  // CSR build
  k_hist<<<cdiv(E,256), 256, 0, stream>>>(ei, E, N, dmode, deg);
  k_scan1<<<nb, 1024, 0, stream>>>(deg, N, offs, part);
  k_scan2<<<1, 1024, 0, stream>>>(part, nb);
  k_scan3<<<nb, 1024, 0, stream>>>(deg, part, N, E, offs, cursor);
  k_fill<<<cdiv(E,256), 256, 0, stream>>>(ei, E, N, dmode, cursor, bucket);

  // conv1 (fused stats; edges in bucket order)
  k_m1stats<<<cdiv(E,2048), 256, 0, stream>>>(epos, ei, E, N, dmode, eW[1], eb[1], repl);
  k_finalize<<<1, 128, 0, stream>>>(repl, 64, (float)E, eg[1], ebe[1], ss1);
  k_conv1_l2<<<cdiv(E,256), 256, 0, stream>>>(epos, ei, bucket, E, N, dmode,
                                              eW[1], eb[1], ss1, eW[2], eb[2], mbuf4, repl);
  k_finalize<<<1, 128, 0, stream>>>(repl, 64, (float)E, eg[2], ebe[2], ss2);
  k_conv1_l3<<<cdiv(E,256), 256, 0, stream>>>(mbuf4, E, ss2, eW[3], eb[3], repl);
  k_finalize<<<1, 128, 0, stream>>>(repl, 64, (float)E, eg[3], ebe[3], ss3);
  k_aggregate<<<cdiv(N,4), 256, 0, stream>>>(mbuf, offs, N, E, ss3, x1b);

  // conv2
  k_conv2<<<cdiv(E,256), 256, 0, stream>>>(x1b, ei, bucket, E, N, dmode, Wa, Wb, eb[4], mbuf4, repl);
  k_finalize<<<1, 128, 0, stream>>>(repl, 64, (float)E, eg[4], ebe[4], ss4);
  k_aggregate<<<cdiv(N,4), 256, 0, stream>>>(mbuf, offs, N, E, ss4, x2b);

  // lin5 + BN5 stats + pool
  k_lin5<<<cdiv(N,16), 256, 0, stream>>>(x1b, x2b, N, eW[5], eb[5], y5b);
  k_stats_bf16<<<512, 256, 0, stream>>>(y5b, (long)N*128, 127, repl);
  k_finalize<<<1, 128, 0, stream>>>(repl, 128, (float)N, eg[5], ebe[5], ss5);
  k_pool<<<cdiv(N,512), 128, 0, stream>>>(y5b, batch, N, dmode, ss5, pooled);

  // head
  k_pooled2f<<<32, 256, 0, stream>>>(pooled, pooledF);
  k_linH<<<32, 256, 0, stream>>>(pooledF, eW[6], eb[6], 128, 128, Y6);
  k_bnH<<<1, 128, 0, stream>>>(Y6, 128, eg[6], ebe[6], ssH);
  k_bnreluH<<<32, 256, 0, stream>>>(Y6, 128, ssH);
  k_linH<<<32, 256, 0, stream>>>(Y6, eW[7], eb[7], 128, 128, Y7);
  k_bnH<<<1, 128, 0, stream>>>(Y7, 128, eg[7], ebe[7], ssH);
  k_bnreluH<<<32, 256, 0, stream>>>(Y7, 128, ssH);
  k_linH<<<10, 256, 0, stream>>>(Y7, eW[8], eb[8], 128, 40, Zl);
  k_logsm<<<1, 64, 0, stream>>>(Zl, out_f);
}

// Round 11
// 6782.457 us; speedup vs baseline: 1.8548x; 1.6414x over previous
//
#include <hip/hip_runtime.h>
#include <math.h>

#define EPS_BN 1e-5f

// Wire formats (established r0-r8): float inputs = bf16 (runtime-detected),
// int inputs = int32/int64 (runtime-detected), OUTPUT = FP32.
// mbuf layout: [tile=64 edges][8 chunks][64 edge-slots][16B]; edges in CSR-bucket order.
// r11: __launch_bounds__(256,1) on the fat kernels -- r10's VGPR_Count=64 proved
// xi/xj/z arrays were SPILLED to scratch (16.8 GB of HBM FETCH was spill reload,
// not global gathers). Registers now hold the working set.

// ---------- helpers ----------
static __device__ __forceinline__ float bf2f(unsigned short b){
  return __uint_as_float(((unsigned)b) << 16);
}
static __device__ __forceinline__ unsigned short f2bf(float f){
  unsigned u = __float_as_uint(f);
  u += 0x7fffu + ((u >> 16) & 1u);   // RNE (finite values only)
  return (unsigned short)(u >> 16);
}
static inline int cdiv(int a, int b){ return (a + b - 1) / b; }
static __device__ __forceinline__ int clampi(int v, int lo, int hi){
  return v < lo ? lo : (v > hi ? hi : v);
}
static __device__ __forceinline__ int ld_idx(const void* p, long e, int m64){
  return m64 ? (int)((const long long*)p)[e] : ((const int*)p)[e];
}
static __device__ __forceinline__ uint4 pack8(const float* acc){
  uint4 u;
  u.x = ((unsigned)f2bf(acc[1]) << 16) | (unsigned)f2bf(acc[0]);
  u.y = ((unsigned)f2bf(acc[3]) << 16) | (unsigned)f2bf(acc[2]);
  u.z = ((unsigned)f2bf(acc[5]) << 16) | (unsigned)f2bf(acc[4]);
  u.w = ((unsigned)f2bf(acc[7]) << 16) | (unsigned)f2bf(acc[6]);
  return u;
}
// butterfly-reduce s,q over 64 lanes; lane j commits channel c
static __device__ __forceinline__ void stat_commit(float v, int valid, int lane, int j,
                                                   float* repl, int r, int c){
  float s = valid ? v : 0.f;
  float q = s * s;
  #pragma unroll
  for (int m = 1; m < 64; m <<= 1){ s += __shfl_xor(s, m, 64); q += __shfl_xor(q, m, 64); }
  if (lane == j){
    atomicAdd(&repl[r*256 + c], s);
    atomicAdd(&repl[r*256 + 128 + c], q);
  }
}

// ---------- sentinel ----------
__global__ void k_sentinel(float* out, int n){
  int i = blockIdx.x*256 + threadIdx.x;
  if (i < n) out[i] = -12288.0f;
}

// ---------- runtime dtype detection ----------
__global__ void k_detect(const void* ei, const void* pos, int* dmode){
  __shared__ int nz, ff;
  if (threadIdx.x == 0){ nz = 0; ff = 0; }
  __syncthreads();
  const int* w32 = (const int*)ei;
  if (w32[1 + 2*threadIdx.x] != 0) nz = 1;
  const unsigned short* ph = (const unsigned short*)pos;
  int bad = 0;
  for (int i = threadIdx.x; i < 8192; i += 256)
    if (((ph[i] >> 7) & 0xFF) == 0xFF) bad = 1;
  if (bad) ff = 1;
  __syncthreads();
  if (threadIdx.x == 0){ dmode[0] = nz ? 0 : 1; dmode[1] = ff; }
}

// ---------- expand float inputs -> fp32 scratch ----------
struct ExpItem { const void* s; float* d; int n; };
struct ExpArgs { ExpItem it[31]; };
__global__ void k_expand(ExpArgs a, int cnt, const int* dmode){
  int i = blockIdx.y;
  if (i >= cnt) return;
  int m32 = dmode[1];
  int t = blockIdx.x*256 + threadIdx.x;
  if (t < a.it[i].n){
    a.it[i].d[t] = m32 ? ((const float*)a.it[i].s)[t]
                       : bf2f(((const unsigned short*)a.it[i].s)[t]);
  }
}

// ---------- W4 split ----------
__global__ void k_prepW4(const float* __restrict__ W4, float* __restrict__ Wa, float* __restrict__ Wb){
  int i = blockIdx.x*256 + threadIdx.x;
  if (i < 4096){
    int c = i >> 6, k = i & 63;
    float a = W4[c*128 + k], b = W4[c*128 + 64 + k];
    Wa[i] = a - b;
    Wb[i] = b;
  }
}

// ---------- CSR build ----------
__global__ void k_hist(const void* __restrict__ ei, int E, int N, const int* dmode, int* __restrict__ deg){
  int m64 = dmode[0];
  int e = blockIdx.x*256 + threadIdx.x;
  if (e < E) atomicAdd(&deg[clampi(ld_idx(ei, (long)E + e, m64), 0, N-1)], 1);
}

__global__ void k_scan1(const int* __restrict__ deg, int N, int* __restrict__ incl, int* __restrict__ part){
  __shared__ int s[1024];
  int i = blockIdx.x*1024 + threadIdx.x;
  s[threadIdx.x] = (i < N) ? deg[i] : 0;
  __syncthreads();
  for (int off = 1; off < 1024; off <<= 1){
    int t = (threadIdx.x >= off) ? s[threadIdx.x - off] : 0;
    __syncthreads();
    s[threadIdx.x] += t;
    __syncthreads();
  }
  if (i < N) incl[i] = s[threadIdx.x];
  if (threadIdx.x == 1023) part[blockIdx.x] = s[1023];
}

__global__ void k_scan2(int* __restrict__ part, int nb){
  __shared__ int s[1024];
  int i = threadIdx.x;
  s[i] = (i < nb) ? part[i] : 0;
  __syncthreads();
  for (int off = 1; off < 1024; off <<= 1){
    int t = (i >= off) ? s[i - off] : 0;
    __syncthreads();
    s[i] += t;
    __syncthreads();
  }
  if (i < nb) part[i] = s[i];
}

__global__ void k_scan3(const int* __restrict__ deg, const int* __restrict__ part, int N, int E,
                        int* __restrict__ offs, int* __restrict__ cursor){
  int i = blockIdx.x*1024 + threadIdx.x;
  if (i < N){
    int prev = (blockIdx.x > 0) ? part[blockIdx.x - 1] : 0;
    int v = prev + offs[i] - deg[i];
    offs[i] = v;
    cursor[i] = v;
  }
  if (blockIdx.x == 0 && threadIdx.x == 0) offs[N] = E;
}

__global__ void k_fill(const void* __restrict__ ei, int E, int N, const int* dmode,
                       int* __restrict__ cursor, int* __restrict__ bucket){
  int m64 = dmode[0];
  int e = blockIdx.x*256 + threadIdx.x;
  if (e < E){
    int p = atomicAdd(&cursor[clampi(ld_idx(ei, (long)E + e, m64), 0, N-1)], 1);
    if (p >= 0 && p < E) bucket[p] = e;
  }
}

// ---------- conv1 layer1 stats ----------
__global__ void __launch_bounds__(256, 1)
k_m1stats(const float* __restrict__ pos, const void* __restrict__ ei,
          int E, int N, const int* dmode,
          const float* __restrict__ W1, const float* __restrict__ b1,
          float* __restrict__ repl){
  int m64 = dmode[0];
  int lane = threadIdx.x & 63;
  int flatwave = (blockIdx.x*256 + threadIdx.x) >> 6;
  long base = (long)flatwave * 512;
  float as[64], aq[64];
  #pragma unroll
  for (int c = 0; c < 64; c++){ as[c] = 0.f; aq[c] = 0.f; }
  for (int k = 0; k < 8; k++){
    long e = base + (long)k*64 + lane;
    if (e < E){
      int si = clampi(ld_idx(ei, e, m64), 0, N-1);
      int di = clampi(ld_idx(ei, (long)E + e, m64), 0, N-1);
      float x0 = pos[di*3+0], x1 = pos[di*3+1], x2 = pos[di*3+2];
      float j0 = pos[si*3+0]-x0, j1 = pos[si*3+1]-x1, j2 = pos[si*3+2]-x2;
      #pragma unroll
      for (int c = 0; c < 64; c++){
        float m = b1[c];
        m = fmaf(x0, W1[c*6+0], m); m = fmaf(x1, W1[c*6+1], m); m = fmaf(x2, W1[c*6+2], m);
        m = fmaf(j0, W1[c*6+3], m); m = fmaf(j1, W1[c*6+4], m); m = fmaf(j2, W1[c*6+5], m);
        as[c] += m; aq[c] += m*m;
      }
    }
  }
  float outs = 0.f, outq = 0.f;
  #pragma unroll
  for (int c = 0; c < 64; c++){
    float s = as[c], q = aq[c];
    #pragma unroll
    for (int m = 1; m < 64; m <<= 1){ s += __shfl_xor(s, m, 64); q += __shfl_xor(q, m, 64); }
    if (lane == c){ outs = s; outq = q; }
  }
  int r = flatwave & 63;
  atomicAdd(&repl[r*256 + lane], outs);
  atomicAdd(&repl[r*256 + 128 + lane], outq);
}

// ---------- finalize BN ----------
__global__ void k_finalize(float* __restrict__ repl, int C, float count,
                           const float* __restrict__ g, const float* __restrict__ be,
                           float* __restrict__ ss){
  int c = threadIdx.x;
  if (c < C){
    float s = 0.f, q = 0.f;
    for (int r = 0; r < 64; r++){
      s += repl[r*256 + c];       repl[r*256 + c] = 0.f;
      q += repl[r*256 + 128 + c]; repl[r*256 + 128 + c] = 0.f;
    }
    float mean = s / count;
    float var  = fmaxf(q / count - mean*mean, 0.f);
    float inv  = rsqrtf(var + EPS_BN);
    float sc   = g[c] * inv;
    ss[c]     = sc;
    ss[C + c] = be[c] - mean*sc;
  }
}

// ---------- conv1 l2: bucket order, tiled store, fused stats ----------
__global__ void __launch_bounds__(256, 1)
k_conv1_l2(const float* __restrict__ pos, const void* __restrict__ ei,
           const int* __restrict__ bucket, int E, int N, const int* dmode,
           const float* __restrict__ W1, const float* __restrict__ b1,
           const float* __restrict__ ss1,
           const float* __restrict__ W2, const float* __restrict__ b2,
           uint4* __restrict__ mbuf4, float* __restrict__ repl){
  int m64 = dmode[0];
  int t = blockIdx.x*256 + threadIdx.x;
  int lane = threadIdx.x & 63;
  int valid = (t < E);
  int p = valid ? bucket[t] : 0;
  int si = clampi(ld_idx(ei, (long)p, m64), 0, N-1);
  int di = clampi(ld_idx(ei, (long)E + p, m64), 0, N-1);
  float x0 = pos[di*3+0], x1 = pos[di*3+1], x2 = pos[di*3+2];
  float j0 = pos[si*3+0]-x0, j1 = pos[si*3+1]-x1, j2 = pos[si*3+2]-x2;
  float z[64];
  #pragma unroll
  for (int c = 0; c < 64; c++){
    float m = b1[c];
    m = fmaf(x0, W1[c*6+0], m); m = fmaf(x1, W1[c*6+1], m); m = fmaf(x2, W1[c*6+2], m);
    m = fmaf(j0, W1[c*6+3], m); m = fmaf(j1, W1[c*6+4], m); m = fmaf(j2, W1[c*6+5], m);
    z[c] = fmaxf(fmaf(m, ss1[c], ss1[64 + c]), 0.f);
  }
  int tt = valid ? t : 0;
  uint4* obase = mbuf4 + (((size_t)(tt >> 6)) << 9) + (tt & 63);
  int r = ((blockIdx.x*256 + threadIdx.x) >> 6) & 63;
  for (int c0 = 0; c0 < 64; c0 += 8){
    float acc[8];
    #pragma unroll
    for (int j = 0; j < 8; j++) acc[j] = b2[c0 + j];
    #pragma unroll
    for (int i = 0; i < 64; i++){
      float zi = z[i];
      #pragma unroll
      for (int j = 0; j < 8; j++) acc[j] = fmaf(zi, W2[(c0 + j)*64 + i], acc[j]);
    }
    #pragma unroll
    for (int j = 0; j < 8; j++) stat_commit(acc[j], valid, lane, j, repl, r, c0 + j);
    if (valid) obase[(size_t)(c0 << 3)] = pack8(acc);
  }
}

// ---------- conv1 l3: tiled in-place, fused stats ----------
__global__ void __launch_bounds__(256, 1)
k_conv1_l3(uint4* __restrict__ mbuf4, int E,
           const float* __restrict__ ss, const float* __restrict__ W3,
           const float* __restrict__ b3, float* __restrict__ repl){
  int t = blockIdx.x*256 + threadIdx.x;
  int lane = threadIdx.x & 63;
  int valid = (t < E);
  int tt = valid ? t : 0;
  uint4* base = mbuf4 + (((size_t)(tt >> 6)) << 9) + (tt & 63);
  uint4 u[8];
  #pragma unroll
  for (int k = 0; k < 8; k++) u[k] = base[(size_t)(k << 6)];
  float z[64];
  #pragma unroll
  for (int k = 0; k < 8; k++){
    unsigned vals[4] = {u[k].x, u[k].y, u[k].z, u[k].w};
    #pragma unroll
    for (int q = 0; q < 4; q++){
      int c = k*8 + q*2;
      float lo = __uint_as_float(vals[q] << 16);
      float hi = __uint_as_float(vals[q] & 0xffff0000u);
      z[c]   = fmaxf(fmaf(lo, ss[c],   ss[64 + c]),   0.f);
      z[c+1] = fmaxf(fmaf(hi, ss[c+1], ss[64 + c+1]), 0.f);
    }
  }
  int r = ((blockIdx.x*256 + threadIdx.x) >> 6) & 63;
  for (int c0 = 0; c0 < 64; c0 += 8){
    float acc[8];
    #pragma unroll
    for (int j = 0; j < 8; j++) acc[j] = b3[c0 + j];
    #pragma unroll
    for (int i = 0; i < 64; i++){
      float zi = z[i];
      #pragma unroll
      for (int j = 0; j < 8; j++) acc[j] = fmaf(zi, W3[(c0 + j)*64 + i], acc[j]);
    }
    #pragma unroll
    for (int j = 0; j < 8; j++) stat_commit(acc[j], valid, lane, j, repl, r, c0 + j);
    if (valid) base[(size_t)(c0 << 3)] = pack8(acc);
  }
}

// ---------- aggregate: sequential CSR rows in tiled layout ----------
__global__ void k_aggregate(const unsigned short* __restrict__ mbuf,
                            const int* __restrict__ offs, int N, int E,
                            const float* __restrict__ ss, unsigned short* __restrict__ xout){
  int wave = threadIdx.x >> 6;
  int lane = threadIdx.x & 63;
  int n = blockIdx.x*4 + wave;
  if (n >= N) return;
  int s0 = clampi(offs[n], 0, E);
  int s1 = clampi(offs[n + 1], s0, E);
  float sc = ss[lane], sh = ss[64 + lane];
  int g = lane >> 3, pz = lane & 7;
  float acc = 0.f;
  for (int k = s0; k < s1; k++){
    size_t idx = (((size_t)(k >> 6)) << 12) + (g << 9) + ((k & 63) << 3) + pz;
    float v = bf2f(mbuf[idx]);
    acc = fmaxf(acc, fmaf(v, sc, sh));
  }
  xout[(size_t)n*64 + lane] = f2bf(acc);
}

// ---------- unpack row-major 64-wide bf16 row ----------
static __device__ __forceinline__ void unpack_row64(const unsigned short* row, float* v){
  const uint4* r4 = (const uint4*)row;
  #pragma unroll
  for (int k = 0; k < 8; k++){
    uint4 u = r4[k];
    unsigned w[4] = {u.x, u.y, u.z, u.w};
    #pragma unroll
    for (int q = 0; q < 4; q++){
      v[k*8 + q*2]     = __uint_as_float(w[q] << 16);
      v[k*8 + q*2 + 1] = __uint_as_float(w[q] & 0xffff0000u);
    }
  }
}

// ---------- conv2: LDS-staged xj gather + register-resident compute ----------
__global__ void __launch_bounds__(256, 1)
k_conv2(const unsigned short* __restrict__ x1, const void* __restrict__ ei,
        const int* __restrict__ bucket, int E, int N, const int* dmode,
        const float* __restrict__ Wa, const float* __restrict__ Wb,
        const float* __restrict__ b4, uint4* __restrict__ mbuf4,
        float* __restrict__ repl){
  __shared__ __align__(16) unsigned short xjs[4][64][68];  // stride 68: 2-way bank alias = free
  __shared__ int sis[4][64];
  int m64 = dmode[0];
  int wv = threadIdx.x >> 6, lane = threadIdx.x & 63;
  int t = blockIdx.x*256 + threadIdx.x;
  int valid = (t < E);
  int p = valid ? bucket[t] : 0;
  int si = clampi(ld_idx(ei, (long)p, m64), 0, N-1);
  int di = clampi(ld_idx(ei, (long)E + p, m64), 0, N-1);
  sis[wv][lane] = si;
  __syncthreads();
  int rl = lane >> 3, ch = lane & 7;
  #pragma unroll
  for (int r = 0; r < 8; r++){
    int row = sis[wv][r*8 + rl];
    uint4 v = *(const uint4*)(x1 + (size_t)row*64 + ch*8);
    unsigned short* dp = &xjs[wv][r*8 + rl][ch*8];
    *(uint2*)(dp)     = make_uint2(v.x, v.y);
    *(uint2*)(dp + 4) = make_uint2(v.z, v.w);
  }
  __syncthreads();
  float xi[64], xj[64];
  unpack_row64(x1 + (size_t)di*64, xi);   // dst-sequential: L1/L2-hot
  {
    const unsigned short* xr = xjs[wv][lane];
    #pragma unroll
    for (int k = 0; k < 8; k++){
      uint2 a = *(const uint2*)(xr + k*8);
      uint2 b = *(const uint2*)(xr + k*8 + 4);
      xj[k*8+0] = __uint_as_float(a.x << 16);
      xj[k*8+1] = __uint_as_float(a.x & 0xffff0000u);
      xj[k*8+2] = __uint_as_float(a.y << 16);
      xj[k*8+3] = __uint_as_float(a.y & 0xffff0000u);
      xj[k*8+4] = __uint_as_float(b.x << 16);
      xj[k*8+5] = __uint_as_float(b.x & 0xffff0000u);
      xj[k*8+6] = __uint_as_float(b.y << 16);
      xj[k*8+7] = __uint_as_float(b.y & 0xffff0000u);
    }
  }
  int tt = valid ? t : 0;
  uint4* obase = mbuf4 + (((size_t)(tt >> 6)) << 9) + (tt & 63);
  int r2 = (t >> 6) & 63;
  for (int c0 = 0; c0 < 64; c0 += 8){
    float acc[8];
    #pragma unroll
    for (int j = 0; j < 8; j++) acc[j] = b4[c0 + j];
    #pragma unroll
    for (int i = 0; i < 64; i++){
      float a = xi[i], b = xj[i];
      #pragma unroll
      for (int j = 0; j < 8; j++){
        acc[j] = fmaf(a, Wa[(c0 + j)*64 + i], acc[j]);
        acc[j] = fmaf(b, Wb[(c0 + j)*64 + i], acc[j]);
      }
    }
    #pragma unroll
    for (int j = 0; j < 8; j++) stat_commit(acc[j], valid, lane, j, repl, r2, c0 + j);
    if (valid) obase[(size_t)(c0 << 3)] = pack8(acc);
  }
}

// ---------- lin5: 16 nodes x 16 col-groups per block, LDS-staged inputs ----------
__global__ void k_lin5(const unsigned short* __restrict__ x1, const unsigned short* __restrict__ x2,
                       int N, const float* __restrict__ W5, const float* __restrict__ b5,
                       unsigned short* __restrict__ y5){
  __shared__ float xs[16][130];
  int t = threadIdx.x;            // 256
  int nb0 = blockIdx.x * 16;
  {
    int row = t >> 4, col4 = (t & 15) * 4;
    if (nb0 + row < N){
      uint2 a = *(const uint2*)(x1 + (size_t)(nb0 + row)*64 + col4);
      uint2 b = *(const uint2*)(x2 + (size_t)(nb0 + row)*64 + col4);
      xs[row][col4+0] = __uint_as_float(a.x << 16);
      xs[row][col4+1] = __uint_as_float(a.x & 0xffff0000u);
      xs[row][col4+2] = __uint_as_float(a.y << 16);
      xs[row][col4+3] = __uint_as_float(a.y & 0xffff0000u);
      xs[row][64+col4+0] = __uint_as_float(b.x << 16);
      xs[row][64+col4+1] = __uint_as_float(b.x & 0xffff0000u);
      xs[row][64+col4+2] = __uint_as_float(b.y << 16);
      xs[row][64+col4+3] = __uint_as_float(b.y & 0xffff0000u);
    } else {
      #pragma unroll
      for (int q = 0; q < 4; q++){ xs[row][col4+q] = 0.f; xs[row][64+col4+q] = 0.f; }
    }
  }
  __syncthreads();
  int node = t >> 4, cg = t & 15;
  int n = nb0 + node;
  const float* xr = xs[node];
  const float* wbase = W5 + (size_t)(cg*8)*128;
  float acc[8];
  #pragma unroll
  for (int j = 0; j < 8; j++) acc[j] = b5[cg*8 + j];
  for (int i = 0; i < 128; i++){
    float xv = xr[i];
    #pragma unroll
    for (int j = 0; j < 8; j++) acc[j] = fmaf(xv, wbase[j*128 + i], acc[j]);
  }
  if (n < N) *(uint4*)(y5 + (size_t)n*128 + cg*8) = pack8(acc);
}

// ---------- column stats over row-major bf16 (y5 only) ----------
__global__ void k_stats_bf16(const unsigned short* __restrict__ buf, long total, int cmask,
                             float* __restrict__ repl){
  int tid = blockIdx.x*256 + threadIdx.x;
  int c = tid & cmask;
  long stride = (long)gridDim.x * 256;
  float s = 0.f, q = 0.f;
  long i = tid;
  for (; i + 3*stride < total; i += 4*stride){
    float v0 = bf2f(buf[i]);
    float v1 = bf2f(buf[i +   stride]);
    float v2 = bf2f(buf[i + 2*stride]);
    float v3 = bf2f(buf[i + 3*stride]);
    s += (v0 + v1) + (v2 + v3);
    q += (v0*v0 + v1*v1) + (v2*v2 + v3*v3);
  }
  for (; i < total; i += stride){ float v = bf2f(buf[i]); s += v; q += v*v; }
  int r = (tid >> 6) & 63;
  atomicAdd(&repl[r*256 + c], s);
  atomicAdd(&repl[r*256 + 128 + c], q);
}

// ---------- pool ----------
__global__ void k_pool(const unsigned short* __restrict__ y5, const void* __restrict__ batch, int N,
                       const int* dmode, const float* __restrict__ ss5, unsigned int* __restrict__ pooled){
  int m64 = dmode[0];
  int c = threadIdx.x;               // 128 threads
  int n0 = blockIdx.x*512;
  int n1 = min(n0 + 512, N);
  float sc = ss5[c], sh = ss5[128 + c];
  int curb = -1; float curm = 0.f;
  for (int n = n0; n < n1; n++){
    int b = clampi(ld_idx(batch, (long)n, m64), 0, 63);
    float v = fmaf(bf2f(y5[(size_t)n*128 + c]), sc, sh);
    if (b != curb){
      if (curb >= 0) atomicMax(&pooled[curb*128 + c], __float_as_uint(fmaxf(curm, 0.f)));
      curb = b; curm = v;
    } else {
      curm = fmaxf(curm, v);
    }
  }
  if (curb >= 0) atomicMax(&pooled[curb*128 + c], __float_as_uint(fmaxf(curm, 0.f)));
}

// ---------- head ----------
__global__ void k_pooled2f(const unsigned int* __restrict__ pooled, float* __restrict__ pf){
  int i = blockIdx.x*256 + threadIdx.x;
  if (i < 8192) pf[i] = __uint_as_float(pooled[i]);
}

__global__ void k_linH(const float* __restrict__ X, const float* __restrict__ W,
                       const float* __restrict__ b, int CI, int CO, float* __restrict__ Y){
  int cell = blockIdx.x*256 + threadIdx.x;
  if (cell >= 64*CO) return;
  int r = cell / CO, c = cell - r*CO;
  const float* xr = X + r*CI;
  const float* wr = W + c*CI;
  float a = b[c];
  for (int j = 0; j < CI; j++) a = fmaf(xr[j], wr[j], a);
  Y[cell] = a;
}

__global__ void k_bnH(const float* __restrict__ Y, int CO,
                      const float* __restrict__ g, const float* __restrict__ be,
                      float* __restrict__ ss){
  int c = threadIdx.x;
  if (c >= CO) return;
  float s = 0.f;
  for (int r = 0; r < 64; r++) s += Y[r*CO + c];
  float mean = s * (1.f/64.f);
  float q = 0.f;
  for (int r = 0; r < 64; r++){ float d = Y[r*CO + c] - mean; q += d*d; }
  float var = fmaxf(q * (1.f/64.f), 0.f);
  float inv = rsqrtf(var + EPS_BN);
  float sc = g[c] * inv;
  ss[c] = sc;
  ss[CO + c] = be[c] - mean*sc;
}

__global__ void k_bnreluH(float* __restrict__ Y, int CO, const float* __restrict__ ss){
  int cell = blockIdx.x*256 + threadIdx.x;
  if (cell >= 64*CO) return;
  int c = cell % CO;
  Y[cell] = fmaxf(fmaf(Y[cell], ss[c], ss[CO + c]), 0.f);
}

__global__ void k_logsm(const float* __restrict__ Z, float* __restrict__ out){
  int r = threadIdx.x;   // 64 threads
  const float* zr = Z + r*40;
  float m = zr[0];
  for (int c = 1; c < 40; c++) m = fmaxf(m, zr[c]);
  float s = 0.f;
  for (int c = 0; c < 40; c++) s += expf(zr[c] - m);
  float ls = logf(s);
  for (int c = 0; c < 40; c++) out[r*40 + c] = zr[c] - m - ls;
}

// ---------- launch ----------
extern "C" void kernel_launch(void* const* d_in, const int* in_sizes, int n_in,
                              void* d_out, int out_size, void* d_ws, size_t ws_size,
                              hipStream_t stream) {
  const void* pos   = d_in[0];
  const void* ei    = d_in[1];
  const void* batch = d_in[2];
  (void)n_in;

  const int N = in_sizes[0] / 3;
  const int E = in_sizes[1] / 2;
  const int nTiles = cdiv(E, 64);

  // ---- workspace layout ----
  auto al = [](size_t x){ return (x + 255) & ~(size_t)255; };
  char* w = (char*)d_ws;
  size_t o = 0;
  float* repl = (float*)(w + o);                 o += (size_t)64*256*4;
  unsigned int* pooled = (unsigned int*)(w + o); o += (size_t)64*128*4;
  int* deg = (int*)(w + o);                      o += al((size_t)4*N);
  size_t zero_bytes = o;
  int* dmode = (int*)(w + o);                    o += 256;
  int* offs = (int*)(w + o);                     o += al((size_t)4*(N + 1));
  int* cursor = (int*)(w + o);                   o += al((size_t)4*N);
  int* part = (int*)(w + o);                     o += 4096;
  int* bucket = (int*)(w + o);                   o += al((size_t)4*E);
  float* ss1 = (float*)(w + o);                  o += 1024;
  float* ss2 = (float*)(w + o);                  o += 1024;
  float* ss3 = (float*)(w + o);                  o += 1024;
  float* ss4 = (float*)(w + o);                  o += 1024;
  float* ss5 = (float*)(w + o);                  o += 1024;
  float* ssH = (float*)(w + o);                  o += 1024;
  float* Wa = (float*)(w + o);                   o += (size_t)4096*4;
  float* Wb = (float*)(w + o);                   o += (size_t)4096*4;
  float* pooledF = (float*)(w + o);              o += (size_t)8192*4;
  float* Y6 = (float*)(w + o);                   o += (size_t)8192*4;
  float* Y7 = (float*)(w + o);                   o += (size_t)8192*4;
  float* Zl = (float*)(w + o);                   o += al((size_t)2560*4);
  // fp32 expansion region
  float* expBase = (float*)(w + o);
  float* ep = expBase;
  float* epos = ep; ep += (size_t)3*N;
  float* eW[9], *eb[9], *eg[9], *ebe[9];
  const int wsz[9] = {0, 64*6, 64*64, 64*64, 64*128, 128*128, 128*128, 128*128, 40*128};
  const int bsz[9] = {0, 64, 64, 64, 64, 128, 128, 128, 40};
  for (int i = 1; i <= 8; i++){
    eW[i] = ep; ep += wsz[i];
    eb[i] = ep; ep += bsz[i];
    if (i < 8){ eg[i] = ep; ep += bsz[i]; ebe[i] = ep; ep += bsz[i]; }
  }
  long expCount = (long)(ep - expBase);
  o += al((size_t)expCount * 4);
  unsigned short* x1b = (unsigned short*)(w + o); o += al((size_t)2*64*N);
  unsigned short* x2b = (unsigned short*)(w + o); o += al((size_t)2*64*N);
  unsigned short* y5b = (unsigned short*)(w + o); o += al((size_t)2*128*N);
  unsigned short* mbuf = (unsigned short*)(w + o); o += al((size_t)8192*nTiles);
  uint4* mbuf4 = (uint4*)mbuf;

  float* out_f = (float*)d_out;
  if (ws_size < o){
    k_sentinel<<<cdiv(out_size,256), 256, 0, stream>>>(out_f, out_size);
    return;
  }

  hipMemsetAsync(w, 0, zero_bytes, stream);
  k_detect<<<1, 256, 0, stream>>>(ei, pos, dmode);

  // expand all float inputs -> fp32
  ExpArgs ea;
  int it = 0;
  ea.it[it++] = {pos, epos, 3*N};
  int di_idx = 3;
  for (int i = 1; i <= 8; i++){
    ea.it[it++] = {d_in[di_idx++], eW[i], wsz[i]};
    ea.it[it++] = {d_in[di_idx++], eb[i], bsz[i]};
    if (i < 8){
      ea.it[it++] = {d_in[di_idx++], eg[i], bsz[i]};
      ea.it[it++] = {d_in[di_idx++], ebe[i], bsz[i]};
    }
  }
  k_expand<<<dim3(cdiv(3*N,256), 31), 256, 0, stream>>>(ea, it, dmode);
  k_prepW4<<<16, 256, 0, stream>>>(eW[4], Wa, Wb);

  const int nb = cdiv(N, 1024);
  // CSR build
  k_hist<<<cdiv(E,256), 256, 0, stream>>>(ei, E, N, dmode, deg);
  k_scan1<<<nb, 1024, 0, stream>>>(deg, N, offs, part);
  k_scan2<<<1, 1024, 0, stream>>>(part, nb);
  k_scan3<<<nb, 1024, 0, stream>>>(deg, part, N, E, offs, cursor);
  k_fill<<<cdiv(E,256), 256, 0, stream>>>(ei, E, N, dmode, cursor, bucket);

  // conv1 (fused stats; edges in bucket order)
  k_m1stats<<<cdiv(E,2048), 256, 0, stream>>>(epos, ei, E, N, dmode, eW[1], eb[1], repl);
  k_finalize<<<1, 128, 0, stream>>>(repl, 64, (float)E, eg[1], ebe[1], ss1);
  k_conv1_l2<<<cdiv(E,256), 256, 0, stream>>>(epos, ei, bucket, E, N, dmode,
                                              eW[1], eb[1], ss1, eW[2], eb[2], mbuf4, repl);
  k_finalize<<<1, 128, 0, stream>>>(repl, 64, (float)E, eg[2], ebe[2], ss2);
  k_conv1_l3<<<cdiv(E,256), 256, 0, stream>>>(mbuf4, E, ss2, eW[3], eb[3], repl);
  k_finalize<<<1, 128, 0, stream>>>(repl, 64, (float)E, eg[3], ebe[3], ss3);
  k_aggregate<<<cdiv(N,4), 256, 0, stream>>>(mbuf, offs, N, E, ss3, x1b);

  // conv2
  k_conv2<<<cdiv(E,256), 256, 0, stream>>>(x1b, ei, bucket, E, N, dmode, Wa, Wb, eb[4], mbuf4, repl);
  k_finalize<<<1, 128, 0, stream>>>(repl, 64, (float)E, eg[4], ebe[4], ss4);
  k_aggregate<<<cdiv(N,4), 256, 0, stream>>>(mbuf, offs, N, E, ss4, x2b);

  // lin5 + BN5 stats + pool
  k_lin5<<<cdiv(N,16), 256, 0, stream>>>(x1b, x2b, N, eW[5], eb[5], y5b);
  k_stats_bf16<<<512, 256, 0, stream>>>(y5b, (long)N*128, 127, repl);
  k_finalize<<<1, 128, 0, stream>>>(repl, 128, (float)N, eg[5], ebe[5], ss5);
  k_pool<<<cdiv(N,512), 128, 0, stream>>>(y5b, batch, N, dmode, ss5, pooled);

  // head
  k_pooled2f<<<32, 256, 0, stream>>>(pooled, pooledF);
  k_linH<<<32, 256, 0, stream>>>(pooledF, eW[6], eb[6], 128, 128, Y6);
  k_bnH<<<1, 128, 0, stream>>>(Y6, 128, eg[6], ebe[6], ssH);
  k_bnreluH<<<32, 256, 0, stream>>>(Y6, 128, ssH);
  k_linH<<<32, 256, 0, stream>>>(Y6, eW[7], eb[7], 128, 128, Y7);
  k_bnH<<<1, 128, 0, stream>>>(Y7, 128, eg[7], ebe[7], ssH);
  k_bnreluH<<<32, 256, 0, stream>>>(Y7, 128, ssH);
  k_linH<<<10, 256, 0, stream>>>(Y7, eW[8], eb[8], 128, 40, Zl);
  k_logsm<<<1, 64, 0, stream>>>(Zl, out_f);
}

// Round 12
// 1852.993 us; speedup vs baseline: 6.7889x; 3.6603x over previous
//
#include <hip/hip_runtime.h>
#include <math.h>

#define EPS_BN 1e-5f

// Wire formats (established r0-r8): float inputs = bf16 (runtime-detected),
// int inputs = int32/int64 (runtime-detected), OUTPUT = FP32.
// mbuf layout: [tile=64 edges][8 chunks][64 edge-slots][16B]; edges in CSR-bucket order.
// r12: conv1_l2/l3 + conv2 rewritten as wave-level MFMA GEMMs (16x16x32 bf16).
// r11 evidence: per-thread matmul was VMEM-issue-bound (1 uniform weight load per
// 2 FMAs, VALUBusy 20%). MFMA holds weights in register fragments.

typedef short short8_t __attribute__((ext_vector_type(8)));
typedef float f32x4_t  __attribute__((ext_vector_type(4)));

// ---------- helpers ----------
static __device__ __forceinline__ float bf2f(unsigned short b){
  return __uint_as_float(((unsigned)b) << 16);
}
static __device__ __forceinline__ unsigned short f2bf(float f){
  unsigned u = __float_as_uint(f);
  u += 0x7fffu + ((u >> 16) & 1u);   // RNE (finite values only)
  return (unsigned short)(u >> 16);
}
static inline int cdiv(int a, int b){ return (a + b - 1) / b; }
static __device__ __forceinline__ int clampi(int v, int lo, int hi){
  return v < lo ? lo : (v > hi ? hi : v);
}
static __device__ __forceinline__ int ld_idx(const void* p, long e, int m64){
  return m64 ? (int)((const long long*)p)[e] : ((const int*)p)[e];
}

// ---------- sentinel ----------
__global__ void k_sentinel(float* out, int n){
  int i = blockIdx.x*256 + threadIdx.x;
  if (i < n) out[i] = -12288.0f;
}

// ---------- runtime dtype detection ----------
__global__ void k_detect(const void* ei, const void* pos, int* dmode){
  __shared__ int nz, ff;
  if (threadIdx.x == 0){ nz = 0; ff = 0; }
  __syncthreads();
  const int* w32 = (const int*)ei;
  if (w32[1 + 2*threadIdx.x] != 0) nz = 1;
  const unsigned short* ph = (const unsigned short*)pos;
  int bad = 0;
  for (int i = threadIdx.x; i < 8192; i += 256)
    if (((ph[i] >> 7) & 0xFF) == 0xFF) bad = 1;
  if (bad) ff = 1;
  __syncthreads();
  if (threadIdx.x == 0){ dmode[0] = nz ? 0 : 1; dmode[1] = ff; }
}

// ---------- expand float inputs -> fp32 scratch ----------
struct ExpItem { const void* s; float* d; int n; };
struct ExpArgs { ExpItem it[31]; };
__global__ void k_expand(ExpArgs a, int cnt, const int* dmode){
  int i = blockIdx.y;
  if (i >= cnt) return;
  int m32 = dmode[1];
  int t = blockIdx.x*256 + threadIdx.x;
  if (t < a.it[i].n){
    a.it[i].d[t] = m32 ? ((const float*)a.it[i].s)[t]
                       : bf2f(((const unsigned short*)a.it[i].s)[t]);
  }
}

// ---------- Wab prep: [64][128] = [Wa | Wb], Wa = A-part minus B-part ----------
__global__ void k_prepW4(const float* __restrict__ W4, float* __restrict__ Wab){
  int i = blockIdx.x*256 + threadIdx.x;
  if (i < 8192){
    int c = i >> 7, k = i & 127;
    float v;
    if (k < 64) v = W4[c*128 + k] - W4[c*128 + 64 + k];
    else        v = W4[c*128 + k];
    Wab[i] = v;
  }
}

// ---------- CSR build ----------
__global__ void k_hist(const void* __restrict__ ei, int E, int N, const int* dmode, int* __restrict__ deg){
  int m64 = dmode[0];
  int e = blockIdx.x*256 + threadIdx.x;
  if (e < E) atomicAdd(&deg[clampi(ld_idx(ei, (long)E + e, m64), 0, N-1)], 1);
}

__global__ void k_scan1(const int* __restrict__ deg, int N, int* __restrict__ incl, int* __restrict__ part){
  __shared__ int s[1024];
  int i = blockIdx.x*1024 + threadIdx.x;
  s[threadIdx.x] = (i < N) ? deg[i] : 0;
  __syncthreads();
  for (int off = 1; off < 1024; off <<= 1){
    int t = (threadIdx.x >= off) ? s[threadIdx.x - off] : 0;
    __syncthreads();
    s[threadIdx.x] += t;
    __syncthreads();
  }
  if (i < N) incl[i] = s[threadIdx.x];
  if (threadIdx.x == 1023) part[blockIdx.x] = s[1023];
}

__global__ void k_scan2(int* __restrict__ part, int nb){
  __shared__ int s[1024];
  int i = threadIdx.x;
  s[i] = (i < nb) ? part[i] : 0;
  __syncthreads();
  for (int off = 1; off < 1024; off <<= 1){
    int t = (i >= off) ? s[i - off] : 0;
    __syncthreads();
    s[i] += t;
    __syncthreads();
  }
  if (i < nb) part[i] = s[i];
}

__global__ void k_scan3(const int* __restrict__ deg, const int* __restrict__ part, int N, int E,
                        int* __restrict__ offs, int* __restrict__ cursor){
  int i = blockIdx.x*1024 + threadIdx.x;
  if (i < N){
    int prev = (blockIdx.x > 0) ? part[blockIdx.x - 1] : 0;
    int v = prev + offs[i] - deg[i];
    offs[i] = v;
    cursor[i] = v;
  }
  if (blockIdx.x == 0 && threadIdx.x == 0) offs[N] = E;
}

__global__ void k_fill(const void* __restrict__ ei, int E, int N, const int* dmode,
                       int* __restrict__ cursor, int* __restrict__ bucket){
  int m64 = dmode[0];
  int e = blockIdx.x*256 + threadIdx.x;
  if (e < E){
    int p = atomicAdd(&cursor[clampi(ld_idx(ei, (long)E + e, m64), 0, N-1)], 1);
    if (p >= 0 && p < E) bucket[p] = e;
  }
}

// ---------- conv1 layer1 stats ----------
__global__ void __launch_bounds__(256, 1)
k_m1stats(const float* __restrict__ pos, const void* __restrict__ ei,
          int E, int N, const int* dmode,
          const float* __restrict__ W1, const float* __restrict__ b1,
          float* __restrict__ repl){
  int m64 = dmode[0];
  int lane = threadIdx.x & 63;
  int flatwave = (blockIdx.x*256 + threadIdx.x) >> 6;
  long base = (long)flatwave * 512;
  float as[64], aq[64];
  #pragma unroll
  for (int c = 0; c < 64; c++){ as[c] = 0.f; aq[c] = 0.f; }
  for (int k = 0; k < 8; k++){
    long e = base + (long)k*64 + lane;
    if (e < E){
      int si = clampi(ld_idx(ei, e, m64), 0, N-1);
      int di = clampi(ld_idx(ei, (long)E + e, m64), 0, N-1);
      float x0 = pos[di*3+0], x1 = pos[di*3+1], x2 = pos[di*3+2];
      float j0 = pos[si*3+0]-x0, j1 = pos[si*3+1]-x1, j2 = pos[si*3+2]-x2;
      #pragma unroll
      for (int c = 0; c < 64; c++){
        float m = b1[c];
        m = fmaf(x0, W1[c*6+0], m); m = fmaf(x1, W1[c*6+1], m); m = fmaf(x2, W1[c*6+2], m);
        m = fmaf(j0, W1[c*6+3], m); m = fmaf(j1, W1[c*6+4], m); m = fmaf(j2, W1[c*6+5], m);
        as[c] += m; aq[c] += m*m;
      }
    }
  }
  float outs = 0.f, outq = 0.f;
  #pragma unroll
  for (int c = 0; c < 64; c++){
    float s = as[c], q = aq[c];
    #pragma unroll
    for (int m = 1; m < 64; m <<= 1){ s += __shfl_xor(s, m, 64); q += __shfl_xor(q, m, 64); }
    if (lane == c){ outs = s; outq = q; }
  }
  int r = flatwave & 63;
  atomicAdd(&repl[r*256 + lane], outs);
  atomicAdd(&repl[r*256 + 128 + lane], outq);
}

// ---------- finalize BN ----------
__global__ void k_finalize(float* __restrict__ repl, int C, float count,
                           const float* __restrict__ g, const float* __restrict__ be,
                           float* __restrict__ ss){
  int c = threadIdx.x;
  if (c < C){
    float s = 0.f, q = 0.f;
    for (int r = 0; r < 64; r++){
      s += repl[r*256 + c];       repl[r*256 + c] = 0.f;
      q += repl[r*256 + 128 + c]; repl[r*256 + 128 + c] = 0.f;
    }
    float mean = s / count;
    float var  = fmaxf(q / count - mean*mean, 0.f);
    float inv  = rsqrtf(var + EPS_BN);
    float sc   = g[c] * inv;
    ss[c]     = sc;
    ss[C + c] = be[c] - mean*sc;
  }
}

// ---------- MFMA tail: C[64e][64c] = A(LDS) @ W^T + bias; stats; tiled store ----------
// A layout (verified m120): lane holds A[m=lane&15][k=(lane>>4)*8+j]
// C/D layout (verified m89/m91): col=lane&15, row=(lane>>4)*4+reg
template<int KT, int ST>
static __device__ __forceinline__ void mfma_tail(
    unsigned short* Aw, const float* __restrict__ Wp, const float* __restrict__ bias,
    long tb, int E, int lane, int r_idx, float* __restrict__ repl,
    uint4* __restrict__ mbuf4){
  int c15 = lane & 15, q = lane >> 4;
  short8_t bf[4][KT];
  #pragma unroll
  for (int nt = 0; nt < 4; nt++){
    int c = nt*16 + c15;
    #pragma unroll
    for (int kt = 0; kt < KT; kt++){
      const float* wr = Wp + (size_t)c*(KT*32) + kt*32 + q*8;
      union { short8_t v; unsigned short u[8]; } pb;
      #pragma unroll
      for (int j = 0; j < 8; j++) pb.u[j] = f2bf(wr[j]);
      bf[nt][kt] = pb.v;
    }
  }
  f32x4_t acc[4][4];
  #pragma unroll
  for (int mt = 0; mt < 4; mt++)
    #pragma unroll
    for (int nt = 0; nt < 4; nt++){
      float bv = bias[nt*16 + c15];
      acc[mt][nt] = (f32x4_t){bv, bv, bv, bv};
    }
  #pragma unroll
  for (int mt = 0; mt < 4; mt++){
    #pragma unroll
    for (int kt = 0; kt < KT; kt++){
      short8_t af = *(const short8_t*)&Aw[(mt*16 + c15)*ST + kt*32 + q*8];
      #pragma unroll
      for (int nt = 0; nt < 4; nt++)
        acc[mt][nt] = __builtin_amdgcn_mfma_f32_16x16x32_bf16(af, bf[nt][kt], acc[mt][nt], 0, 0, 0);
    }
  }
  // fused BN statistics (mask rows >= E)
  #pragma unroll
  for (int nt = 0; nt < 4; nt++){
    float s = 0.f, qq = 0.f;
    #pragma unroll
    for (int mt = 0; mt < 4; mt++){
      #pragma unroll
      for (int r = 0; r < 4; r++){
        long eidx = tb + mt*16 + q*4 + r;
        float v = (eidx < E) ? acc[mt][nt][r] : 0.f;
        s += v; qq += v*v;
      }
    }
    s += __shfl_xor(s, 16, 64); qq += __shfl_xor(qq, 16, 64);
    s += __shfl_xor(s, 32, 64); qq += __shfl_xor(qq, 32, 64);
    if (lane < 16){
      atomicAdd(&repl[r_idx*256 + nt*16 + lane], s);
      atomicAdd(&repl[r_idx*256 + 128 + nt*16 + lane], qq);
    }
  }
  // C -> LDS (reuse A region, cols 0..63) -> coalesced tiled-mbuf store
  __syncthreads();
  #pragma unroll
  for (int mt = 0; mt < 4; mt++)
    #pragma unroll
    for (int nt = 0; nt < 4; nt++){
      #pragma unroll
      for (int r = 0; r < 4; r++){
        int row = mt*16 + q*4 + r;
        Aw[row*ST + nt*16 + c15] = f2bf(acc[mt][nt][r]);
      }
    }
  __syncthreads();
  long t = tb + lane;
  if (t < E){
    uint4* ob = mbuf4 + (((size_t)(t >> 6)) << 9) + (t & 63);
    #pragma unroll
    for (int ci = 0; ci < 8; ci++){
      uint4 v = *(const uint4*)&Aw[lane*ST + ci*8];
      ob[ci << 6] = v;
    }
  }
}

// ---------- conv1 l2 (MFMA): z from pos, BN1+ReLU, m2 = z@W2^T ----------
__global__ void __launch_bounds__(128, 1)
k_conv1_l2(const float* __restrict__ pos, const void* __restrict__ ei,
           const int* __restrict__ bucket, int E, int N, const int* dmode,
           const float* __restrict__ W1, const float* __restrict__ b1,
           const float* __restrict__ ss1,
           const float* __restrict__ W2, const float* __restrict__ b2,
           uint4* __restrict__ mbuf4, float* __restrict__ repl){
  __shared__ unsigned short A[2][64][72];
  int m64 = dmode[0];
  int wv = threadIdx.x >> 6, lane = threadIdx.x & 63;
  long tb = (long)blockIdx.x*128 + wv*64;
  long t = tb + lane;
  int valid = (t < E);
  unsigned short* Ar = &A[wv][lane][0];
  if (valid){
    int p = bucket[t];
    int si = clampi(ld_idx(ei, (long)p, m64), 0, N-1);
    int di = clampi(ld_idx(ei, (long)E + p, m64), 0, N-1);
    float x0 = pos[di*3+0], x1 = pos[di*3+1], x2 = pos[di*3+2];
    float j0 = pos[si*3+0]-x0, j1 = pos[si*3+1]-x1, j2 = pos[si*3+2]-x2;
    #pragma unroll
    for (int c4 = 0; c4 < 64; c4 += 4){
      unsigned short h[4];
      #pragma unroll
      for (int u = 0; u < 4; u++){
        int c = c4 + u;
        float m = b1[c];
        m = fmaf(x0, W1[c*6+0], m); m = fmaf(x1, W1[c*6+1], m); m = fmaf(x2, W1[c*6+2], m);
        m = fmaf(j0, W1[c*6+3], m); m = fmaf(j1, W1[c*6+4], m); m = fmaf(j2, W1[c*6+5], m);
        h[u] = f2bf(fmaxf(fmaf(m, ss1[c], ss1[64 + c]), 0.f));
      }
      uint2 pk;
      pk.x = ((unsigned)h[1] << 16) | h[0];
      pk.y = ((unsigned)h[3] << 16) | h[2];
      *(uint2*)&Ar[c4] = pk;
    }
  } else {
    #pragma unroll
    for (int c4 = 0; c4 < 64; c4 += 4) *(uint2*)&Ar[c4] = make_uint2(0u, 0u);
  }
  __syncthreads();
  mfma_tail<2, 72>(&A[wv][0][0], W2, b2, tb, E, lane, (blockIdx.x*2 + wv) & 63, repl, mbuf4);
}

// ---------- conv1 l3 (MFMA): read m2 tile, BN2+ReLU, m3 = z@W3^T (in place) ----------
__global__ void __launch_bounds__(128, 1)
k_conv1_l3(uint4* __restrict__ mbuf4, int E,
           const float* __restrict__ ss, const float* __restrict__ W3,
           const float* __restrict__ b3, float* __restrict__ repl){
  __shared__ unsigned short A[2][64][72];
  int wv = threadIdx.x >> 6, lane = threadIdx.x & 63;
  long tb = (long)blockIdx.x*128 + wv*64;
  long t = tb + lane;
  int valid = (t < E);
  unsigned short* Ar = &A[wv][lane][0];
  if (valid){
    const uint4* base = mbuf4 + (((size_t)(t >> 6)) << 9) + (t & 63);
    #pragma unroll
    for (int k = 0; k < 8; k++){
      uint4 u = base[(size_t)(k << 6)];
      unsigned vals[4] = {u.x, u.y, u.z, u.w};
      unsigned short h[8];
      #pragma unroll
      for (int q = 0; q < 4; q++){
        int c = k*8 + q*2;
        float lo = __uint_as_float(vals[q] << 16);
        float hi = __uint_as_float(vals[q] & 0xffff0000u);
        h[q*2]   = f2bf(fmaxf(fmaf(lo, ss[c],   ss[64 + c]),   0.f));
        h[q*2+1] = f2bf(fmaxf(fmaf(hi, ss[c+1], ss[64 + c+1]), 0.f));
      }
      uint4 pk;
      pk.x = ((unsigned)h[1] << 16) | h[0];
      pk.y = ((unsigned)h[3] << 16) | h[2];
      pk.z = ((unsigned)h[5] << 16) | h[4];
      pk.w = ((unsigned)h[7] << 16) | h[6];
      *(uint4*)&Ar[k*8] = pk;
    }
  } else {
    #pragma unroll
    for (int k = 0; k < 8; k++) *(uint4*)&Ar[k*8] = make_uint4(0u,0u,0u,0u);
  }
  __syncthreads();
  mfma_tail<2, 72>(&A[wv][0][0], W3, b3, tb, E, lane, (blockIdx.x*2 + wv) & 63, repl, mbuf4);
}

// ---------- conv2 (MFMA): A = [xi | xj] bf16 passthrough, B = Wab[64][128] ----------
__global__ void __launch_bounds__(128, 1)
k_conv2(const unsigned short* __restrict__ x1, const void* __restrict__ ei,
        const int* __restrict__ bucket, int E, int N, const int* dmode,
        const float* __restrict__ Wab, const float* __restrict__ b4,
        uint4* __restrict__ mbuf4, float* __restrict__ repl){
  __shared__ unsigned short A[2][64][136];
  int m64 = dmode[0];
  int wv = threadIdx.x >> 6, lane = threadIdx.x & 63;
  long tb = (long)blockIdx.x*128 + wv*64;
  long t = tb + lane;
  int valid = (t < E);
  unsigned short* Ar = &A[wv][lane][0];
  if (valid){
    int p = bucket[t];
    int si = clampi(ld_idx(ei, (long)p, m64), 0, N-1);
    int di = clampi(ld_idx(ei, (long)E + p, m64), 0, N-1);
    const uint4* xi4 = (const uint4*)(x1 + (size_t)di*64);
    const uint4* xj4 = (const uint4*)(x1 + (size_t)si*64);
    #pragma unroll
    for (int k = 0; k < 8; k++) *(uint4*)&Ar[k*8]      = xi4[k];
    #pragma unroll
    for (int k = 0; k < 8; k++) *(uint4*)&Ar[64 + k*8] = xj4[k];
  } else {
    #pragma unroll
    for (int k = 0; k < 16; k++) *(uint4*)&Ar[k*8] = make_uint4(0u,0u,0u,0u);
  }
  __syncthreads();
  mfma_tail<4, 136>(&A[wv][0][0], Wab, b4, tb, E, lane, (blockIdx.x*2 + wv) & 63, repl, mbuf4);
}

// ---------- aggregate: sequential CSR rows in tiled layout ----------
__global__ void k_aggregate(const unsigned short* __restrict__ mbuf,
                            const int* __restrict__ offs, int N, int E,
                            const float* __restrict__ ss, unsigned short* __restrict__ xout){
  int wave = threadIdx.x >> 6;
  int lane = threadIdx.x & 63;
  int n = blockIdx.x*4 + wave;
  if (n >= N) return;
  int s0 = clampi(offs[n], 0, E);
  int s1 = clampi(offs[n + 1], s0, E);
  float sc = ss[lane], sh = ss[64 + lane];
  int g = lane >> 3, pz = lane & 7;
  float acc = 0.f;
  for (int k = s0; k < s1; k++){
    size_t idx = (((size_t)(k >> 6)) << 12) + (g << 9) + ((k & 63) << 3) + pz;
    float v = bf2f(mbuf[idx]);
    acc = fmaxf(acc, fmaf(v, sc, sh));
  }
  xout[(size_t)n*64 + lane] = f2bf(acc);
}

// ---------- lin5: 16 nodes x 16 col-groups per block, LDS-staged inputs ----------
static __device__ __forceinline__ uint4 pack8(const float* acc){
  uint4 u;
  u.x = ((unsigned)f2bf(acc[1]) << 16) | (unsigned)f2bf(acc[0]);
  u.y = ((unsigned)f2bf(acc[3]) << 16) | (unsigned)f2bf(acc[2]);
  u.z = ((unsigned)f2bf(acc[5]) << 16) | (unsigned)f2bf(acc[4]);
  u.w = ((unsigned)f2bf(acc[7]) << 16) | (unsigned)f2bf(acc[6]);
  return u;
}

__global__ void k_lin5(const unsigned short* __restrict__ x1, const unsigned short* __restrict__ x2,
                       int N, const float* __restrict__ W5, const float* __restrict__ b5,
                       unsigned short* __restrict__ y5){
  __shared__ float xs[16][130];
  int t = threadIdx.x;            // 256
  int nb0 = blockIdx.x * 16;
  {
    int row = t >> 4, col4 = (t & 15) * 4;
    if (nb0 + row < N){
      uint2 a = *(const uint2*)(x1 + (size_t)(nb0 + row)*64 + col4);
      uint2 b = *(const uint2*)(x2 + (size_t)(nb0 + row)*64 + col4);
      xs[row][col4+0] = __uint_as_float(a.x << 16);
      xs[row][col4+1] = __uint_as_float(a.x & 0xffff0000u);
      xs[row][col4+2] = __uint_as_float(a.y << 16);
      xs[row][col4+3] = __uint_as_float(a.y & 0xffff0000u);
      xs[row][64+col4+0] = __uint_as_float(b.x << 16);
      xs[row][64+col4+1] = __uint_as_float(b.x & 0xffff0000u);
      xs[row][64+col4+2] = __uint_as_float(b.y << 16);
      xs[row][64+col4+3] = __uint_as_float(b.y & 0xffff0000u);
    } else {
      #pragma unroll
      for (int q = 0; q < 4; q++){ xs[row][col4+q] = 0.f; xs[row][64+col4+q] = 0.f; }
    }
  }
  __syncthreads();
  int node = t >> 4, cg = t & 15;
  int n = nb0 + node;
  const float* xr = xs[node];
  const float* wbase = W5 + (size_t)(cg*8)*128;
  float acc[8];
  #pragma unroll
  for (int j = 0; j < 8; j++) acc[j] = b5[cg*8 + j];
  for (int i = 0; i < 128; i++){
    float xv = xr[i];
    #pragma unroll
    for (int j = 0; j < 8; j++) acc[j] = fmaf(xv, wbase[j*128 + i], acc[j]);
  }
  if (n < N) *(uint4*)(y5 + (size_t)n*128 + cg*8) = pack8(acc);
}

// ---------- column stats over row-major bf16 (y5 only) ----------
__global__ void k_stats_bf16(const unsigned short* __restrict__ buf, long total, int cmask,
                             float* __restrict__ repl){
  int tid = blockIdx.x*256 + threadIdx.x;
  int c = tid & cmask;
  long stride = (long)gridDim.x * 256;
  float s = 0.f, q = 0.f;
  long i = tid;
  for (; i + 3*stride < total; i += 4*stride){
    float v0 = bf2f(buf[i]);
    float v1 = bf2f(buf[i +   stride]);
    float v2 = bf2f(buf[i + 2*stride]);
    float v3 = bf2f(buf[i + 3*stride]);
    s += (v0 + v1) + (v2 + v3);
    q += (v0*v0 + v1*v1) + (v2*v2 + v3*v3);
  }
  for (; i < total; i += stride){ float v = bf2f(buf[i]); s += v; q += v*v; }
  int r = (tid >> 6) & 63;
  atomicAdd(&repl[r*256 + c], s);
  atomicAdd(&repl[r*256 + 128 + c], q);
}

// ---------- pool ----------
__global__ void k_pool(const unsigned short* __restrict__ y5, const void* __restrict__ batch, int N,
                       const int* dmode, const float* __restrict__ ss5, unsigned int* __restrict__ pooled){
  int m64 = dmode[0];
  int c = threadIdx.x;               // 128 threads
  int n0 = blockIdx.x*512;
  int n1 = min(n0 + 512, N);
  float sc = ss5[c], sh = ss5[128 + c];
  int curb = -1; float curm = 0.f;
  for (int n = n0; n < n1; n++){
    int b = clampi(ld_idx(batch, (long)n, m64), 0, 63);
    float v = fmaf(bf2f(y5[(size_t)n*128 + c]), sc, sh);
    if (b != curb){
      if (curb >= 0) atomicMax(&pooled[curb*128 + c], __float_as_uint(fmaxf(curm, 0.f)));
      curb = b; curm = v;
    } else {
      curm = fmaxf(curm, v);
    }
  }
  if (curb >= 0) atomicMax(&pooled[curb*128 + c], __float_as_uint(fmaxf(curm, 0.f)));
}

// ---------- head ----------
__global__ void k_pooled2f(const unsigned int* __restrict__ pooled, float* __restrict__ pf){
  int i = blockIdx.x*256 + threadIdx.x;
  if (i < 8192) pf[i] = __uint_as_float(pooled[i]);
}

__global__ void k_linH(const float* __restrict__ X, const float* __restrict__ W,
                       const float* __restrict__ b, int CI, int CO, float* __restrict__ Y){
  int cell = blockIdx.x*256 + threadIdx.x;
  if (cell >= 64*CO) return;
  int r = cell / CO, c = cell - r*CO;
  const float* xr = X + r*CI;
  const float* wr = W + c*CI;
  float a = b[c];
  for (int j = 0; j < CI; j++) a = fmaf(xr[j], wr[j], a);
  Y[cell] = a;
}

__global__ void k_bnH(const float* __restrict__ Y, int CO,
                      const float* __restrict__ g, const float* __restrict__ be,
                      float* __restrict__ ss){
  int c = threadIdx.x;
  if (c >= CO) return;
  float s = 0.f;
  for (int r = 0; r < 64; r++) s += Y[r*CO + c];
  float mean = s * (1.f/64.f);
  float q = 0.f;
  for (int r = 0; r < 64; r++){ float d = Y[r*CO + c] - mean; q += d*d; }
  float var = fmaxf(q * (1.f/64.f), 0.f);
  float inv = rsqrtf(var + EPS_BN);
  float sc = g[c] * inv;
  ss[c] = sc;
  ss[CO + c] = be[c] - mean*sc;
}

__global__ void k_bnreluH(float* __restrict__ Y, int CO, const float* __restrict__ ss){
  int cell = blockIdx.x*256 + threadIdx.x;
  if (cell >= 64*CO) return;
  int c = cell % CO;
  Y[cell] = fmaxf(fmaf(Y[cell], ss[c], ss[CO + c]), 0.f);
}

__global__ void k_logsm(const float* __restrict__ Z, float* __restrict__ out){
  int r = threadIdx.x;   // 64 threads
  const float* zr = Z + r*40;
  float m = zr[0];
  for (int c = 1; c < 40; c++) m = fmaxf(m, zr[c]);
  float s = 0.f;
  for (int c = 0; c < 40; c++) s += expf(zr[c] - m);
  float ls = logf(s);
  for (int c = 0; c < 40; c++) out[r*40 + c] = zr[c] - m - ls;
}

// ---------- launch ----------
extern "C" void kernel_launch(void* const* d_in, const int* in_sizes, int n_in,
                              void* d_out, int out_size, void* d_ws, size_t ws_size,
                              hipStream_t stream) {
  const void* pos   = d_in[0];
  const void* ei    = d_in[1];
  const void* batch = d_in[2];
  (void)n_in;

  const int N = in_sizes[0] / 3;
  const int E = in_sizes[1] / 2;
  const int nTiles = cdiv(E, 64);

  // ---- workspace layout ----
  auto al = [](size_t x){ return (x + 255) & ~(size_t)255; };
  char* w = (char*)d_ws;
  size_t o = 0;
  float* repl = (float*)(w + o);                 o += (size_t)64*256*4;
  unsigned int* pooled = (unsigned int*)(w + o); o += (size_t)64*128*4;
  int* deg = (int*)(w + o);                      o += al((size_t)4*N);
  size_t zero_bytes = o;
  int* dmode = (int*)(w + o);                    o += 256;
  int* offs = (int*)(w + o);                     o += al((size_t)4*(N + 1));
  int* cursor = (int*)(w + o);                   o += al((size_t)4*N);
  int* part = (int*)(w + o);                     o += 4096;
  int* bucket = (int*)(w + o);                   o += al((size_t)4*E);
  float* ss1 = (float*)(w + o);                  o += 1024;
  float* ss2 = (float*)(w + o);                  o += 1024;
  float* ss3 = (float*)(w + o);                  o += 1024;
  float* ss4 = (float*)(w + o);                  o += 1024;
  float* ss5 = (float*)(w + o);                  o += 1024;
  float* ssH = (float*)(w + o);                  o += 1024;
  float* Wab = (float*)(w + o);                  o += (size_t)8192*4;
  float* pooledF = (float*)(w + o);              o += (size_t)8192*4;
  float* Y6 = (float*)(w + o);                   o += (size_t)8192*4;
  float* Y7 = (float*)(w + o);                   o += (size_t)8192*4;
  float* Zl = (float*)(w + o);                   o += al((size_t)2560*4);
  // fp32 expansion region
  float* expBase = (float*)(w + o);
  float* ep = expBase;
  float* epos = ep; ep += (size_t)3*N;
  float* eW[9], *eb[9], *eg[9], *ebe[9];
  const int wsz[9] = {0, 64*6, 64*64, 64*64, 64*128, 128*128, 128*128, 128*128, 40*128};
  const int bsz[9] = {0, 64, 64, 64, 64, 128, 128, 128, 40};
  for (int i = 1; i <= 8; i++){
    eW[i] = ep; ep += wsz[i];
    eb[i] = ep; ep += bsz[i];
    if (i < 8){ eg[i] = ep; ep += bsz[i]; ebe[i] = ep; ep += bsz[i]; }
  }
  long expCount = (long)(ep - expBase);
  o += al((size_t)expCount * 4);
  unsigned short* x1b = (unsigned short*)(w + o); o += al((size_t)2*64*N);
  unsigned short* x2b = (unsigned short*)(w + o); o += al((size_t)2*64*N);
  unsigned short* y5b = (unsigned short*)(w + o); o += al((size_t)2*128*N);
  unsigned short* mbuf = (unsigned short*)(w + o); o += al((size_t)8192*nTiles);
  uint4* mbuf4 = (uint4*)mbuf;

  float* out_f = (float*)d_out;
  if (ws_size < o){
    k_sentinel<<<cdiv(out_size,256), 256, 0, stream>>>(out_f, out_size);
    return;
  }

  hipMemsetAsync(w, 0, zero_bytes, stream);
  k_detect<<<1, 256, 0, stream>>>(ei, pos, dmode);

  // expand all float inputs -> fp32
  ExpArgs ea;
  int it = 0;
  ea.it[it++] = {pos, epos, 3*N};
  int di_idx = 3;
  for (int i = 1; i <= 8; i++){
    ea.it[it++] = {d_in[di_idx++], eW[i], wsz[i]};
    ea.it[it++] = {d_in[di_idx++], eb[i], bsz[i]};
    if (i < 8){
      ea.it[it++] = {d_in[di_idx++], eg[i], bsz[i]};
      ea.it[it++] = {d_in[di_idx++], ebe[i], bsz[i]};
    }
  }
  k_expand<<<dim3(cdiv(3*N,256), 31), 256, 0, stream>>>(ea, it, dmode);
  k_prepW4<<<32, 256, 0, stream>>>(eW[4], Wab);

  const int nb = cdiv(N, 1024);
  // CSR build
  k_hist<<<cdiv(E,256), 256, 0, stream>>>(ei, E, N, dmode, deg);
  k_scan1<<<nb, 1024, 0, stream>>>(deg, N, offs, part);
  k_scan2<<<1, 1024, 0, stream>>>(part, nb);
  k_scan3<<<nb, 1024, 0, stream>>>(deg, part, N, E, offs, cursor);
  k_fill<<<cdiv(E,256), 256, 0, stream>>>(ei, E, N, dmode, cursor, bucket);

  // conv1 (MFMA, fused stats; edges in bucket order)
  k_m1stats<<<cdiv(E,2048), 256, 0, stream>>>(epos, ei, E, N, dmode, eW[1], eb[1], repl);
  k_finalize<<<1, 128, 0, stream>>>(repl, 64, (float)E, eg[1], ebe[1], ss1);
  k_conv1_l2<<<cdiv(E,128), 128, 0, stream>>>(epos, ei, bucket, E, N, dmode,
                                              eW[1], eb[1], ss1, eW[2], eb[2], mbuf4, repl);
  k_finalize<<<1, 128, 0, stream>>>(repl, 64, (float)E, eg[2], ebe[2], ss2);
  k_conv1_l3<<<cdiv(E,128), 128, 0, stream>>>(mbuf4, E, ss2, eW[3], eb[3], repl);
  k_finalize<<<1, 128, 0, stream>>>(repl, 64, (float)E, eg[3], ebe[3], ss3);
  k_aggregate<<<cdiv(N,4), 256, 0, stream>>>(mbuf, offs, N, E, ss3, x1b);

  // conv2 (MFMA)
  k_conv2<<<cdiv(E,128), 128, 0, stream>>>(x1b, ei, bucket, E, N, dmode, Wab, eb[4], mbuf4, repl);
  k_finalize<<<1, 128, 0, stream>>>(repl, 64, (float)E, eg[4], ebe[4], ss4);
  k_aggregate<<<cdiv(N,4), 256, 0, stream>>>(mbuf, offs, N, E, ss4, x2b);

  // lin5 + BN5 stats + pool
  k_lin5<<<cdiv(N,16), 256, 0, stream>>>(x1b, x2b, N, eW[5], eb[5], y5b);
  k_stats_bf16<<<512, 256, 0, stream>>>(y5b, (long)N*128, 127, repl);
  k_finalize<<<1, 128, 0, stream>>>(repl, 128, (float)N, eg[5], ebe[5], ss5);
  k_pool<<<cdiv(N,512), 128, 0, stream>>>(y5b, batch, N, dmode, ss5, pooled);

  // head
  k_pooled2f<<<32, 256, 0, stream>>>(pooled, pooledF);
  k_linH<<<32, 256, 0, stream>>>(pooledF, eW[6], eb[6], 128, 128, Y6);
  k_bnH<<<1, 128, 0, stream>>>(Y6, 128, eg[6], ebe[6], ssH);
  k_bnreluH<<<32, 256, 0, stream>>>(Y6, 128, ssH);
  k_linH<<<32, 256, 0, stream>>>(Y6, eW[7], eb[7], 128, 128, Y7);
  k_bnH<<<1, 128, 0, stream>>>(Y7, 128, eg[7], ebe[7], ssH);
  k_bnreluH<<<32, 256, 0, stream>>>(Y7, 128, ssH);
  k_linH<<<10, 256, 0, stream>>>(Y7, eW[8], eb[8], 128, 40, Zl);
  k_logsm<<<1, 64, 0, stream>>>(Zl, out_f);
}

// Round 13
// 1238.754 us; speedup vs baseline: 10.1552x; 1.4959x over previous
//
#include <hip/hip_runtime.h>
#include <math.h>

#define EPS_BN 1e-5f

// Wire formats (established r0-r8): float inputs = bf16 (runtime-detected),
// int inputs = int32/int64 (runtime-detected), OUTPUT = FP32.
// mbuf layout: [tile=64 edges][8 chunks][64 edge-slots][16B]; edges in CSR-bucket order.
// r12: conv kernels as wave-level MFMA GEMMs (16x16x32 bf16) -> 6.8ms -> 1.85ms.
// r13: k_lin5 -> MFMA with fused BN5 stats (was 720us scalar GEMM, issue-bound).

typedef short short8_t __attribute__((ext_vector_type(8)));
typedef float f32x4_t  __attribute__((ext_vector_type(4)));

// ---------- helpers ----------
static __device__ __forceinline__ float bf2f(unsigned short b){
  return __uint_as_float(((unsigned)b) << 16);
}
static __device__ __forceinline__ unsigned short f2bf(float f){
  unsigned u = __float_as_uint(f);
  u += 0x7fffu + ((u >> 16) & 1u);   // RNE (finite values only)
  return (unsigned short)(u >> 16);
}
static inline int cdiv(int a, int b){ return (a + b - 1) / b; }
static __device__ __forceinline__ int clampi(int v, int lo, int hi){
  return v < lo ? lo : (v > hi ? hi : v);
}
static __device__ __forceinline__ int ld_idx(const void* p, long e, int m64){
  return m64 ? (int)((const long long*)p)[e] : ((const int*)p)[e];
}

// ---------- sentinel ----------
__global__ void k_sentinel(float* out, int n){
  int i = blockIdx.x*256 + threadIdx.x;
  if (i < n) out[i] = -12288.0f;
}

// ---------- runtime dtype detection ----------
__global__ void k_detect(const void* ei, const void* pos, int* dmode){
  __shared__ int nz, ff;
  if (threadIdx.x == 0){ nz = 0; ff = 0; }
  __syncthreads();
  const int* w32 = (const int*)ei;
  if (w32[1 + 2*threadIdx.x] != 0) nz = 1;
  const unsigned short* ph = (const unsigned short*)pos;
  int bad = 0;
  for (int i = threadIdx.x; i < 8192; i += 256)
    if (((ph[i] >> 7) & 0xFF) == 0xFF) bad = 1;
  if (bad) ff = 1;
  __syncthreads();
  if (threadIdx.x == 0){ dmode[0] = nz ? 0 : 1; dmode[1] = ff; }
}

// ---------- expand float inputs -> fp32 scratch ----------
struct ExpItem { const void* s; float* d; int n; };
struct ExpArgs { ExpItem it[31]; };
__global__ void k_expand(ExpArgs a, int cnt, const int* dmode){
  int i = blockIdx.y;
  if (i >= cnt) return;
  int m32 = dmode[1];
  int t = blockIdx.x*256 + threadIdx.x;
  if (t < a.it[i].n){
    a.it[i].d[t] = m32 ? ((const float*)a.it[i].s)[t]
                       : bf2f(((const unsigned short*)a.it[i].s)[t]);
  }
}

// ---------- Wab prep: [64][128] = [Wa | Wb], Wa = A-part minus B-part ----------
__global__ void k_prepW4(const float* __restrict__ W4, float* __restrict__ Wab){
  int i = blockIdx.x*256 + threadIdx.x;
  if (i < 8192){
    int c = i >> 7, k = i & 127;
    float v;
    if (k < 64) v = W4[c*128 + k] - W4[c*128 + 64 + k];
    else        v = W4[c*128 + k];
    Wab[i] = v;
  }
}

// ---------- CSR build ----------
__global__ void k_hist(const void* __restrict__ ei, int E, int N, const int* dmode, int* __restrict__ deg){
  int m64 = dmode[0];
  int e = blockIdx.x*256 + threadIdx.x;
  if (e < E) atomicAdd(&deg[clampi(ld_idx(ei, (long)E + e, m64), 0, N-1)], 1);
}

__global__ void k_scan1(const int* __restrict__ deg, int N, int* __restrict__ incl, int* __restrict__ part){
  __shared__ int s[1024];
  int i = blockIdx.x*1024 + threadIdx.x;
  s[threadIdx.x] = (i < N) ? deg[i] : 0;
  __syncthreads();
  for (int off = 1; off < 1024; off <<= 1){
    int t = (threadIdx.x >= off) ? s[threadIdx.x - off] : 0;
    __syncthreads();
    s[threadIdx.x] += t;
    __syncthreads();
  }
  if (i < N) incl[i] = s[threadIdx.x];
  if (threadIdx.x == 1023) part[blockIdx.x] = s[1023];
}

__global__ void k_scan2(int* __restrict__ part, int nb){
  __shared__ int s[1024];
  int i = threadIdx.x;
  s[i] = (i < nb) ? part[i] : 0;
  __syncthreads();
  for (int off = 1; off < 1024; off <<= 1){
    int t = (i >= off) ? s[i - off] : 0;
    __syncthreads();
    s[i] += t;
    __syncthreads();
  }
  if (i < nb) part[i] = s[i];
}

__global__ void k_scan3(const int* __restrict__ deg, const int* __restrict__ part, int N, int E,
                        int* __restrict__ offs, int* __restrict__ cursor){
  int i = blockIdx.x*1024 + threadIdx.x;
  if (i < N){
    int prev = (blockIdx.x > 0) ? part[blockIdx.x - 1] : 0;
    int v = prev + offs[i] - deg[i];
    offs[i] = v;
    cursor[i] = v;
  }
  if (blockIdx.x == 0 && threadIdx.x == 0) offs[N] = E;
}

__global__ void k_fill(const void* __restrict__ ei, int E, int N, const int* dmode,
                       int* __restrict__ cursor, int* __restrict__ bucket){
  int m64 = dmode[0];
  int e = blockIdx.x*256 + threadIdx.x;
  if (e < E){
    int p = atomicAdd(&cursor[clampi(ld_idx(ei, (long)E + e, m64), 0, N-1)], 1);
    if (p >= 0 && p < E) bucket[p] = e;
  }
}

// ---------- conv1 layer1 stats ----------
__global__ void __launch_bounds__(256, 1)
k_m1stats(const float* __restrict__ pos, const void* __restrict__ ei,
          int E, int N, const int* dmode,
          const float* __restrict__ W1, const float* __restrict__ b1,
          float* __restrict__ repl){
  int m64 = dmode[0];
  int lane = threadIdx.x & 63;
  int flatwave = (blockIdx.x*256 + threadIdx.x) >> 6;
  long base = (long)flatwave * 512;
  float as[64], aq[64];
  #pragma unroll
  for (int c = 0; c < 64; c++){ as[c] = 0.f; aq[c] = 0.f; }
  for (int k = 0; k < 8; k++){
    long e = base + (long)k*64 + lane;
    if (e < E){
      int si = clampi(ld_idx(ei, e, m64), 0, N-1);
      int di = clampi(ld_idx(ei, (long)E + e, m64), 0, N-1);
      float x0 = pos[di*3+0], x1 = pos[di*3+1], x2 = pos[di*3+2];
      float j0 = pos[si*3+0]-x0, j1 = pos[si*3+1]-x1, j2 = pos[si*3+2]-x2;
      #pragma unroll
      for (int c = 0; c < 64; c++){
        float m = b1[c];
        m = fmaf(x0, W1[c*6+0], m); m = fmaf(x1, W1[c*6+1], m); m = fmaf(x2, W1[c*6+2], m);
        m = fmaf(j0, W1[c*6+3], m); m = fmaf(j1, W1[c*6+4], m); m = fmaf(j2, W1[c*6+5], m);
        as[c] += m; aq[c] += m*m;
      }
    }
  }
  float outs = 0.f, outq = 0.f;
  #pragma unroll
  for (int c = 0; c < 64; c++){
    float s = as[c], q = aq[c];
    #pragma unroll
    for (int m = 1; m < 64; m <<= 1){ s += __shfl_xor(s, m, 64); q += __shfl_xor(q, m, 64); }
    if (lane == c){ outs = s; outq = q; }
  }
  int r = flatwave & 63;
  atomicAdd(&repl[r*256 + lane], outs);
  atomicAdd(&repl[r*256 + 128 + lane], outq);
}

// ---------- finalize BN ----------
__global__ void k_finalize(float* __restrict__ repl, int C, float count,
                           const float* __restrict__ g, const float* __restrict__ be,
                           float* __restrict__ ss){
  int c = threadIdx.x;
  if (c < C){
    float s = 0.f, q = 0.f;
    for (int r = 0; r < 64; r++){
      s += repl[r*256 + c];       repl[r*256 + c] = 0.f;
      q += repl[r*256 + 128 + c]; repl[r*256 + 128 + c] = 0.f;
    }
    float mean = s / count;
    float var  = fmaxf(q / count - mean*mean, 0.f);
    float inv  = rsqrtf(var + EPS_BN);
    float sc   = g[c] * inv;
    ss[c]     = sc;
    ss[C + c] = be[c] - mean*sc;
  }
}

// ---------- MFMA tail: C[64e][64c] = A(LDS) @ W^T + bias; stats; tiled store ----------
// A layout (verified m120): lane holds A[m=lane&15][k=(lane>>4)*8+j]
// C/D layout (verified m89/m91): col=lane&15, row=(lane>>4)*4+reg
template<int KT, int ST>
static __device__ __forceinline__ void mfma_tail(
    unsigned short* Aw, const float* __restrict__ Wp, const float* __restrict__ bias,
    long tb, int E, int lane, int r_idx, float* __restrict__ repl,
    uint4* __restrict__ mbuf4){
  int c15 = lane & 15, q = lane >> 4;
  short8_t bf[4][KT];
  #pragma unroll
  for (int nt = 0; nt < 4; nt++){
    int c = nt*16 + c15;
    #pragma unroll
    for (int kt = 0; kt < KT; kt++){
      const float* wr = Wp + (size_t)c*(KT*32) + kt*32 + q*8;
      union { short8_t v; unsigned short u[8]; } pb;
      #pragma unroll
      for (int j = 0; j < 8; j++) pb.u[j] = f2bf(wr[j]);
      bf[nt][kt] = pb.v;
    }
  }
  f32x4_t acc[4][4];
  #pragma unroll
  for (int mt = 0; mt < 4; mt++)
    #pragma unroll
    for (int nt = 0; nt < 4; nt++){
      float bv = bias[nt*16 + c15];
      acc[mt][nt] = (f32x4_t){bv, bv, bv, bv};
    }
  #pragma unroll
  for (int mt = 0; mt < 4; mt++){
    #pragma unroll
    for (int kt = 0; kt < KT; kt++){
      short8_t af = *(const short8_t*)&Aw[(mt*16 + c15)*ST + kt*32 + q*8];
      #pragma unroll
      for (int nt = 0; nt < 4; nt++)
        acc[mt][nt] = __builtin_amdgcn_mfma_f32_16x16x32_bf16(af, bf[nt][kt], acc[mt][nt], 0, 0, 0);
    }
  }
  // fused BN statistics (mask rows >= E)
  #pragma unroll
  for (int nt = 0; nt < 4; nt++){
    float s = 0.f, qq = 0.f;
    #pragma unroll
    for (int mt = 0; mt < 4; mt++){
      #pragma unroll
      for (int r = 0; r < 4; r++){
        long eidx = tb + mt*16 + q*4 + r;
        float v = (eidx < E) ? acc[mt][nt][r] : 0.f;
        s += v; qq += v*v;
      }
    }
    s += __shfl_xor(s, 16, 64); qq += __shfl_xor(qq, 16, 64);
    s += __shfl_xor(s, 32, 64); qq += __shfl_xor(qq, 32, 64);
    if (lane < 16){
      atomicAdd(&repl[r_idx*256 + nt*16 + lane], s);
      atomicAdd(&repl[r_idx*256 + 128 + nt*16 + lane], qq);
    }
  }
  // C -> LDS (reuse A region, cols 0..63) -> coalesced tiled-mbuf store
  __syncthreads();
  #pragma unroll
  for (int mt = 0; mt < 4; mt++)
    #pragma unroll
    for (int nt = 0; nt < 4; nt++){
      #pragma unroll
      for (int r = 0; r < 4; r++){
        int row = mt*16 + q*4 + r;
        Aw[row*ST + nt*16 + c15] = f2bf(acc[mt][nt][r]);
      }
    }
  __syncthreads();
  long t = tb + lane;
  if (t < E){
    uint4* ob = mbuf4 + (((size_t)(t >> 6)) << 9) + (t & 63);
    #pragma unroll
    for (int ci = 0; ci < 8; ci++){
      uint4 v = *(const uint4*)&Aw[lane*ST + ci*8];
      ob[ci << 6] = v;
    }
  }
}

// ---------- conv1 l2 (MFMA): z from pos, BN1+ReLU, m2 = z@W2^T ----------
__global__ void __launch_bounds__(128, 1)
k_conv1_l2(const float* __restrict__ pos, const void* __restrict__ ei,
           const int* __restrict__ bucket, int E, int N, const int* dmode,
           const float* __restrict__ W1, const float* __restrict__ b1,
           const float* __restrict__ ss1,
           const float* __restrict__ W2, const float* __restrict__ b2,
           uint4* __restrict__ mbuf4, float* __restrict__ repl){
  __shared__ unsigned short A[2][64][72];
  int m64 = dmode[0];
  int wv = threadIdx.x >> 6, lane = threadIdx.x & 63;
  long tb = (long)blockIdx.x*128 + wv*64;
  long t = tb + lane;
  int valid = (t < E);
  unsigned short* Ar = &A[wv][lane][0];
  if (valid){
    int p = bucket[t];
    int si = clampi(ld_idx(ei, (long)p, m64), 0, N-1);
    int di = clampi(ld_idx(ei, (long)E + p, m64), 0, N-1);
    float x0 = pos[di*3+0], x1 = pos[di*3+1], x2 = pos[di*3+2];
    float j0 = pos[si*3+0]-x0, j1 = pos[si*3+1]-x1, j2 = pos[si*3+2]-x2;
    #pragma unroll
    for (int c4 = 0; c4 < 64; c4 += 4){
      unsigned short h[4];
      #pragma unroll
      for (int u = 0; u < 4; u++){
        int c = c4 + u;
        float m = b1[c];
        m = fmaf(x0, W1[c*6+0], m); m = fmaf(x1, W1[c*6+1], m); m = fmaf(x2, W1[c*6+2], m);
        m = fmaf(j0, W1[c*6+3], m); m = fmaf(j1, W1[c*6+4], m); m = fmaf(j2, W1[c*6+5], m);
        h[u] = f2bf(fmaxf(fmaf(m, ss1[c], ss1[64 + c]), 0.f));
      }
      uint2 pk;
      pk.x = ((unsigned)h[1] << 16) | h[0];
      pk.y = ((unsigned)h[3] << 16) | h[2];
      *(uint2*)&Ar[c4] = pk;
    }
  } else {
    #pragma unroll
    for (int c4 = 0; c4 < 64; c4 += 4) *(uint2*)&Ar[c4] = make_uint2(0u, 0u);
  }
  __syncthreads();
  mfma_tail<2, 72>(&A[wv][0][0], W2, b2, tb, E, lane, (blockIdx.x*2 + wv) & 63, repl, mbuf4);
}

// ---------- conv1 l3 (MFMA): read m2 tile, BN2+ReLU, m3 = z@W3^T (in place) ----------
__global__ void __launch_bounds__(128, 1)
k_conv1_l3(uint4* __restrict__ mbuf4, int E,
           const float* __restrict__ ss, const float* __restrict__ W3,
           const float* __restrict__ b3, float* __restrict__ repl){
  __shared__ unsigned short A[2][64][72];
  int wv = threadIdx.x >> 6, lane = threadIdx.x & 63;
  long tb = (long)blockIdx.x*128 + wv*64;
  long t = tb + lane;
  int valid = (t < E);
  unsigned short* Ar = &A[wv][lane][0];
  if (valid){
    const uint4* base = mbuf4 + (((size_t)(t >> 6)) << 9) + (t & 63);
    #pragma unroll
    for (int k = 0; k < 8; k++){
      uint4 u = base[(size_t)(k << 6)];
      unsigned vals[4] = {u.x, u.y, u.z, u.w};
      unsigned short h[8];
      #pragma unroll
      for (int q = 0; q < 4; q++){
        int c = k*8 + q*2;
        float lo = __uint_as_float(vals[q] << 16);
        float hi = __uint_as_float(vals[q] & 0xffff0000u);
        h[q*2]   = f2bf(fmaxf(fmaf(lo, ss[c],   ss[64 + c]),   0.f));
        h[q*2+1] = f2bf(fmaxf(fmaf(hi, ss[c+1], ss[64 + c+1]), 0.f));
      }
      uint4 pk;
      pk.x = ((unsigned)h[1] << 16) | h[0];
      pk.y = ((unsigned)h[3] << 16) | h[2];
      pk.z = ((unsigned)h[5] << 16) | h[4];
      pk.w = ((unsigned)h[7] << 16) | h[6];
      *(uint4*)&Ar[k*8] = pk;
    }
  } else {
    #pragma unroll
    for (int k = 0; k < 8; k++) *(uint4*)&Ar[k*8] = make_uint4(0u,0u,0u,0u);
  }
  __syncthreads();
  mfma_tail<2, 72>(&A[wv][0][0], W3, b3, tb, E, lane, (blockIdx.x*2 + wv) & 63, repl, mbuf4);
}

// ---------- conv2 (MFMA): A = [xi | xj] bf16 passthrough, B = Wab[64][128] ----------
__global__ void __launch_bounds__(128, 1)
k_conv2(const unsigned short* __restrict__ x1, const void* __restrict__ ei,
        const int* __restrict__ bucket, int E, int N, const int* dmode,
        const float* __restrict__ Wab, const float* __restrict__ b4,
        uint4* __restrict__ mbuf4, float* __restrict__ repl){
  __shared__ unsigned short A[2][64][136];
  int m64 = dmode[0];
  int wv = threadIdx.x >> 6, lane = threadIdx.x & 63;
  long tb = (long)blockIdx.x*128 + wv*64;
  long t = tb + lane;
  int valid = (t < E);
  unsigned short* Ar = &A[wv][lane][0];
  if (valid){
    int p = bucket[t];
    int si = clampi(ld_idx(ei, (long)p, m64), 0, N-1);
    int di = clampi(ld_idx(ei, (long)E + p, m64), 0, N-1);
    const uint4* xi4 = (const uint4*)(x1 + (size_t)di*64);
    const uint4* xj4 = (const uint4*)(x1 + (size_t)si*64);
    #pragma unroll
    for (int k = 0; k < 8; k++) *(uint4*)&Ar[k*8]      = xi4[k];
    #pragma unroll
    for (int k = 0; k < 8; k++) *(uint4*)&Ar[64 + k*8] = xj4[k];
  } else {
    #pragma unroll
    for (int k = 0; k < 16; k++) *(uint4*)&Ar[k*8] = make_uint4(0u,0u,0u,0u);
  }
  __syncthreads();
  mfma_tail<4, 136>(&A[wv][0][0], Wab, b4, tb, E, lane, (blockIdx.x*2 + wv) & 63, repl, mbuf4);
}

// ---------- aggregate: sequential CSR rows in tiled layout ----------
__global__ void k_aggregate(const unsigned short* __restrict__ mbuf,
                            const int* __restrict__ offs, int N, int E,
                            const float* __restrict__ ss, unsigned short* __restrict__ xout){
  int wave = threadIdx.x >> 6;
  int lane = threadIdx.x & 63;
  int n = blockIdx.x*4 + wave;
  if (n >= N) return;
  int s0 = clampi(offs[n], 0, E);
  int s1 = clampi(offs[n + 1], s0, E);
  float sc = ss[lane], sh = ss[64 + lane];
  int g = lane >> 3, pz = lane & 7;
  float acc = 0.f;
  for (int k = s0; k < s1; k++){
    size_t idx = (((size_t)(k >> 6)) << 12) + (g << 9) + ((k & 63) << 3) + pz;
    float v = bf2f(mbuf[idx]);
    acc = fmaxf(acc, fmaf(v, sc, sh));
  }
  xout[(size_t)n*64 + lane] = f2bf(acc);
}

// ---------- lin5 (MFMA): y5 = cat(x1,x2)@W5^T + b5, fused BN5 stats ----------
// Two 64-channel halves per wave; A/W inputs are exact bf16 (no new rounding).
__global__ void __launch_bounds__(128, 1)
k_lin5m(const unsigned short* __restrict__ x1, const unsigned short* __restrict__ x2,
        int N, const float* __restrict__ W5, const float* __restrict__ b5,
        unsigned short* __restrict__ y5, float* __restrict__ repl){
  __shared__ unsigned short A[2][64][136];
  __shared__ unsigned short Cb[2][64][72];
  int wv = threadIdx.x >> 6, lane = threadIdx.x & 63;
  long nb0 = (long)blockIdx.x*128 + wv*64;
  long n = nb0 + lane;
  unsigned short* Ar = &A[wv][lane][0];
  if (n < N){
    const uint4* a4 = (const uint4*)(x1 + (size_t)n*64);
    const uint4* b4 = (const uint4*)(x2 + (size_t)n*64);
    #pragma unroll
    for (int k = 0; k < 8; k++) *(uint4*)&Ar[k*8]      = a4[k];
    #pragma unroll
    for (int k = 0; k < 8; k++) *(uint4*)&Ar[64 + k*8] = b4[k];
  } else {
    #pragma unroll
    for (int k = 0; k < 16; k++) *(uint4*)&Ar[k*8] = make_uint4(0u,0u,0u,0u);
  }
  __syncthreads();
  int c15 = lane & 15, q = lane >> 4;
  int r_idx = (blockIdx.x*2 + wv) & 63;
  unsigned short* Aw = &A[wv][0][0];
  unsigned short* Cw = &Cb[wv][0][0];
  for (int h = 0; h < 2; h++){
    const float* Wp = W5 + (size_t)h*64*128;
    short8_t bf[4][4];
    #pragma unroll
    for (int nt = 0; nt < 4; nt++){
      int c = nt*16 + c15;
      #pragma unroll
      for (int kt = 0; kt < 4; kt++){
        const float* wr = Wp + (size_t)c*128 + kt*32 + q*8;
        union { short8_t v; unsigned short u[8]; } pb;
        #pragma unroll
        for (int j = 0; j < 8; j++) pb.u[j] = f2bf(wr[j]);
        bf[nt][kt] = pb.v;
      }
    }
    f32x4_t acc[4][4];
    #pragma unroll
    for (int mt = 0; mt < 4; mt++)
      #pragma unroll
      for (int nt = 0; nt < 4; nt++){
        float bv = b5[h*64 + nt*16 + c15];
        acc[mt][nt] = (f32x4_t){bv, bv, bv, bv};
      }
    #pragma unroll
    for (int mt = 0; mt < 4; mt++){
      #pragma unroll
      for (int kt = 0; kt < 4; kt++){
        short8_t af = *(const short8_t*)&Aw[(mt*16 + c15)*136 + kt*32 + q*8];
        #pragma unroll
        for (int nt = 0; nt < 4; nt++)
          acc[mt][nt] = __builtin_amdgcn_mfma_f32_16x16x32_bf16(af, bf[nt][kt], acc[mt][nt], 0, 0, 0);
      }
    }
    // fused BN5 stats (channels h*64 .. h*64+63), mask n >= N
    #pragma unroll
    for (int nt = 0; nt < 4; nt++){
      float s = 0.f, qq = 0.f;
      #pragma unroll
      for (int mt = 0; mt < 4; mt++){
        #pragma unroll
        for (int r = 0; r < 4; r++){
          long ni = nb0 + mt*16 + q*4 + r;
          float v = (ni < N) ? acc[mt][nt][r] : 0.f;
          s += v; qq += v*v;
        }
      }
      s += __shfl_xor(s, 16, 64); qq += __shfl_xor(qq, 16, 64);
      s += __shfl_xor(s, 32, 64); qq += __shfl_xor(qq, 32, 64);
      if (lane < 16){
        int ch = h*64 + nt*16 + lane;
        atomicAdd(&repl[r_idx*256 + ch], s);
        atomicAdd(&repl[r_idx*256 + 128 + ch], qq);
      }
    }
    // C half -> LDS -> coalesced y5 stores (8 lanes per row, 16B each)
    #pragma unroll
    for (int mt = 0; mt < 4; mt++)
      #pragma unroll
      for (int nt = 0; nt < 4; nt++){
        #pragma unroll
        for (int r = 0; r < 4; r++){
          int row = mt*16 + q*4 + r;
          Cw[row*72 + nt*16 + c15] = f2bf(acc[mt][nt][r]);
        }
      }
    int rl = lane >> 3, ch8 = lane & 7;
    #pragma unroll
    for (int pass = 0; pass < 8; pass++){
      int row = pass*8 + rl;
      long nn = nb0 + row;
      if (nn < N)
        *(uint4*)(y5 + (size_t)nn*128 + h*64 + ch8*8) = *(const uint4*)&Cw[row*72 + ch8*8];
    }
  }
}

// ---------- pool ----------
__global__ void k_pool(const unsigned short* __restrict__ y5, const void* __restrict__ batch, int N,
                       const int* dmode, const float* __restrict__ ss5, unsigned int* __restrict__ pooled){
  int m64 = dmode[0];
  int c = threadIdx.x;               // 128 threads
  int n0 = blockIdx.x*512;
  int n1 = min(n0 + 512, N);
  float sc = ss5[c], sh = ss5[128 + c];
  int curb = -1; float curm = 0.f;
  for (int n = n0; n < n1; n++){
    int b = clampi(ld_idx(batch, (long)n, m64), 0, 63);
    float v = fmaf(bf2f(y5[(size_t)n*128 + c]), sc, sh);
    if (b != curb){
      if (curb >= 0) atomicMax(&pooled[curb*128 + c], __float_as_uint(fmaxf(curm, 0.f)));
      curb = b; curm = v;
    } else {
      curm = fmaxf(curm, v);
    }
  }
  if (curb >= 0) atomicMax(&pooled[curb*128 + c], __float_as_uint(fmaxf(curm, 0.f)));
}

// ---------- head ----------
__global__ void k_pooled2f(const unsigned int* __restrict__ pooled, float* __restrict__ pf){
  int i = blockIdx.x*256 + threadIdx.x;
  if (i < 8192) pf[i] = __uint_as_float(pooled[i]);
}

__global__ void k_linH(const float* __restrict__ X, const float* __restrict__ W,
                       const float* __restrict__ b, int CI, int CO, float* __restrict__ Y){
  int cell = blockIdx.x*256 + threadIdx.x;
  if (cell >= 64*CO) return;
  int r = cell / CO, c = cell - r*CO;
  const float* xr = X + r*CI;
  const float* wr = W + c*CI;
  float a = b[c];
  for (int j = 0; j < CI; j++) a = fmaf(xr[j], wr[j], a);
  Y[cell] = a;
}

__global__ void k_bnH(const float* __restrict__ Y, int CO,
                      const float* __restrict__ g, const float* __restrict__ be,
                      float* __restrict__ ss){
  int c = threadIdx.x;
  if (c >= CO) return;
  float s = 0.f;
  for (int r = 0; r < 64; r++) s += Y[r*CO + c];
  float mean = s * (1.f/64.f);
  float q = 0.f;
  for (int r = 0; r < 64; r++){ float d = Y[r*CO + c] - mean; q += d*d; }
  float var = fmaxf(q * (1.f/64.f), 0.f);
  float inv = rsqrtf(var + EPS_BN);
  float sc = g[c] * inv;
  ss[c] = sc;
  ss[CO + c] = be[c] - mean*sc;
}

__global__ void k_bnreluH(float* __restrict__ Y, int CO, const float* __restrict__ ss){
  int cell = blockIdx.x*256 + threadIdx.x;
  if (cell >= 64*CO) return;
  int c = cell % CO;
  Y[cell] = fmaxf(fmaf(Y[cell], ss[c], ss[CO + c]), 0.f);
}

__global__ void k_logsm(const float* __restrict__ Z, float* __restrict__ out){
  int r = threadIdx.x;   // 64 threads
  const float* zr = Z + r*40;
  float m = zr[0];
  for (int c = 1; c < 40; c++) m = fmaxf(m, zr[c]);
  float s = 0.f;
  for (int c = 0; c < 40; c++) s += expf(zr[c] - m);
  float ls = logf(s);
  for (int c = 0; c < 40; c++) out[r*40 + c] = zr[c] - m - ls;
}

// ---------- launch ----------
extern "C" void kernel_launch(void* const* d_in, const int* in_sizes, int n_in,
                              void* d_out, int out_size, void* d_ws, size_t ws_size,
                              hipStream_t stream) {
  const void* pos   = d_in[0];
  const void* ei    = d_in[1];
  const void* batch = d_in[2];
  (void)n_in;

  const int N = in_sizes[0] / 3;
  const int E = in_sizes[1] / 2;
  const int nTiles = cdiv(E, 64);

  // ---- workspace layout ----
  auto al = [](size_t x){ return (x + 255) & ~(size_t)255; };
  char* w = (char*)d_ws;
  size_t o = 0;
  float* repl = (float*)(w + o);                 o += (size_t)64*256*4;
  unsigned int* pooled = (unsigned int*)(w + o); o += (size_t)64*128*4;
  int* deg = (int*)(w + o);                      o += al((size_t)4*N);
  size_t zero_bytes = o;
  int* dmode = (int*)(w + o);                    o += 256;
  int* offs = (int*)(w + o);                     o += al((size_t)4*(N + 1));
  int* cursor = (int*)(w + o);                   o += al((size_t)4*N);
  int* part = (int*)(w + o);                     o += 4096;
  int* bucket = (int*)(w + o);                   o += al((size_t)4*E);
  float* ss1 = (float*)(w + o);                  o += 1024;
  float* ss2 = (float*)(w + o);                  o += 1024;
  float* ss3 = (float*)(w + o);                  o += 1024;
  float* ss4 = (float*)(w + o);                  o += 1024;
  float* ss5 = (float*)(w + o);                  o += 1024;
  float* ssH = (float*)(w + o);                  o += 1024;
  float* Wab = (float*)(w + o);                  o += (size_t)8192*4;
  float* pooledF = (float*)(w + o);              o += (size_t)8192*4;
  float* Y6 = (float*)(w + o);                   o += (size_t)8192*4;
  float* Y7 = (float*)(w + o);                   o += (size_t)8192*4;
  float* Zl = (float*)(w + o);                   o += al((size_t)2560*4);
  // fp32 expansion region
  float* expBase = (float*)(w + o);
  float* ep = expBase;
  float* epos = ep; ep += (size_t)3*N;
  float* eW[9], *eb[9], *eg[9], *ebe[9];
  const int wsz[9] = {0, 64*6, 64*64, 64*64, 64*128, 128*128, 128*128, 128*128, 40*128};
  const int bsz[9] = {0, 64, 64, 64, 64, 128, 128, 128, 40};
  for (int i = 1; i <= 8; i++){
    eW[i] = ep; ep += wsz[i];
    eb[i] = ep; ep += bsz[i];
    if (i < 8){ eg[i] = ep; ep += bsz[i]; ebe[i] = ep; ep += bsz[i]; }
  }
  long expCount = (long)(ep - expBase);
  o += al((size_t)expCount * 4);
  unsigned short* x1b = (unsigned short*)(w + o); o += al((size_t)2*64*N);
  unsigned short* x2b = (unsigned short*)(w + o); o += al((size_t)2*64*N);
  unsigned short* y5b = (unsigned short*)(w + o); o += al((size_t)2*128*N);
  unsigned short* mbuf = (unsigned short*)(w + o); o += al((size_t)8192*nTiles);
  uint4* mbuf4 = (uint4*)mbuf;

  float* out_f = (float*)d_out;
  if (ws_size < o){
    k_sentinel<<<cdiv(out_size,256), 256, 0, stream>>>(out_f, out_size);
    return;
  }

  hipMemsetAsync(w, 0, zero_bytes, stream);
  k_detect<<<1, 256, 0, stream>>>(ei, pos, dmode);

  // expand all float inputs -> fp32
  ExpArgs ea;
  int it = 0;
  ea.it[it++] = {pos, epos, 3*N};
  int di_idx = 3;
  for (int i = 1; i <= 8; i++){
    ea.it[it++] = {d_in[di_idx++], eW[i], wsz[i]};
    ea.it[it++] = {d_in[di_idx++], eb[i], bsz[i]};
    if (i < 8){
      ea.it[it++] = {d_in[di_idx++], eg[i], bsz[i]};
      ea.it[it++] = {d_in[di_idx++], ebe[i], bsz[i]};
    }
  }
  k_expand<<<dim3(cdiv(3*N,256), 31), 256, 0, stream>>>(ea, it, dmode);
  k_prepW4<<<32, 256, 0, stream>>>(eW[4], Wab);

  const int nb = cdiv(N, 1024);
  // CSR build
  k_hist<<<cdiv(E,256), 256, 0, stream>>>(ei, E, N, dmode, deg);
  k_scan1<<<nb, 1024, 0, stream>>>(deg, N, offs, part);
  k_scan2<<<1, 1024, 0, stream>>>(part, nb);
  k_scan3<<<nb, 1024, 0, stream>>>(deg, part, N, E, offs, cursor);
  k_fill<<<cdiv(E,256), 256, 0, stream>>>(ei, E, N, dmode, cursor, bucket);

  // conv1 (MFMA, fused stats; edges in bucket order)
  k_m1stats<<<cdiv(E,2048), 256, 0, stream>>>(epos, ei, E, N, dmode, eW[1], eb[1], repl);
  k_finalize<<<1, 128, 0, stream>>>(repl, 64, (float)E, eg[1], ebe[1], ss1);
  k_conv1_l2<<<cdiv(E,128), 128, 0, stream>>>(epos, ei, bucket, E, N, dmode,
                                              eW[1], eb[1], ss1, eW[2], eb[2], mbuf4, repl);
  k_finalize<<<1, 128, 0, stream>>>(repl, 64, (float)E, eg[2], ebe[2], ss2);
  k_conv1_l3<<<cdiv(E,128), 128, 0, stream>>>(mbuf4, E, ss2, eW[3], eb[3], repl);
  k_finalize<<<1, 128, 0, stream>>>(repl, 64, (float)E, eg[3], ebe[3], ss3);
  k_aggregate<<<cdiv(N,4), 256, 0, stream>>>(mbuf, offs, N, E, ss3, x1b);

  // conv2 (MFMA)
  k_conv2<<<cdiv(E,128), 128, 0, stream>>>(x1b, ei, bucket, E, N, dmode, Wab, eb[4], mbuf4, repl);
  k_finalize<<<1, 128, 0, stream>>>(repl, 64, (float)E, eg[4], ebe[4], ss4);
  k_aggregate<<<cdiv(N,4), 256, 0, stream>>>(mbuf, offs, N, E, ss4, x2b);

  // lin5 (MFMA, fused BN5 stats) + pool
  k_lin5m<<<cdiv(N,128), 128, 0, stream>>>(x1b, x2b, N, eW[5], eb[5], y5b, repl);
  k_finalize<<<1, 128, 0, stream>>>(repl, 128, (float)N, eg[5], ebe[5], ss5);
  k_pool<<<cdiv(N,512), 128, 0, stream>>>(y5b, batch, N, dmode, ss5, pooled);

  // head
  k_pooled2f<<<32, 256, 0, stream>>>(pooled, pooledF);
  k_linH<<<32, 256, 0, stream>>>(pooledF, eW[6], eb[6], 128, 128, Y6);
  k_bnH<<<1, 128, 0, stream>>>(Y6, 128, eg[6], ebe[6], ssH);
  k_bnreluH<<<32, 256, 0, stream>>>(Y6, 128, ssH);
  k_linH<<<32, 256, 0, stream>>>(Y6, eW[7], eb[7], 128, 128, Y7);
  k_bnH<<<1, 128, 0, stream>>>(Y7, 128, eg[7], ebe[7], ssH);
  k_bnreluH<<<32, 256, 0, stream>>>(Y7, 128, ssH);
  k_linH<<<10, 256, 0, stream>>>(Y7, eW[8], eb[8], 128, 40, Zl);
  k_logsm<<<1, 64, 0, stream>>>(Zl, out_f);
}

// Round 14
// 1058.229 us; speedup vs baseline: 11.8876x; 1.1706x over previous
//
#include <hip/hip_runtime.h>
#include <math.h>

#define EPS_BN 1e-5f

// Wire formats (established r0-r8): float inputs = bf16 (runtime-detected),
// int inputs = int32/int64 (runtime-detected), OUTPUT = FP32.
// mbuf layout: [tile=64 edges][8 chunks][64 edge-slots][16B]; edges in CSR-bucket order.
// r12: conv kernels as wave-level MFMA GEMMs -> 6.8ms -> 1.85ms.
// r13: k_lin5 -> MFMA + fused BN5 stats -> 1.24ms.
// r14: k_pool re-gridded (was 25K threads, 3% occupancy, latency-bound 220us).

typedef short short8_t __attribute__((ext_vector_type(8)));
typedef float f32x4_t  __attribute__((ext_vector_type(4)));

// ---------- helpers ----------
static __device__ __forceinline__ float bf2f(unsigned short b){
  return __uint_as_float(((unsigned)b) << 16);
}
static __device__ __forceinline__ unsigned short f2bf(float f){
  unsigned u = __float_as_uint(f);
  u += 0x7fffu + ((u >> 16) & 1u);   // RNE (finite values only)
  return (unsigned short)(u >> 16);
}
static inline int cdiv(int a, int b){ return (a + b - 1) / b; }
static __device__ __forceinline__ int clampi(int v, int lo, int hi){
  return v < lo ? lo : (v > hi ? hi : v);
}
static __device__ __forceinline__ int ld_idx(const void* p, long e, int m64){
  return m64 ? (int)((const long long*)p)[e] : ((const int*)p)[e];
}

// ---------- sentinel ----------
__global__ void k_sentinel(float* out, int n){
  int i = blockIdx.x*256 + threadIdx.x;
  if (i < n) out[i] = -12288.0f;
}

// ---------- runtime dtype detection ----------
__global__ void k_detect(const void* ei, const void* pos, int* dmode){
  __shared__ int nz, ff;
  if (threadIdx.x == 0){ nz = 0; ff = 0; }
  __syncthreads();
  const int* w32 = (const int*)ei;
  if (w32[1 + 2*threadIdx.x] != 0) nz = 1;
  const unsigned short* ph = (const unsigned short*)pos;
  int bad = 0;
  for (int i = threadIdx.x; i < 8192; i += 256)
    if (((ph[i] >> 7) & 0xFF) == 0xFF) bad = 1;
  if (bad) ff = 1;
  __syncthreads();
  if (threadIdx.x == 0){ dmode[0] = nz ? 0 : 1; dmode[1] = ff; }
}

// ---------- expand float inputs -> fp32 scratch ----------
struct ExpItem { const void* s; float* d; int n; };
struct ExpArgs { ExpItem it[31]; };
__global__ void k_expand(ExpArgs a, int cnt, const int* dmode){
  int i = blockIdx.y;
  if (i >= cnt) return;
  int m32 = dmode[1];
  int t = blockIdx.x*256 + threadIdx.x;
  if (t < a.it[i].n){
    a.it[i].d[t] = m32 ? ((const float*)a.it[i].s)[t]
                       : bf2f(((const unsigned short*)a.it[i].s)[t]);
  }
}

// ---------- Wab prep: [64][128] = [Wa | Wb], Wa = A-part minus B-part ----------
__global__ void k_prepW4(const float* __restrict__ W4, float* __restrict__ Wab){
  int i = blockIdx.x*256 + threadIdx.x;
  if (i < 8192){
    int c = i >> 7, k = i & 127;
    float v;
    if (k < 64) v = W4[c*128 + k] - W4[c*128 + 64 + k];
    else        v = W4[c*128 + k];
    Wab[i] = v;
  }
}

// ---------- CSR build ----------
__global__ void k_hist(const void* __restrict__ ei, int E, int N, const int* dmode, int* __restrict__ deg){
  int m64 = dmode[0];
  int e = blockIdx.x*256 + threadIdx.x;
  if (e < E) atomicAdd(&deg[clampi(ld_idx(ei, (long)E + e, m64), 0, N-1)], 1);
}

__global__ void k_scan1(const int* __restrict__ deg, int N, int* __restrict__ incl, int* __restrict__ part){
  __shared__ int s[1024];
  int i = blockIdx.x*1024 + threadIdx.x;
  s[threadIdx.x] = (i < N) ? deg[i] : 0;
  __syncthreads();
  for (int off = 1; off < 1024; off <<= 1){
    int t = (threadIdx.x >= off) ? s[threadIdx.x - off] : 0;
    __syncthreads();
    s[threadIdx.x] += t;
    __syncthreads();
  }
  if (i < N) incl[i] = s[threadIdx.x];
  if (threadIdx.x == 1023) part[blockIdx.x] = s[1023];
}

__global__ void k_scan2(int* __restrict__ part, int nb){
  __shared__ int s[1024];
  int i = threadIdx.x;
  s[i] = (i < nb) ? part[i] : 0;
  __syncthreads();
  for (int off = 1; off < 1024; off <<= 1){
    int t = (i >= off) ? s[i - off] : 0;
    __syncthreads();
    s[i] += t;
    __syncthreads();
  }
  if (i < nb) part[i] = s[i];
}

__global__ void k_scan3(const int* __restrict__ deg, const int* __restrict__ part, int N, int E,
                        int* __restrict__ offs, int* __restrict__ cursor){
  int i = blockIdx.x*1024 + threadIdx.x;
  if (i < N){
    int prev = (blockIdx.x > 0) ? part[blockIdx.x - 1] : 0;
    int v = prev + offs[i] - deg[i];
    offs[i] = v;
    cursor[i] = v;
  }
  if (blockIdx.x == 0 && threadIdx.x == 0) offs[N] = E;
}

__global__ void k_fill(const void* __restrict__ ei, int E, int N, const int* dmode,
                       int* __restrict__ cursor, int* __restrict__ bucket){
  int m64 = dmode[0];
  int e = blockIdx.x*256 + threadIdx.x;
  if (e < E){
    int p = atomicAdd(&cursor[clampi(ld_idx(ei, (long)E + e, m64), 0, N-1)], 1);
    if (p >= 0 && p < E) bucket[p] = e;
  }
}

// ---------- conv1 layer1 stats ----------
__global__ void __launch_bounds__(256, 1)
k_m1stats(const float* __restrict__ pos, const void* __restrict__ ei,
          int E, int N, const int* dmode,
          const float* __restrict__ W1, const float* __restrict__ b1,
          float* __restrict__ repl){
  int m64 = dmode[0];
  int lane = threadIdx.x & 63;
  int flatwave = (blockIdx.x*256 + threadIdx.x) >> 6;
  long base = (long)flatwave * 512;
  float as[64], aq[64];
  #pragma unroll
  for (int c = 0; c < 64; c++){ as[c] = 0.f; aq[c] = 0.f; }
  for (int k = 0; k < 8; k++){
    long e = base + (long)k*64 + lane;
    if (e < E){
      int si = clampi(ld_idx(ei, e, m64), 0, N-1);
      int di = clampi(ld_idx(ei, (long)E + e, m64), 0, N-1);
      float x0 = pos[di*3+0], x1 = pos[di*3+1], x2 = pos[di*3+2];
      float j0 = pos[si*3+0]-x0, j1 = pos[si*3+1]-x1, j2 = pos[si*3+2]-x2;
      #pragma unroll
      for (int c = 0; c < 64; c++){
        float m = b1[c];
        m = fmaf(x0, W1[c*6+0], m); m = fmaf(x1, W1[c*6+1], m); m = fmaf(x2, W1[c*6+2], m);
        m = fmaf(j0, W1[c*6+3], m); m = fmaf(j1, W1[c*6+4], m); m = fmaf(j2, W1[c*6+5], m);
        as[c] += m; aq[c] += m*m;
      }
    }
  }
  float outs = 0.f, outq = 0.f;
  #pragma unroll
  for (int c = 0; c < 64; c++){
    float s = as[c], q = aq[c];
    #pragma unroll
    for (int m = 1; m < 64; m <<= 1){ s += __shfl_xor(s, m, 64); q += __shfl_xor(q, m, 64); }
    if (lane == c){ outs = s; outq = q; }
  }
  int r = flatwave & 63;
  atomicAdd(&repl[r*256 + lane], outs);
  atomicAdd(&repl[r*256 + 128 + lane], outq);
}

// ---------- finalize BN ----------
__global__ void k_finalize(float* __restrict__ repl, int C, float count,
                           const float* __restrict__ g, const float* __restrict__ be,
                           float* __restrict__ ss){
  int c = threadIdx.x;
  if (c < C){
    float s = 0.f, q = 0.f;
    for (int r = 0; r < 64; r++){
      s += repl[r*256 + c];       repl[r*256 + c] = 0.f;
      q += repl[r*256 + 128 + c]; repl[r*256 + 128 + c] = 0.f;
    }
    float mean = s / count;
    float var  = fmaxf(q / count - mean*mean, 0.f);
    float inv  = rsqrtf(var + EPS_BN);
    float sc   = g[c] * inv;
    ss[c]     = sc;
    ss[C + c] = be[c] - mean*sc;
  }
}

// ---------- MFMA tail: C[64e][64c] = A(LDS) @ W^T + bias; stats; tiled store ----------
template<int KT, int ST>
static __device__ __forceinline__ void mfma_tail(
    unsigned short* Aw, const float* __restrict__ Wp, const float* __restrict__ bias,
    long tb, int E, int lane, int r_idx, float* __restrict__ repl,
    uint4* __restrict__ mbuf4){
  int c15 = lane & 15, q = lane >> 4;
  short8_t bf[4][KT];
  #pragma unroll
  for (int nt = 0; nt < 4; nt++){
    int c = nt*16 + c15;
    #pragma unroll
    for (int kt = 0; kt < KT; kt++){
      const float* wr = Wp + (size_t)c*(KT*32) + kt*32 + q*8;
      union { short8_t v; unsigned short u[8]; } pb;
      #pragma unroll
      for (int j = 0; j < 8; j++) pb.u[j] = f2bf(wr[j]);
      bf[nt][kt] = pb.v;
    }
  }
  f32x4_t acc[4][4];
  #pragma unroll
  for (int mt = 0; mt < 4; mt++)
    #pragma unroll
    for (int nt = 0; nt < 4; nt++){
      float bv = bias[nt*16 + c15];
      acc[mt][nt] = (f32x4_t){bv, bv, bv, bv};
    }
  #pragma unroll
  for (int mt = 0; mt < 4; mt++){
    #pragma unroll
    for (int kt = 0; kt < KT; kt++){
      short8_t af = *(const short8_t*)&Aw[(mt*16 + c15)*ST + kt*32 + q*8];
      #pragma unroll
      for (int nt = 0; nt < 4; nt++)
        acc[mt][nt] = __builtin_amdgcn_mfma_f32_16x16x32_bf16(af, bf[nt][kt], acc[mt][nt], 0, 0, 0);
    }
  }
  #pragma unroll
  for (int nt = 0; nt < 4; nt++){
    float s = 0.f, qq = 0.f;
    #pragma unroll
    for (int mt = 0; mt < 4; mt++){
      #pragma unroll
      for (int r = 0; r < 4; r++){
        long eidx = tb + mt*16 + q*4 + r;
        float v = (eidx < E) ? acc[mt][nt][r] : 0.f;
        s += v; qq += v*v;
      }
    }
    s += __shfl_xor(s, 16, 64); qq += __shfl_xor(qq, 16, 64);
    s += __shfl_xor(s, 32, 64); qq += __shfl_xor(qq, 32, 64);
    if (lane < 16){
      atomicAdd(&repl[r_idx*256 + nt*16 + lane], s);
      atomicAdd(&repl[r_idx*256 + 128 + nt*16 + lane], qq);
    }
  }
  __syncthreads();
  #pragma unroll
  for (int mt = 0; mt < 4; mt++)
    #pragma unroll
    for (int nt = 0; nt < 4; nt++){
      #pragma unroll
      for (int r = 0; r < 4; r++){
        int row = mt*16 + q*4 + r;
        Aw[row*ST + nt*16 + c15] = f2bf(acc[mt][nt][r]);
      }
    }
  __syncthreads();
  long t = tb + lane;
  if (t < E){
    uint4* ob = mbuf4 + (((size_t)(t >> 6)) << 9) + (t & 63);
    #pragma unroll
    for (int ci = 0; ci < 8; ci++){
      uint4 v = *(const uint4*)&Aw[lane*ST + ci*8];
      ob[ci << 6] = v;
    }
  }
}

// ---------- conv1 l2 (MFMA) ----------
__global__ void __launch_bounds__(128, 1)
k_conv1_l2(const float* __restrict__ pos, const void* __restrict__ ei,
           const int* __restrict__ bucket, int E, int N, const int* dmode,
           const float* __restrict__ W1, const float* __restrict__ b1,
           const float* __restrict__ ss1,
           const float* __restrict__ W2, const float* __restrict__ b2,
           uint4* __restrict__ mbuf4, float* __restrict__ repl){
  __shared__ unsigned short A[2][64][72];
  int m64 = dmode[0];
  int wv = threadIdx.x >> 6, lane = threadIdx.x & 63;
  long tb = (long)blockIdx.x*128 + wv*64;
  long t = tb + lane;
  int valid = (t < E);
  unsigned short* Ar = &A[wv][lane][0];
  if (valid){
    int p = bucket[t];
    int si = clampi(ld_idx(ei, (long)p, m64), 0, N-1);
    int di = clampi(ld_idx(ei, (long)E + p, m64), 0, N-1);
    float x0 = pos[di*3+0], x1 = pos[di*3+1], x2 = pos[di*3+2];
    float j0 = pos[si*3+0]-x0, j1 = pos[si*3+1]-x1, j2 = pos[si*3+2]-x2;
    #pragma unroll
    for (int c4 = 0; c4 < 64; c4 += 4){
      unsigned short h[4];
      #pragma unroll
      for (int u = 0; u < 4; u++){
        int c = c4 + u;
        float m = b1[c];
        m = fmaf(x0, W1[c*6+0], m); m = fmaf(x1, W1[c*6+1], m); m = fmaf(x2, W1[c*6+2], m);
        m = fmaf(j0, W1[c*6+3], m); m = fmaf(j1, W1[c*6+4], m); m = fmaf(j2, W1[c*6+5], m);
        h[u] = f2bf(fmaxf(fmaf(m, ss1[c], ss1[64 + c]), 0.f));
      }
      uint2 pk;
      pk.x = ((unsigned)h[1] << 16) | h[0];
      pk.y = ((unsigned)h[3] << 16) | h[2];
      *(uint2*)&Ar[c4] = pk;
    }
  } else {
    #pragma unroll
    for (int c4 = 0; c4 < 64; c4 += 4) *(uint2*)&Ar[c4] = make_uint2(0u, 0u);
  }
  __syncthreads();
  mfma_tail<2, 72>(&A[wv][0][0], W2, b2, tb, E, lane, (blockIdx.x*2 + wv) & 63, repl, mbuf4);
}

// ---------- conv1 l3 (MFMA, in place) ----------
__global__ void __launch_bounds__(128, 1)
k_conv1_l3(uint4* __restrict__ mbuf4, int E,
           const float* __restrict__ ss, const float* __restrict__ W3,
           const float* __restrict__ b3, float* __restrict__ repl){
  __shared__ unsigned short A[2][64][72];
  int wv = threadIdx.x >> 6, lane = threadIdx.x & 63;
  long tb = (long)blockIdx.x*128 + wv*64;
  long t = tb + lane;
  int valid = (t < E);
  unsigned short* Ar = &A[wv][lane][0];
  if (valid){
    const uint4* base = mbuf4 + (((size_t)(t >> 6)) << 9) + (t & 63);
    #pragma unroll
    for (int k = 0; k < 8; k++){
      uint4 u = base[(size_t)(k << 6)];
      unsigned vals[4] = {u.x, u.y, u.z, u.w};
      unsigned short h[8];
      #pragma unroll
      for (int q = 0; q < 4; q++){
        int c = k*8 + q*2;
        float lo = __uint_as_float(vals[q] << 16);
        float hi = __uint_as_float(vals[q] & 0xffff0000u);
        h[q*2]   = f2bf(fmaxf(fmaf(lo, ss[c],   ss[64 + c]),   0.f));
        h[q*2+1] = f2bf(fmaxf(fmaf(hi, ss[c+1], ss[64 + c+1]), 0.f));
      }
      uint4 pk;
      pk.x = ((unsigned)h[1] << 16) | h[0];
      pk.y = ((unsigned)h[3] << 16) | h[2];
      pk.z = ((unsigned)h[5] << 16) | h[4];
      pk.w = ((unsigned)h[7] << 16) | h[6];
      *(uint4*)&Ar[k*8] = pk;
    }
  } else {
    #pragma unroll
    for (int k = 0; k < 8; k++) *(uint4*)&Ar[k*8] = make_uint4(0u,0u,0u,0u);
  }
  __syncthreads();
  mfma_tail<2, 72>(&A[wv][0][0], W3, b3, tb, E, lane, (blockIdx.x*2 + wv) & 63, repl, mbuf4);
}

// ---------- conv2 (MFMA) ----------
__global__ void __launch_bounds__(128, 1)
k_conv2(const unsigned short* __restrict__ x1, const void* __restrict__ ei,
        const int* __restrict__ bucket, int E, int N, const int* dmode,
        const float* __restrict__ Wab, const float* __restrict__ b4,
        uint4* __restrict__ mbuf4, float* __restrict__ repl){
  __shared__ unsigned short A[2][64][136];
  int m64 = dmode[0];
  int wv = threadIdx.x >> 6, lane = threadIdx.x & 63;
  long tb = (long)blockIdx.x*128 + wv*64;
  long t = tb + lane;
  int valid = (t < E);
  unsigned short* Ar = &A[wv][lane][0];
  if (valid){
    int p = bucket[t];
    int si = clampi(ld_idx(ei, (long)p, m64), 0, N-1);
    int di = clampi(ld_idx(ei, (long)E + p, m64), 0, N-1);
    const uint4* xi4 = (const uint4*)(x1 + (size_t)di*64);
    const uint4* xj4 = (const uint4*)(x1 + (size_t)si*64);
    #pragma unroll
    for (int k = 0; k < 8; k++) *(uint4*)&Ar[k*8]      = xi4[k];
    #pragma unroll
    for (int k = 0; k < 8; k++) *(uint4*)&Ar[64 + k*8] = xj4[k];
  } else {
    #pragma unroll
    for (int k = 0; k < 16; k++) *(uint4*)&Ar[k*8] = make_uint4(0u,0u,0u,0u);
  }
  __syncthreads();
  mfma_tail<4, 136>(&A[wv][0][0], Wab, b4, tb, E, lane, (blockIdx.x*2 + wv) & 63, repl, mbuf4);
}

// ---------- aggregate: sequential CSR rows in tiled layout ----------
__global__ void k_aggregate(const unsigned short* __restrict__ mbuf,
                            const int* __restrict__ offs, int N, int E,
                            const float* __restrict__ ss, unsigned short* __restrict__ xout){
  int wave = threadIdx.x >> 6;
  int lane = threadIdx.x & 63;
  int n = blockIdx.x*4 + wave;
  if (n >= N) return;
  int s0 = clampi(offs[n], 0, E);
  int s1 = clampi(offs[n + 1], s0, E);
  float sc = ss[lane], sh = ss[64 + lane];
  int g = lane >> 3, pz = lane & 7;
  float acc = 0.f;
  for (int k = s0; k < s1; k++){
    size_t idx = (((size_t)(k >> 6)) << 12) + (g << 9) + ((k & 63) << 3) + pz;
    float v = bf2f(mbuf[idx]);
    acc = fmaxf(acc, fmaf(v, sc, sh));
  }
  xout[(size_t)n*64 + lane] = f2bf(acc);
}

// ---------- lin5 (MFMA): y5 = cat(x1,x2)@W5^T + b5, fused BN5 stats ----------
__global__ void __launch_bounds__(128, 1)
k_lin5m(const unsigned short* __restrict__ x1, const unsigned short* __restrict__ x2,
        int N, const float* __restrict__ W5, const float* __restrict__ b5,
        unsigned short* __restrict__ y5, float* __restrict__ repl){
  __shared__ unsigned short A[2][64][136];
  __shared__ unsigned short Cb[2][64][72];
  int wv = threadIdx.x >> 6, lane = threadIdx.x & 63;
  long nb0 = (long)blockIdx.x*128 + wv*64;
  long n = nb0 + lane;
  unsigned short* Ar = &A[wv][lane][0];
  if (n < N){
    const uint4* a4 = (const uint4*)(x1 + (size_t)n*64);
    const uint4* b4 = (const uint4*)(x2 + (size_t)n*64);
    #pragma unroll
    for (int k = 0; k < 8; k++) *(uint4*)&Ar[k*8]      = a4[k];
    #pragma unroll
    for (int k = 0; k < 8; k++) *(uint4*)&Ar[64 + k*8] = b4[k];
  } else {
    #pragma unroll
    for (int k = 0; k < 16; k++) *(uint4*)&Ar[k*8] = make_uint4(0u,0u,0u,0u);
  }
  __syncthreads();
  int c15 = lane & 15, q = lane >> 4;
  int r_idx = (blockIdx.x*2 + wv) & 63;
  unsigned short* Aw = &A[wv][0][0];
  unsigned short* Cw = &Cb[wv][0][0];
  for (int h = 0; h < 2; h++){
    const float* Wp = W5 + (size_t)h*64*128;
    short8_t bf[4][4];
    #pragma unroll
    for (int nt = 0; nt < 4; nt++){
      int c = nt*16 + c15;
      #pragma unroll
      for (int kt = 0; kt < 4; kt++){
        const float* wr = Wp + (size_t)c*128 + kt*32 + q*8;
        union { short8_t v; unsigned short u[8]; } pb;
        #pragma unroll
        for (int j = 0; j < 8; j++) pb.u[j] = f2bf(wr[j]);
        bf[nt][kt] = pb.v;
      }
    }
    f32x4_t acc[4][4];
    #pragma unroll
    for (int mt = 0; mt < 4; mt++)
      #pragma unroll
      for (int nt = 0; nt < 4; nt++){
        float bv = b5[h*64 + nt*16 + c15];
        acc[mt][nt] = (f32x4_t){bv, bv, bv, bv};
      }
    #pragma unroll
    for (int mt = 0; mt < 4; mt++){
      #pragma unroll
      for (int kt = 0; kt < 4; kt++){
        short8_t af = *(const short8_t*)&Aw[(mt*16 + c15)*136 + kt*32 + q*8];
        #pragma unroll
        for (int nt = 0; nt < 4; nt++)
          acc[mt][nt] = __builtin_amdgcn_mfma_f32_16x16x32_bf16(af, bf[nt][kt], acc[mt][nt], 0, 0, 0);
      }
    }
    #pragma unroll
    for (int nt = 0; nt < 4; nt++){
      float s = 0.f, qq = 0.f;
      #pragma unroll
      for (int mt = 0; mt < 4; mt++){
        #pragma unroll
        for (int r = 0; r < 4; r++){
          long ni = nb0 + mt*16 + q*4 + r;
          float v = (ni < N) ? acc[mt][nt][r] : 0.f;
          s += v; qq += v*v;
        }
      }
      s += __shfl_xor(s, 16, 64); qq += __shfl_xor(qq, 16, 64);
      s += __shfl_xor(s, 32, 64); qq += __shfl_xor(qq, 32, 64);
      if (lane < 16){
        int ch = h*64 + nt*16 + lane;
        atomicAdd(&repl[r_idx*256 + ch], s);
        atomicAdd(&repl[r_idx*256 + 128 + ch], qq);
      }
    }
    #pragma unroll
    for (int mt = 0; mt < 4; mt++)
      #pragma unroll
      for (int nt = 0; nt < 4; nt++){
        #pragma unroll
        for (int r = 0; r < 4; r++){
          int row = mt*16 + q*4 + r;
          Cw[row*72 + nt*16 + c15] = f2bf(acc[mt][nt][r]);
        }
      }
    int rl = lane >> 3, ch8 = lane & 7;
    #pragma unroll
    for (int pass = 0; pass < 8; pass++){
      int row = pass*8 + rl;
      long nn = nb0 + row;
      if (nn < N)
        *(uint4*)(y5 + (size_t)nn*128 + h*64 + ch8*8) = *(const uint4*)&Cw[row*72 + ch8*8];
    }
  }
}

// ---------- pool: 256 threads, 128 rows/block (r14: was 3% occupancy) ----------
__global__ void k_pool(const unsigned short* __restrict__ y5, const void* __restrict__ batch, int N,
                       const int* dmode, const float* __restrict__ ss5, unsigned int* __restrict__ pooled){
  int m64 = dmode[0];
  int c = threadIdx.x & 127;
  int par = threadIdx.x >> 7;        // row parity: thread walks rows n0+2k+par
  int n0 = blockIdx.x*128;
  int n1 = min(n0 + 128, N);
  float sc = ss5[c], sh = ss5[128 + c];
  int curb = -1; float curm = 0.f;
  for (int n = n0 + par; n < n1; n += 2){
    int b = clampi(ld_idx(batch, (long)n, m64), 0, 63);
    float v = fmaf(bf2f(y5[(size_t)n*128 + c]), sc, sh);
    if (b != curb){
      if (curb >= 0) atomicMax(&pooled[curb*128 + c], __float_as_uint(fmaxf(curm, 0.f)));
      curb = b; curm = v;
    } else {
      curm = fmaxf(curm, v);
    }
  }
  if (curb >= 0) atomicMax(&pooled[curb*128 + c], __float_as_uint(fmaxf(curm, 0.f)));
}

// ---------- head ----------
__global__ void k_pooled2f(const unsigned int* __restrict__ pooled, float* __restrict__ pf){
  int i = blockIdx.x*256 + threadIdx.x;
  if (i < 8192) pf[i] = __uint_as_float(pooled[i]);
}

__global__ void k_linH(const float* __restrict__ X, const float* __restrict__ W,
                       const float* __restrict__ b, int CI, int CO, float* __restrict__ Y){
  int cell = blockIdx.x*256 + threadIdx.x;
  if (cell >= 64*CO) return;
  int r = cell / CO, c = cell - r*CO;
  const float* xr = X + r*CI;
  const float* wr = W + c*CI;
  float a = b[c];
  for (int j = 0; j < CI; j++) a = fmaf(xr[j], wr[j], a);
  Y[cell] = a;
}

__global__ void k_bnH(const float* __restrict__ Y, int CO,
                      const float* __restrict__ g, const float* __restrict__ be,
                      float* __restrict__ ss){
  int c = threadIdx.x;
  if (c >= CO) return;
  float s = 0.f;
  for (int r = 0; r < 64; r++) s += Y[r*CO + c];
  float mean = s * (1.f/64.f);
  float q = 0.f;
  for (int r = 0; r < 64; r++){ float d = Y[r*CO + c] - mean; q += d*d; }
  float var = fmaxf(q * (1.f/64.f), 0.f);
  float inv = rsqrtf(var + EPS_BN);
  float sc = g[c] * inv;
  ss[c] = sc;
  ss[CO + c] = be[c] - mean*sc;
}

__global__ void k_bnreluH(float* __restrict__ Y, int CO, const float* __restrict__ ss){
  int cell = blockIdx.x*256 + threadIdx.x;
  if (cell >= 64*CO) return;
  int c = cell % CO;
  Y[cell] = fmaxf(fmaf(Y[cell], ss[c], ss[CO + c]), 0.f);
}

__global__ void k_logsm(const float* __restrict__ Z, float* __restrict__ out){
  int r = threadIdx.x;   // 64 threads
  const float* zr = Z + r*40;
  float m = zr[0];
  for (int c = 1; c < 40; c++) m = fmaxf(m, zr[c]);
  float s = 0.f;
  for (int c = 0; c < 40; c++) s += expf(zr[c] - m);
  float ls = logf(s);
  for (int c = 0; c < 40; c++) out[r*40 + c] = zr[c] - m - ls;
}

// ---------- launch ----------
extern "C" void kernel_launch(void* const* d_in, const int* in_sizes, int n_in,
                              void* d_out, int out_size, void* d_ws, size_t ws_size,
                              hipStream_t stream) {
  const void* pos   = d_in[0];
  const void* ei    = d_in[1];
  const void* batch = d_in[2];
  (void)n_in;

  const int N = in_sizes[0] / 3;
  const int E = in_sizes[1] / 2;
  const int nTiles = cdiv(E, 64);

  // ---- workspace layout ----
  auto al = [](size_t x){ return (x + 255) & ~(size_t)255; };
  char* w = (char*)d_ws;
  size_t o = 0;
  float* repl = (float*)(w + o);                 o += (size_t)64*256*4;
  unsigned int* pooled = (unsigned int*)(w + o); o += (size_t)64*128*4;
  int* deg = (int*)(w + o);                      o += al((size_t)4*N);
  size_t zero_bytes = o;
  int* dmode = (int*)(w + o);                    o += 256;
  int* offs = (int*)(w + o);                     o += al((size_t)4*(N + 1));
  int* cursor = (int*)(w + o);                   o += al((size_t)4*N);
  int* part = (int*)(w + o);                     o += 4096;
  int* bucket = (int*)(w + o);                   o += al((size_t)4*E);
  float* ss1 = (float*)(w + o);                  o += 1024;
  float* ss2 = (float*)(w + o);                  o += 1024;
  float* ss3 = (float*)(w + o);                  o += 1024;
  float* ss4 = (float*)(w + o);                  o += 1024;
  float* ss5 = (float*)(w + o);                  o += 1024;
  float* ssH = (float*)(w + o);                  o += 1024;
  float* Wab = (float*)(w + o);                  o += (size_t)8192*4;
  float* pooledF = (float*)(w + o);              o += (size_t)8192*4;
  float* Y6 = (float*)(w + o);                   o += (size_t)8192*4;
  float* Y7 = (float*)(w + o);                   o += (size_t)8192*4;
  float* Zl = (float*)(w + o);                   o += al((size_t)2560*4);
  // fp32 expansion region
  float* expBase = (float*)(w + o);
  float* ep = expBase;
  float* epos = ep; ep += (size_t)3*N;
  float* eW[9], *eb[9], *eg[9], *ebe[9];
  const int wsz[9] = {0, 64*6, 64*64, 64*64, 64*128, 128*128, 128*128, 128*128, 40*128};
  const int bsz[9] = {0, 64, 64, 64, 64, 128, 128, 128, 40};
  for (int i = 1; i <= 8; i++){
    eW[i] = ep; ep += wsz[i];
    eb[i] = ep; ep += bsz[i];
    if (i < 8){ eg[i] = ep; ep += bsz[i]; ebe[i] = ep; ep += bsz[i]; }
  }
  long expCount = (long)(ep - expBase);
  o += al((size_t)expCount * 4);
  unsigned short* x1b = (unsigned short*)(w + o); o += al((size_t)2*64*N);
  unsigned short* x2b = (unsigned short*)(w + o); o += al((size_t)2*64*N);
  unsigned short* y5b = (unsigned short*)(w + o); o += al((size_t)2*128*N);
  unsigned short* mbuf = (unsigned short*)(w + o); o += al((size_t)8192*nTiles);
  uint4* mbuf4 = (uint4*)mbuf;

  float* out_f = (float*)d_out;
  if (ws_size < o){
    k_sentinel<<<cdiv(out_size,256), 256, 0, stream>>>(out_f, out_size);
    return;
  }

  hipMemsetAsync(w, 0, zero_bytes, stream);
  k_detect<<<1, 256, 0, stream>>>(ei, pos, dmode);

  // expand all float inputs -> fp32
  ExpArgs ea;
  int it = 0;
  ea.it[it++] = {pos, epos, 3*N};
  int di_idx = 3;
  for (int i = 1; i <= 8; i++){
    ea.it[it++] = {d_in[di_idx++], eW[i], wsz[i]};
    ea.it[it++] = {d_in[di_idx++], eb[i], bsz[i]};
    if (i < 8){
      ea.it[it++] = {d_in[di_idx++], eg[i], bsz[i]};
      ea.it[it++] = {d_in[di_idx++], ebe[i], bsz[i]};
    }
  }
  k_expand<<<dim3(cdiv(3*N,256), 31), 256, 0, stream>>>(ea, it, dmode);
  k_prepW4<<<32, 256, 0, stream>>>(eW[4], Wab);

  const int nb = cdiv(N, 1024);
  // CSR build
  k_hist<<<cdiv(E,256), 256, 0, stream>>>(ei, E, N, dmode, deg);
  k_scan1<<<nb, 1024, 0, stream>>>(deg, N, offs, part);
  k_scan2<<<1, 1024, 0, stream>>>(part, nb);
  k_scan3<<<nb, 1024, 0, stream>>>(deg, part, N, E, offs, cursor);
  k_fill<<<cdiv(E,256), 256, 0, stream>>>(ei, E, N, dmode, cursor, bucket);

  // conv1 (MFMA, fused stats; edges in bucket order)
  k_m1stats<<<cdiv(E,2048), 256, 0, stream>>>(epos, ei, E, N, dmode, eW[1], eb[1], repl);
  k_finalize<<<1, 128, 0, stream>>>(repl, 64, (float)E, eg[1], ebe[1], ss1);
  k_conv1_l2<<<cdiv(E,128), 128, 0, stream>>>(epos, ei, bucket, E, N, dmode,
                                              eW[1], eb[1], ss1, eW[2], eb[2], mbuf4, repl);
  k_finalize<<<1, 128, 0, stream>>>(repl, 64, (float)E, eg[2], ebe[2], ss2);
  k_conv1_l3<<<cdiv(E,128), 128, 0, stream>>>(mbuf4, E, ss2, eW[3], eb[3], repl);
  k_finalize<<<1, 128, 0, stream>>>(repl, 64, (float)E, eg[3], ebe[3], ss3);
  k_aggregate<<<cdiv(N,4), 256, 0, stream>>>(mbuf, offs, N, E, ss3, x1b);

  // conv2 (MFMA)
  k_conv2<<<cdiv(E,128), 128, 0, stream>>>(x1b, ei, bucket, E, N, dmode, Wab, eb[4], mbuf4, repl);
  k_finalize<<<1, 128, 0, stream>>>(repl, 64, (float)E, eg[4], ebe[4], ss4);
  k_aggregate<<<cdiv(N,4), 256, 0, stream>>>(mbuf, offs, N, E, ss4, x2b);

  // lin5 (MFMA, fused BN5 stats) + pool
  k_lin5m<<<cdiv(N,128), 128, 0, stream>>>(x1b, x2b, N, eW[5], eb[5], y5b, repl);
  k_finalize<<<1, 128, 0, stream>>>(repl, 128, (float)N, eg[5], ebe[5], ss5);
  k_pool<<<cdiv(N,128), 256, 0, stream>>>(y5b, batch, N, dmode, ss5, pooled);

  // head
  k_pooled2f<<<32, 256, 0, stream>>>(pooled, pooledF);
  k_linH<<<32, 256, 0, stream>>>(pooledF, eW[6], eb[6], 128, 128, Y6);
  k_bnH<<<1, 128, 0, stream>>>(Y6, 128, eg[6], ebe[6], ssH);
  k_bnreluH<<<32, 256, 0, stream>>>(Y6, 128, ssH);
  k_linH<<<32, 256, 0, stream>>>(Y6, eW[7], eb[7], 128, 128, Y7);
  k_bnH<<<1, 128, 0, stream>>>(Y7, 128, eg[7], ebe[7], ssH);
  k_bnreluH<<<32, 256, 0, stream>>>(Y7, 128, ssH);
  k_linH<<<10, 256, 0, stream>>>(Y7, eW[8], eb[8], 128, 40, Zl);
  k_logsm<<<1, 64, 0, stream>>>(Zl, out_f);
}